// Round 5
// baseline (309.749 us; speedup 1.0000x reference)
//
#include <hip/hip_runtime.h>

typedef unsigned short u16;
typedef unsigned int   u32;
typedef short bf16x8 __attribute__((ext_vector_type(8)));
typedef short bf16x4 __attribute__((ext_vector_type(4)));
typedef float f32x4  __attribute__((ext_vector_type(4)));

#define HIMG 56
#define WIMG 56
#define CH   128
#define NHEADS 4
#define WSZ  7
#define SSH  3
#define PP   10
#define HIDD 512
#define NWIN 49          // window tokens
#define NTOK 59          // P + NWIN
#define BWIN 2048        // B * NW
#define DH   32          // head dim
#define MWIN 120832      // BWIN * NTOK
#define MPIX 100352      // B * 56 * 56
#define SLDS 68          // padded u16 stride for attn P-tile (8B aligned rows)

__device__ __forceinline__ u16 f2b(float f) {
  u32 u = __float_as_uint(f);
  u += 0x7fffu + ((u >> 16) & 1u);
  return (u16)(u >> 16);
}
__device__ __forceinline__ u32 pack2(float a, float b) {
  return (u32)f2b(a) | ((u32)f2b(b) << 16);
}

// ---------------------------------------------------------------------------
// Fold LoRA into effective weights, store TRANSPOSED bf16 (K-contiguous).
// ---------------------------------------------------------------------------
__global__ void fuse_all_kernel(
    const float* __restrict__ qw,  const float* __restrict__ qa,  const float* __restrict__ qb,
    const float* __restrict__ pw,  const float* __restrict__ pa,  const float* __restrict__ pb,
    const float* __restrict__ f1w, const float* __restrict__ f1a, const float* __restrict__ f1b,
    const float* __restrict__ f2w, const float* __restrict__ f2a, const float* __restrict__ f2b2,
    u16* __restrict__ out)
{
  int idx = blockIdx.x * 256 + threadIdx.x;
  if (idx >= 196608) return;
  const float *w, *la, *lb; int Nc, K, base;
  if (idx < 49152)       { w = qw;  la = qa;  lb = qb;   Nc = 384; K = 128; base = 0; }
  else if (idx < 65536)  { w = pw;  la = pa;  lb = pb;   Nc = 128; K = 128; base = 49152; }
  else if (idx < 131072) { w = f1w; la = f1a; lb = f1b;  Nc = 512; K = 128; base = 65536; }
  else                   { w = f2w; la = f2a; lb = f2b2; Nc = 128; K = 512; base = 131072; }
  const int li = idx - base;
  const int k = li / Nc, n = li - k * Nc;
  float s = w[li];
  #pragma unroll
  for (int r = 0; r < 4; ++r) s += la[k * 4 + r] * lb[r * Nc + n];
  out[base + n * K + k] = f2b(s);
}

// ---------------------------------------------------------------------------
// Precompute bias+mask table bm[type][h][64][64] f32.
// ---------------------------------------------------------------------------
__global__ void bm_kernel(const float* __restrict__ rpb, float* __restrict__ bm)
{
  const int idx = blockIdx.x * 256 + threadIdx.x;   // 65536
  const int j = idx & 63, i = (idx >> 6) & 63, h = (idx >> 12) & 3, type = idx >> 14;
  float v = 0.f;
  if (i < 49) {
    if (j >= 59) v = -1e30f;
    else if (j >= PP) {
      const int jw = j - PP;
      const int ih = i / 7, iw = i - ih * 7, jh = jw / 7, jw2 = jw - jh * 7;
      v = rpb[((ih - jh + 6) * 13 + (iw - jw2 + 6)) * NHEADS + h];
      const int wh7 = type >> 1, ww7 = type & 1;
      const int mi = 3 * (wh7 ? (ih < 4 ? 1 : 2) : 0) + (ww7 ? (iw < 4 ? 1 : 2) : 0);
      const int mj = 3 * (wh7 ? (jh < 4 ? 1 : 2) : 0) + (ww7 ? (jw2 < 4 ? 1 : 2) : 0);
      if (mi != mj) v -= 100.f;
    }
  }
  bm[idx] = v;
}

// ---------------------------------------------------------------------------
// LN1 + roll(-3,-3) + window partition + prompt concat -> t (MWIN x 128) bf16
// ---------------------------------------------------------------------------
__global__ __launch_bounds__(256) void ln1_gather_kernel(
    const float* __restrict__ x, const float* __restrict__ prompts,
    const float* __restrict__ g, const float* __restrict__ bb,
    u16* __restrict__ t)
{
  const int tok  = blockIdx.x * 4 + (threadIdx.x >> 6);
  const int lane = threadIdx.x & 63;
  const int b_ = tok / NTOK, n = tok - b_ * NTOK;
  u32* dst = (u32*)(t + (size_t)tok * CH) + lane;
  if (n < PP) {
    const int b = b_ >> 6;
    const float2 v = *(const float2*)(prompts + ((size_t)b * PP + n) * CH + lane * 2);
    *dst = pack2(v.x, v.y);
    return;
  }
  const int w  = b_ & 63;
  const int wi = n - PP;
  const int hr = (w >> 3) * WSZ + wi / WSZ;
  const int wc = (w & 7) * WSZ + wi % WSZ;
  const int hs  = (hr + SSH) % HIMG;
  const int ws2 = (wc + SSH) % WIMG;
  const float2 v = *(const float2*)(x + ((size_t)(b_ >> 6) * (HIMG * WIMG) + hs * WIMG + ws2) * CH + lane * 2);
  float s = v.x + v.y, s2 = v.x * v.x + v.y * v.y;
  #pragma unroll
  for (int o = 32; o > 0; o >>= 1) { s += __shfl_xor(s, o); s2 += __shfl_xor(s2, o); }
  const float mean = s * (1.0f / CH);
  const float inv  = rsqrtf(s2 * (1.0f / CH) - mean * mean + 1e-5f);
  const float2 gg = *(const float2*)(g  + lane * 2);
  const float2 bv = *(const float2*)(bb + lane * 2);
  *dst = pack2((v.x - mean) * inv * gg.x + bv.x, (v.y - mean) * inv * gg.y + bv.y);
}

// ---------------------------------------------------------------------------
// MFMA bf16 GEMM, LDS-transpose epilogue.
//  - KTOT==128: single-stage (A 32KB + B 32KB LDS), one drain, 64 MFMAs.
//  - KTOT==512: BK=64 double-buffer with counted s_waitcnt vmcnt(8).
// Epilogue: acc -> LDS f32 [128][129] -> row-major re-read, vectorized IO.
// MODE 0: bf16 store (qkv)  MODE 2: exact GELU -> bf16 (fc1)
// MODE 1: window-reverse + residual -> f32 x1  AND fused LN2 -> bf16 mbuf
// MODE 3: + residual -> f32 (fc2 -> d_out)
// ---------------------------------------------------------------------------
template<int KTOT, int NCOLT, int MODE>
__global__ __launch_bounds__(256) void gemm_kernel(
    const u16* __restrict__ A, const u16* __restrict__ WT,
    const float* __restrict__ bias, const float* __restrict__ aux,
    const float* __restrict__ g2, const float* __restrict__ b2,
    float* __restrict__ outf, u16* __restrict__ outb)
{
  __shared__ __align__(16) char smem[66048];
  u16* sa = (u16*)smem;
  u16* sb = (u16*)(smem + 32768);
  float* T = (float*)smem;
  const int tid = threadIdx.x;
  const int wv = tid >> 6, lane = tid & 63;
  const int lr = lane & 15, lk = lane >> 4;
  const int wrow = wv >> 1, wcol = wv & 1;
  const long rowbase = (long)blockIdx.x * 128;
  const int colbase = blockIdx.y * 128;

  f32x4 acc[4][4];
  #pragma unroll
  for (int m = 0; m < 4; ++m)
    #pragma unroll
    for (int n = 0; n < 4; ++n)
      acc[m][n] = (f32x4){0.f, 0.f, 0.f, 0.f};

  if constexpr (KTOT == 128) {
    // ---- single stage: 2048 chunks/tile of 16B, swizzled source ----
    #pragma unroll
    for (int it = 0; it < 8; ++it) {
      const int c = it * 256 + tid;
      const int r = c >> 4, s = c & 15;
      const int k8 = s ^ (r & 15);
      __builtin_amdgcn_global_load_lds((const void*)(A + (rowbase + r) * 128 + k8 * 8),
                                       (void*)(sa + c * 8), 16, 0, 0);
      __builtin_amdgcn_global_load_lds((const void*)(WT + (long)(colbase + r) * 128 + k8 * 8),
                                       (void*)(sb + c * 8), 16, 0, 0);
    }
    __syncthreads();
    #pragma unroll
    for (int k32 = 0; k32 < 4; ++k32) {
      bf16x8 af[4], bfv[4];
      #pragma unroll
      for (int m = 0; m < 4; ++m) {
        const int r = wrow * 64 + m * 16 + lr;
        af[m] = *(const bf16x8*)(sa + r * 128 + (((k32 * 4 + lk) ^ (r & 15)) << 3));
      }
      #pragma unroll
      for (int n = 0; n < 4; ++n) {
        const int r = wcol * 64 + n * 16 + lr;
        bfv[n] = *(const bf16x8*)(sb + r * 128 + (((k32 * 4 + lk) ^ (r & 15)) << 3));
      }
      #pragma unroll
      for (int m = 0; m < 4; ++m)
        #pragma unroll
        for (int n = 0; n < 4; ++n)
          acc[m][n] = __builtin_amdgcn_mfma_f32_16x16x32_bf16(af[m], bfv[n], acc[m][n], 0, 0, 0);
    }
    __syncthreads();
  } else {
    // ---- K=512: BK=64, 2-deep double buffer, counted vmcnt ----
    auto stage = [&](int t, int pb) {
      #pragma unroll
      for (int it = 0; it < 4; ++it) {
        const int c = it * 256 + tid;
        const int r = c >> 3, s = c & 7;
        const int k8 = s ^ (r & 7);
        __builtin_amdgcn_global_load_lds((const void*)(A + (rowbase + r) * 512 + t * 64 + k8 * 8),
                                         (void*)(sa + pb * 8192 + c * 8), 16, 0, 0);
        __builtin_amdgcn_global_load_lds((const void*)(WT + (long)(colbase + r) * 512 + t * 64 + k8 * 8),
                                         (void*)(sb + pb * 8192 + c * 8), 16, 0, 0);
      }
    };
    stage(0, 0);
    for (int t = 0; t < 8; ++t) {
      if (t < 7) {
        stage(t + 1, (t + 1) & 1);
        asm volatile("s_waitcnt vmcnt(8)" ::: "memory");   // next tile's 8 loads stay in flight
      } else {
        asm volatile("s_waitcnt vmcnt(0)" ::: "memory");
      }
      __builtin_amdgcn_s_barrier();
      __builtin_amdgcn_sched_barrier(0);
      const u16* pa = sa + (t & 1) * 8192;
      const u16* pbuf = sb + (t & 1) * 8192;
      #pragma unroll
      for (int k32 = 0; k32 < 2; ++k32) {
        bf16x8 af[4], bfv[4];
        #pragma unroll
        for (int m = 0; m < 4; ++m) {
          const int r = wrow * 64 + m * 16 + lr;
          af[m] = *(const bf16x8*)(pa + r * 64 + (((k32 * 4 + lk) ^ (r & 7)) << 3));
        }
        #pragma unroll
        for (int n = 0; n < 4; ++n) {
          const int r = wcol * 64 + n * 16 + lr;
          bfv[n] = *(const bf16x8*)(pbuf + r * 64 + (((k32 * 4 + lk) ^ (r & 7)) << 3));
        }
        #pragma unroll
        for (int m = 0; m < 4; ++m)
          #pragma unroll
          for (int n = 0; n < 4; ++n)
            acc[m][n] = __builtin_amdgcn_mfma_f32_16x16x32_bf16(af[m], bfv[n], acc[m][n], 0, 0, 0);
      }
      __builtin_amdgcn_sched_barrier(0);
      __builtin_amdgcn_s_barrier();
    }
    __syncthreads();
  }

  // ---- transpose acc to LDS: T[row][col], stride 129 ----
  #pragma unroll
  for (int m = 0; m < 4; ++m)
    #pragma unroll
    for (int n = 0; n < 4; ++n)
      #pragma unroll
      for (int j = 0; j < 4; ++j)
        T[(wrow * 64 + m * 16 + lk * 4 + j) * 129 + wcol * 64 + n * 16 + lr] = acc[m][n][j];
  __syncthreads();

  // ---- row-major epilogue: thread = (row r, col-half h), 64 cols ----
  const int r = tid >> 1, h = tid & 1;
  const long grow = rowbase + r;
  const int c0 = colbase + h * 64;
  float4 vv[16];
  #pragma unroll
  for (int i = 0; i < 16; ++i) {
    float4 v = *(float4*)&T[r * 129 + h * 64 + i * 4];
    const float4 bs = *(const float4*)(bias + c0 + i * 4);
    v.x += bs.x; v.y += bs.y; v.z += bs.z; v.w += bs.w;
    vv[i] = v;
  }

  if (MODE == 0 || MODE == 2) {
    u16* orow = outb + grow * NCOLT + c0;
    #pragma unroll
    for (int i2 = 0; i2 < 8; ++i2) {
      float4 a = vv[2 * i2], b = vv[2 * i2 + 1];
      if (MODE == 2) {
        const float kq = 0.70710678118654752f;
        a.x = 0.5f * a.x * (1.f + erff(a.x * kq)); a.y = 0.5f * a.y * (1.f + erff(a.y * kq));
        a.z = 0.5f * a.z * (1.f + erff(a.z * kq)); a.w = 0.5f * a.w * (1.f + erff(a.w * kq));
        b.x = 0.5f * b.x * (1.f + erff(b.x * kq)); b.y = 0.5f * b.y * (1.f + erff(b.y * kq));
        b.z = 0.5f * b.z * (1.f + erff(b.z * kq)); b.w = 0.5f * b.w * (1.f + erff(b.w * kq));
      }
      uint4 pk;
      pk.x = pack2(a.x, a.y); pk.y = pack2(a.z, a.w);
      pk.z = pack2(b.x, b.y); pk.w = pack2(b.z, b.w);
      ((uint4*)orow)[i2] = pk;
    }
  } else if (MODE == 1) {
    // window-reverse: row -> pixel
    const int mi = (int)grow;
    const int b_ = mi / NWIN, wi = mi - b_ * NWIN;
    const int w  = b_ & 63;
    const int hr = (w >> 3) * WSZ + wi / WSZ;
    const int wc2 = (w & 7) * WSZ + wi % WSZ;
    const int hf = (hr + SSH) % HIMG;
    const int wf = (wc2 + SSH) % WIMG;
    const long pix = (long)(b_ >> 6) * (HIMG * WIMG) + hf * WIMG + wf;
    const float* arow = aux + pix * CH + h * 64;
    float* xrow = outf + pix * CH + h * 64;
    float sum = 0.f, sq = 0.f;
    #pragma unroll
    for (int i = 0; i < 16; ++i) {
      const float4 ax = *(const float4*)(arow + i * 4);
      float4 v = vv[i];
      v.x += ax.x; v.y += ax.y; v.z += ax.z; v.w += ax.w;
      vv[i] = v;
      *(float4*)(xrow + i * 4) = v;
      sum += v.x + v.y + v.z + v.w;
      sq  += v.x * v.x + v.y * v.y + v.z * v.z + v.w * v.w;
    }
    sum += __shfl_xor(sum, 1);
    sq  += __shfl_xor(sq, 1);
    const float mean = sum * (1.0f / CH);
    const float inv  = rsqrtf(sq * (1.0f / CH) - mean * mean + 1e-5f);
    u16* mrow = outb + pix * CH + h * 64;
    #pragma unroll
    for (int i2 = 0; i2 < 8; ++i2) {
      const float4 a = vv[2 * i2], b = vv[2 * i2 + 1];
      const float4 ga = *(const float4*)(g2 + h * 64 + i2 * 8);
      const float4 gb = *(const float4*)(g2 + h * 64 + i2 * 8 + 4);
      const float4 ba = *(const float4*)(b2 + h * 64 + i2 * 8);
      const float4 bb = *(const float4*)(b2 + h * 64 + i2 * 8 + 4);
      uint4 pk;
      pk.x = pack2((a.x - mean) * inv * ga.x + ba.x, (a.y - mean) * inv * ga.y + ba.y);
      pk.y = pack2((a.z - mean) * inv * ga.z + ba.z, (a.w - mean) * inv * ga.w + ba.w);
      pk.z = pack2((b.x - mean) * inv * gb.x + bb.x, (b.y - mean) * inv * gb.y + bb.y);
      pk.w = pack2((b.z - mean) * inv * gb.z + bb.z, (b.w - mean) * inv * gb.w + bb.w);
      ((uint4*)mrow)[i2] = pk;
    }
  } else {   // MODE 3: + x1 residual -> f32 d_out
    const float* arow = aux + grow * CH + h * 64;
    float* orow = outf + grow * CH + h * 64;
    #pragma unroll
    for (int i = 0; i < 16; ++i) {
      const float4 ax = *(const float4*)(arow + i * 4);
      float4 v = vv[i];
      v.x += ax.x; v.y += ax.y; v.z += ax.z; v.w += ax.w;
      *(float4*)(orow + i * 4) = v;
    }
  }
}

// ---------------------------------------------------------------------------
// MFMA window attention (validated R4). One block = one window; wave = head.
// ---------------------------------------------------------------------------
__global__ __launch_bounds__(256) void attn_mfma_kernel(
    const u16* __restrict__ qkv, const float* __restrict__ bm,
    u16* __restrict__ attn_out)
{
  __shared__ u16 s_lds[NHEADS][64][SLDS];
  const int tid  = threadIdx.x;
  const int h    = tid >> 6, lane = tid & 63;
  const int lr   = lane & 15, lk = lane >> 4;
  const int b_   = blockIdx.x;
  const u16* base = qkv + (size_t)b_ * NTOK * 384;
  const int w    = b_ & 63;
  const int type = (((w >> 3) == 7) ? 2 : 0) + (((w & 7) == 7) ? 1 : 0);
  const float scale = 0.17677669529663687f;   // 32^-0.5

  bf16x8 kf[4], qf[4];
  #pragma unroll
  for (int t4 = 0; t4 < 4; ++t4) {
    int tj = t4 * 16 + lr; if (tj > 58) tj = 58;
    kf[t4] = *(const bf16x8*)(base + (size_t)tj * 384 + 128 + h * DH + lk * 8);
    int ti = PP + t4 * 16 + lr; if (ti > 58) ti = 58;
    qf[t4] = *(const bf16x8*)(base + (size_t)ti * 384 + h * DH + lk * 8);
  }
  f32x4 sacc[4][4];
  #pragma unroll
  for (int a = 0; a < 4; ++a)
    #pragma unroll
    for (int b = 0; b < 4; ++b)
      sacc[a][b] = (f32x4){0.f, 0.f, 0.f, 0.f};
  #pragma unroll
  for (int mtj = 0; mtj < 4; ++mtj)
    #pragma unroll
    for (int nti = 0; nti < 4; ++nti)
      sacc[mtj][nti] = __builtin_amdgcn_mfma_f32_16x16x32_bf16(kf[mtj], qf[nti], sacc[mtj][nti], 0, 0, 0);

  const float* bmh = bm + (size_t)(type * NHEADS + h) * 64 * 64;
  #pragma unroll
  for (int nti = 0; nti < 4; ++nti) {
    const int i = nti * 16 + lr;
    float sv[16];
    #pragma unroll
    for (int mtj = 0; mtj < 4; ++mtj) {
      const float4 bmv = *(const float4*)(bmh + i * 64 + mtj * 16 + lk * 4);
      sv[mtj * 4 + 0] = sacc[mtj][nti][0] * scale + bmv.x;
      sv[mtj * 4 + 1] = sacc[mtj][nti][1] * scale + bmv.y;
      sv[mtj * 4 + 2] = sacc[mtj][nti][2] * scale + bmv.z;
      sv[mtj * 4 + 3] = sacc[mtj][nti][3] * scale + bmv.w;
    }
    float mx = sv[0];
    #pragma unroll
    for (int t = 1; t < 16; ++t) mx = fmaxf(mx, sv[t]);
    mx = fmaxf(mx, __shfl_xor(mx, 16));
    mx = fmaxf(mx, __shfl_xor(mx, 32));
    float sum = 0.f;
    #pragma unroll
    for (int t = 0; t < 16; ++t) { sv[t] = __expf(sv[t] - mx); sum += sv[t]; }
    sum += __shfl_xor(sum, 16);
    sum += __shfl_xor(sum, 32);
    const float inv = 1.0f / sum;
    #pragma unroll
    for (int mtj = 0; mtj < 4; ++mtj) {
      const ushort4 pk = make_ushort4(f2b(sv[mtj * 4 + 0] * inv), f2b(sv[mtj * 4 + 1] * inv),
                                      f2b(sv[mtj * 4 + 2] * inv), f2b(sv[mtj * 4 + 3] * inv));
      *(ushort4*)&s_lds[h][i][mtj * 16 + lk * 4] = pk;
    }
  }
  __syncthreads();

  f32x4 oacc[4][2];
  #pragma unroll
  for (int a = 0; a < 4; ++a) { oacc[a][0] = (f32x4){0,0,0,0}; oacc[a][1] = (f32x4){0,0,0,0}; }
  #pragma unroll
  for (int ks = 0; ks < 2; ++ks) {
    bf16x8 pa[4];
    #pragma unroll
    for (int mt = 0; mt < 4; ++mt) {
      const u16* pr = &s_lds[h][mt * 16 + lr][ks * 32 + lk * 8];
      const bf16x4 lo = *(const bf16x4*)pr;
      const bf16x4 hi = *(const bf16x4*)(pr + 4);
      pa[mt] = __builtin_shufflevector(lo, hi, 0, 1, 2, 3, 4, 5, 6, 7);
    }
    bf16x8 bv[2];
    #pragma unroll
    for (int nd = 0; nd < 2; ++nd) {
      const u16* vb = base + 256 + h * DH + nd * 16 + lr;
      #pragma unroll
      for (int jj = 0; jj < 8; ++jj) {
        int jc = ks * 32 + lk * 8 + jj; if (jc > 58) jc = 58;
        bv[nd][jj] = (short)vb[(size_t)jc * 384];
      }
    }
    #pragma unroll
    for (int mt = 0; mt < 4; ++mt)
      #pragma unroll
      for (int nd = 0; nd < 2; ++nd)
        oacc[mt][nd] = __builtin_amdgcn_mfma_f32_16x16x32_bf16(pa[mt], bv[nd], oacc[mt][nd], 0, 0, 0);
  }

  #pragma unroll
  for (int mt = 0; mt < 4; ++mt)
    #pragma unroll
    for (int reg = 0; reg < 4; ++reg) {
      const int i = mt * 16 + lk * 4 + reg;
      if (i < 49) {
        u16* dst = attn_out + ((size_t)b_ * NWIN + i) * CH + h * DH + lr;
        dst[0]  = f2b(oacc[mt][0][reg]);
        dst[16] = f2b(oacc[mt][1][reg]);
      }
    }
}

// ---------------------------------------------------------------------------
extern "C" void kernel_launch(void* const* d_in, const int* in_sizes, int n_in,
                              void* d_out, int out_size, void* d_ws, size_t ws_size,
                              hipStream_t stream)
{
  const float* x       = (const float*)d_in[0];
  const float* prompts = (const float*)d_in[1];
  const float* n1g     = (const float*)d_in[2];
  const float* n1b     = (const float*)d_in[3];
  const float* qkv_w   = (const float*)d_in[4];
  const float* qkv_b   = (const float*)d_in[5];
  const float* qkv_la  = (const float*)d_in[6];
  const float* qkv_lb  = (const float*)d_in[7];
  const float* rpb     = (const float*)d_in[8];
  const float* proj_w  = (const float*)d_in[9];
  const float* proj_b  = (const float*)d_in[10];
  const float* proj_la = (const float*)d_in[11];
  const float* proj_lb = (const float*)d_in[12];
  const float* n2g     = (const float*)d_in[13];
  const float* n2b     = (const float*)d_in[14];
  const float* fc1_w   = (const float*)d_in[15];
  const float* fc1_b   = (const float*)d_in[16];
  const float* fc1_la  = (const float*)d_in[17];
  const float* fc1_lb  = (const float*)d_in[18];
  const float* fc2_w   = (const float*)d_in[19];
  const float* fc2_b   = (const float*)d_in[20];
  const float* fc2_la  = (const float*)d_in[21];
  const float* fc2_lb  = (const float*)d_in[22];

  // workspace: [wT bf16 196608 | bm f32 65536] | regA | regB | regC
  //  regA: tbuf (30.9MB) -> aobuf (25.7MB)
  //  regB: qkvbuf (92.8MB) -> { x1 (51.4MB) | mbuf (25.7MB) }
  //  regC: hbuf (102.8MB)
  char* ws = (char*)d_ws;
  u16* wT     = (u16*)ws;
  u16* wqkvT  = wT;
  u16* wprojT = wT + 49152;
  u16* wfc1T  = wT + 65536;
  u16* wfc2T  = wT + 131072;
  float* bm   = (float*)(ws + 393216);
  char* regA = ws + 393216 + 262144;
  u16* tbuf   = (u16*)regA;          // MWIN*128 bf16
  u16* aobuf  = (u16*)regA;          // MPIX*128 bf16
  char* regB = regA + (size_t)MWIN * CH * 2;
  u16*   qkvbuf = (u16*)regB;        // MWIN*384 bf16
  float* x1buf  = (float*)regB;      // MPIX*128 f32
  u16*   mbuf   = (u16*)(regB + (size_t)MPIX * CH * 4);  // MPIX*128 bf16
  char* regC = regB + (size_t)MWIN * 384 * 2;
  u16* hbuf = (u16*)regC;            // MPIX*512 bf16

  fuse_all_kernel<<<768, 256, 0, stream>>>(
      qkv_w, qkv_la, qkv_lb, proj_w, proj_la, proj_lb,
      fc1_w, fc1_la, fc1_lb, fc2_w, fc2_la, fc2_lb, wT);

  bm_kernel<<<256, 256, 0, stream>>>(rpb, bm);

  ln1_gather_kernel<<<MWIN / 4, 256, 0, stream>>>(x, prompts, n1g, n1b, tbuf);

  gemm_kernel<128, 384, 0><<<dim3(MWIN / 128, 3), 256, 0, stream>>>(
      tbuf, wqkvT, qkv_b, nullptr, nullptr, nullptr, nullptr, qkvbuf);

  attn_mfma_kernel<<<BWIN, 256, 0, stream>>>(qkvbuf, bm, aobuf);

  gemm_kernel<128, 128, 1><<<dim3(MPIX / 128, 1), 256, 0, stream>>>(
      aobuf, wprojT, proj_b, x, n2g, n2b, x1buf, mbuf);

  gemm_kernel<128, 512, 2><<<dim3(MPIX / 128, 4), 256, 0, stream>>>(
      mbuf, wfc1T, fc1_b, nullptr, nullptr, nullptr, nullptr, hbuf);

  gemm_kernel<512, 128, 3><<<dim3(MPIX / 128, 1), 256, 0, stream>>>(
      hbuf, wfc2T, fc2_b, x1buf, nullptr, nullptr, (float*)d_out, nullptr);
}

// Round 6
// 267.646 us; speedup vs baseline: 1.1573x; 1.1573x over previous
//
#include <hip/hip_runtime.h>

typedef unsigned short u16;
typedef unsigned int   u32;
typedef short bf16x8 __attribute__((ext_vector_type(8)));
typedef short bf16x4 __attribute__((ext_vector_type(4)));
typedef float f32x4  __attribute__((ext_vector_type(4)));

#define HIMG 56
#define WIMG 56
#define CH   128
#define NHEADS 4
#define WSZ  7
#define SSH  3
#define PP   10
#define HIDD 512
#define NWIN 49          // window tokens
#define NTOK 59          // P + NWIN
#define BWIN 2048        // B * NW
#define DH   32          // head dim
#define MWIN 120832      // BWIN * NTOK
#define MPIX 100352      // B * 56 * 56
#define SLDS 68          // padded u16 stride for attn P/O tile

__device__ __forceinline__ u16 f2b(float f) {
  u32 u = __float_as_uint(f);
  u += 0x7fffu + ((u >> 16) & 1u);
  return (u16)(u >> 16);
}
__device__ __forceinline__ u32 pack2(float a, float b) {
  return (u32)f2b(a) | ((u32)f2b(b) << 16);
}

// ---------------------------------------------------------------------------
// Fold LoRA into effective weights, store TRANSPOSED bf16 (K-contiguous).
// ---------------------------------------------------------------------------
__global__ void fuse_all_kernel(
    const float* __restrict__ qw,  const float* __restrict__ qa,  const float* __restrict__ qb,
    const float* __restrict__ pw,  const float* __restrict__ pa,  const float* __restrict__ pb,
    const float* __restrict__ f1w, const float* __restrict__ f1a, const float* __restrict__ f1b,
    const float* __restrict__ f2w, const float* __restrict__ f2a, const float* __restrict__ f2b2,
    u16* __restrict__ out)
{
  int idx = blockIdx.x * 256 + threadIdx.x;
  if (idx >= 196608) return;
  const float *w, *la, *lb; int Nc, K, base;
  if (idx < 49152)       { w = qw;  la = qa;  lb = qb;   Nc = 384; K = 128; base = 0; }
  else if (idx < 65536)  { w = pw;  la = pa;  lb = pb;   Nc = 128; K = 128; base = 49152; }
  else if (idx < 131072) { w = f1w; la = f1a; lb = f1b;  Nc = 512; K = 128; base = 65536; }
  else                   { w = f2w; la = f2a; lb = f2b2; Nc = 128; K = 512; base = 131072; }
  const int li = idx - base;
  const int k = li / Nc, n = li - k * Nc;
  float s = w[li];
  #pragma unroll
  for (int r = 0; r < 4; ++r) s += la[k * 4 + r] * lb[r * Nc + n];
  out[base + n * K + k] = f2b(s);
}

// ---------------------------------------------------------------------------
// Precompute bias+mask table bm[type][h][64][64] f32.
// ---------------------------------------------------------------------------
__global__ void bm_kernel(const float* __restrict__ rpb, float* __restrict__ bm)
{
  const int idx = blockIdx.x * 256 + threadIdx.x;   // 65536
  const int j = idx & 63, i = (idx >> 6) & 63, h = (idx >> 12) & 3, type = idx >> 14;
  float v = 0.f;
  if (i < 49) {
    if (j >= 59) v = -1e30f;
    else if (j >= PP) {
      const int jw = j - PP;
      const int ih = i / 7, iw = i - ih * 7, jh = jw / 7, jw2 = jw - jh * 7;
      v = rpb[((ih - jh + 6) * 13 + (iw - jw2 + 6)) * NHEADS + h];
      const int wh7 = type >> 1, ww7 = type & 1;
      const int mi = 3 * (wh7 ? (ih < 4 ? 1 : 2) : 0) + (ww7 ? (iw < 4 ? 1 : 2) : 0);
      const int mj = 3 * (wh7 ? (jh < 4 ? 1 : 2) : 0) + (ww7 ? (jw2 < 4 ? 1 : 2) : 0);
      if (mi != mj) v -= 100.f;
    }
  }
  bm[idx] = v;
}

// ---------------------------------------------------------------------------
// LN1 + roll(-3,-3) + window partition + prompt concat -> t (MWIN x 128) bf16
// ---------------------------------------------------------------------------
__global__ __launch_bounds__(256) void ln1_gather_kernel(
    const float* __restrict__ x, const float* __restrict__ prompts,
    const float* __restrict__ g, const float* __restrict__ bb,
    u16* __restrict__ t)
{
  const int tok  = blockIdx.x * 4 + (threadIdx.x >> 6);
  const int lane = threadIdx.x & 63;
  const int b_ = tok / NTOK, n = tok - b_ * NTOK;
  u32* dst = (u32*)(t + (size_t)tok * CH) + lane;
  if (n < PP) {
    const int b = b_ >> 6;
    const float2 v = *(const float2*)(prompts + ((size_t)b * PP + n) * CH + lane * 2);
    *dst = pack2(v.x, v.y);
    return;
  }
  const int w  = b_ & 63;
  const int wi = n - PP;
  const int hr = (w >> 3) * WSZ + wi / WSZ;
  const int wc = (w & 7) * WSZ + wi % WSZ;
  const int hs  = (hr + SSH) % HIMG;
  const int ws2 = (wc + SSH) % WIMG;
  const float2 v = *(const float2*)(x + ((size_t)(b_ >> 6) * (HIMG * WIMG) + hs * WIMG + ws2) * CH + lane * 2);
  float s = v.x + v.y, s2 = v.x * v.x + v.y * v.y;
  #pragma unroll
  for (int o = 32; o > 0; o >>= 1) { s += __shfl_xor(s, o); s2 += __shfl_xor(s2, o); }
  const float mean = s * (1.0f / CH);
  const float inv  = rsqrtf(s2 * (1.0f / CH) - mean * mean + 1e-5f);
  const float2 gg = *(const float2*)(g  + lane * 2);
  const float2 bv = *(const float2*)(bb + lane * 2);
  *dst = pack2((v.x - mean) * inv * gg.x + bv.x, (v.y - mean) * inv * gg.y + bv.y);
}

// ---------------------------------------------------------------------------
// MFMA bf16 GEMM (R4-proven loop: BK=64, 32KB staging, 2 barriers/step) with
// compact LDS-transpose epilogue (overlaid on staging buffers, 34.8 KB max):
//   MODE 0/2 (bf16 out): u16 tile [128][136]; per-thread 128B contig stores.
//   MODE 1/3 (f32 out):  f32 tile [64][132], two 64-row chunks; quad-coalesced.
// MODE 0: qkv store   MODE 2: exact GELU (fc1)
// MODE 1: window-reverse + residual -> f32 x1 AND fused LN2 -> bf16 mbuf
// MODE 3: + residual -> f32 (fc2 -> d_out)
// ---------------------------------------------------------------------------
template<int KTOT, int NCOLT, int MODE>
__global__ __launch_bounds__(256, 4) void gemm_kernel(
    const u16* __restrict__ A, const u16* __restrict__ WT,
    const float* __restrict__ bias, const float* __restrict__ aux,
    const float* __restrict__ g2, const float* __restrict__ b2,
    float* __restrict__ outf, u16* __restrict__ outb)
{
  __shared__ __align__(16) char smem[34816];
  u16* sa = (u16*)smem;                 // [128][64] bf16, 16 KB
  u16* sb = (u16*)(smem + 16384);       // [128][64] bf16, 16 KB
  const int tid = threadIdx.x;
  const int wv = tid >> 6, lane = tid & 63;
  const int lr = lane & 15, lk = lane >> 4;
  const int wrow = wv >> 1, wcol = wv & 1;
  const long rowbase = (long)blockIdx.x * 128;
  const int colbase = blockIdx.y * 128;

  f32x4 acc[4][4];
  #pragma unroll
  for (int m = 0; m < 4; ++m)
    #pragma unroll
    for (int n = 0; n < 4; ++n)
      acc[m][n] = (f32x4){0.f, 0.f, 0.f, 0.f};

  for (int kb = 0; kb < KTOT; kb += 64) {
    #pragma unroll
    for (int it = 0; it < 4; ++it) {
      const int c = wv * 256 + it * 64 + lane;
      const int r = c >> 3, s = c & 7;
      const int k8 = s ^ (r & 7);
      __builtin_amdgcn_global_load_lds((const void*)(A + (rowbase + r) * KTOT + kb + k8 * 8),
                                       (void*)(sa + c * 8), 16, 0, 0);
      __builtin_amdgcn_global_load_lds((const void*)(WT + (long)(colbase + r) * KTOT + kb + k8 * 8),
                                       (void*)(sb + c * 8), 16, 0, 0);
    }
    __syncthreads();
    const char* la = (const char*)sa;
    const char* lb = (const char*)sb;
    #pragma unroll
    for (int k32 = 0; k32 < 2; ++k32) {
      bf16x8 af[4], bfv[4];
      #pragma unroll
      for (int m = 0; m < 4; ++m) {
        const int r = wrow * 64 + m * 16 + lr;
        af[m] = *(const bf16x8*)(la + r * 128 + (((k32 * 4 + lk) ^ (r & 7)) << 4));
      }
      #pragma unroll
      for (int n = 0; n < 4; ++n) {
        const int r = wcol * 64 + n * 16 + lr;
        bfv[n] = *(const bf16x8*)(lb + r * 128 + (((k32 * 4 + lk) ^ (r & 7)) << 4));
      }
      #pragma unroll
      for (int m = 0; m < 4; ++m)
        #pragma unroll
        for (int n = 0; n < 4; ++n)
          acc[m][n] = __builtin_amdgcn_mfma_f32_16x16x32_bf16(af[m], bfv[n], acc[m][n], 0, 0, 0);
    }
    __syncthreads();
  }

  if (MODE == 0 || MODE == 2) {
    // ---- bf16 transpose epilogue: u16 tile [128][136] ----
    u16* T16 = (u16*)smem;
    #pragma unroll
    for (int n = 0; n < 4; ++n) {
      const int col = wcol * 64 + n * 16 + lr;
      const float bs = bias[colbase + col];
      #pragma unroll
      for (int m = 0; m < 4; ++m) {
        #pragma unroll
        for (int j = 0; j < 4; ++j) {
          float v = acc[m][n][j] + bs;
          if (MODE == 2) v = 0.5f * v * (1.f + erff(v * 0.70710678118654752f));
          T16[(wrow * 64 + m * 16 + lk * 4 + j) * 136 + col] = f2b(v);
        }
      }
    }
    __syncthreads();
    const int r = tid >> 1, h = tid & 1;
    u16* orow = outb + (rowbase + r) * NCOLT + colbase + h * 64;
    const u16* trow = T16 + r * 136 + h * 64;
    #pragma unroll
    for (int i = 0; i < 8; ++i)
      ((uint4*)orow)[i] = *(const uint4*)(trow + i * 8);
  } else {
    // ---- f32 transpose epilogue: [64][132] in two 64-row chunks ----
    float* T32 = (float*)smem;
    #pragma unroll
    for (int ch = 0; ch < 2; ++ch) {
      if (wrow == ch) {
        #pragma unroll
        for (int n = 0; n < 4; ++n) {
          const int col = wcol * 64 + n * 16 + lr;
          const float bs = bias[colbase + col];
          #pragma unroll
          for (int m = 0; m < 4; ++m)
            #pragma unroll
            for (int j = 0; j < 4; ++j)
              T32[(m * 16 + lk * 4 + j) * 132 + col] = acc[m][n][j] + bs;
        }
      }
      __syncthreads();
      const int rl = tid >> 2, q = tid & 3;       // 64 rows x 4 quads of 32 cols
      const long grow = rowbase + ch * 64 + rl;
      float4 v[8];
      #pragma unroll
      for (int i = 0; i < 8; ++i)
        v[i] = *(const float4*)&T32[rl * 132 + q * 4 + i * 16];   // col = q*4+i*16
      if (MODE == 3) {
        const float* arow = aux + grow * CH;
        float* orow = outf + grow * CH;
        #pragma unroll
        for (int i = 0; i < 8; ++i) {
          const float4 ax = *(const float4*)(arow + q * 4 + i * 16);
          float4 t = v[i];
          t.x += ax.x; t.y += ax.y; t.z += ax.z; t.w += ax.w;
          *(float4*)(orow + q * 4 + i * 16) = t;
        }
      } else {
        // MODE 1: window-reverse + residual + fused LN2
        const int mi = (int)grow;
        const int b_ = mi / NWIN, wi = mi - b_ * NWIN;
        const int w  = b_ & 63;
        const int hr = (w >> 3) * WSZ + wi / WSZ;
        const int wc2 = (w & 7) * WSZ + wi % WSZ;
        const int hf = (hr + SSH) % HIMG;
        const int wf = (wc2 + SSH) % WIMG;
        const long pix = (long)(b_ >> 6) * (HIMG * WIMG) + hf * WIMG + wf;
        const float* arow = aux + pix * CH;
        float* xrow = outf + pix * CH;
        float sum = 0.f, sq = 0.f;
        #pragma unroll
        for (int i = 0; i < 8; ++i) {
          const float4 ax = *(const float4*)(arow + q * 4 + i * 16);
          float4 t = v[i];
          t.x += ax.x; t.y += ax.y; t.z += ax.z; t.w += ax.w;
          v[i] = t;
          *(float4*)(xrow + q * 4 + i * 16) = t;
          sum += t.x + t.y + t.z + t.w;
          sq  += t.x * t.x + t.y * t.y + t.z * t.z + t.w * t.w;
        }
        sum += __shfl_xor(sum, 1); sq += __shfl_xor(sq, 1);
        sum += __shfl_xor(sum, 2); sq += __shfl_xor(sq, 2);
        const float mean = sum * (1.0f / CH);
        const float inv  = rsqrtf(sq * (1.0f / CH) - mean * mean + 1e-5f);
        u16* mrow = outb + pix * CH;
        #pragma unroll
        for (int i2 = 0; i2 < 4; ++i2) {
          const float4 a = v[2 * i2], b = v[2 * i2 + 1];
          const float4 ga = *(const float4*)(g2 + q * 4 + (2 * i2) * 16);
          const float4 gb = *(const float4*)(g2 + q * 4 + (2 * i2 + 1) * 16);
          const float4 ba = *(const float4*)(b2 + q * 4 + (2 * i2) * 16);
          const float4 bb = *(const float4*)(b2 + q * 4 + (2 * i2 + 1) * 16);
          uint2 pkA, pkB;
          pkA.x = pack2((a.x - mean) * inv * ga.x + ba.x, (a.y - mean) * inv * ga.y + ba.y);
          pkA.y = pack2((a.z - mean) * inv * ga.z + ba.z, (a.w - mean) * inv * ga.w + ba.w);
          pkB.x = pack2((b.x - mean) * inv * gb.x + bb.x, (b.y - mean) * inv * gb.y + bb.y);
          pkB.y = pack2((b.z - mean) * inv * gb.z + bb.z, (b.w - mean) * inv * gb.w + bb.w);
          *(uint2*)(mrow + q * 4 + (2 * i2) * 16) = pkA;
          *(uint2*)(mrow + q * 4 + (2 * i2 + 1) * 16) = pkB;
        }
      }
      if (ch == 0) __syncthreads();
    }
  }
}

// ---------------------------------------------------------------------------
// MFMA window attention (R4-proven math). One block = one window; wave = head.
// New: O routed through s_lds -> 64B-contiguous coalesced stores.
// ---------------------------------------------------------------------------
__global__ __launch_bounds__(256) void attn_mfma_kernel(
    const u16* __restrict__ qkv, const float* __restrict__ bm,
    u16* __restrict__ attn_out)
{
  __shared__ u16 s_lds[NHEADS][64][SLDS];
  const int tid  = threadIdx.x;
  const int h    = tid >> 6, lane = tid & 63;
  const int lr   = lane & 15, lk = lane >> 4;
  const int b_   = blockIdx.x;
  const u16* base = qkv + (size_t)b_ * NTOK * 384;
  const int w    = b_ & 63;
  const int type = (((w >> 3) == 7) ? 2 : 0) + (((w & 7) == 7) ? 1 : 0);
  const float scale = 0.17677669529663687f;   // 32^-0.5

  bf16x8 kf[4], qf[4];
  #pragma unroll
  for (int t4 = 0; t4 < 4; ++t4) {
    int tj = t4 * 16 + lr; if (tj > 58) tj = 58;
    kf[t4] = *(const bf16x8*)(base + (size_t)tj * 384 + 128 + h * DH + lk * 8);
    int ti = PP + t4 * 16 + lr; if (ti > 58) ti = 58;
    qf[t4] = *(const bf16x8*)(base + (size_t)ti * 384 + h * DH + lk * 8);
  }
  f32x4 sacc[4][4];
  #pragma unroll
  for (int a = 0; a < 4; ++a)
    #pragma unroll
    for (int b = 0; b < 4; ++b)
      sacc[a][b] = (f32x4){0.f, 0.f, 0.f, 0.f};
  #pragma unroll
  for (int mtj = 0; mtj < 4; ++mtj)
    #pragma unroll
    for (int nti = 0; nti < 4; ++nti)
      sacc[mtj][nti] = __builtin_amdgcn_mfma_f32_16x16x32_bf16(kf[mtj], qf[nti], sacc[mtj][nti], 0, 0, 0);

  const float* bmh = bm + (size_t)(type * NHEADS + h) * 64 * 64;
  #pragma unroll
  for (int nti = 0; nti < 4; ++nti) {
    const int i = nti * 16 + lr;
    float sv[16];
    #pragma unroll
    for (int mtj = 0; mtj < 4; ++mtj) {
      const float4 bmv = *(const float4*)(bmh + i * 64 + mtj * 16 + lk * 4);
      sv[mtj * 4 + 0] = sacc[mtj][nti][0] * scale + bmv.x;
      sv[mtj * 4 + 1] = sacc[mtj][nti][1] * scale + bmv.y;
      sv[mtj * 4 + 2] = sacc[mtj][nti][2] * scale + bmv.z;
      sv[mtj * 4 + 3] = sacc[mtj][nti][3] * scale + bmv.w;
    }
    float mx = sv[0];
    #pragma unroll
    for (int t = 1; t < 16; ++t) mx = fmaxf(mx, sv[t]);
    mx = fmaxf(mx, __shfl_xor(mx, 16));
    mx = fmaxf(mx, __shfl_xor(mx, 32));
    float sum = 0.f;
    #pragma unroll
    for (int t = 0; t < 16; ++t) { sv[t] = __expf(sv[t] - mx); sum += sv[t]; }
    sum += __shfl_xor(sum, 16);
    sum += __shfl_xor(sum, 32);
    const float inv = 1.0f / sum;
    #pragma unroll
    for (int mtj = 0; mtj < 4; ++mtj) {
      const ushort4 pk = make_ushort4(f2b(sv[mtj * 4 + 0] * inv), f2b(sv[mtj * 4 + 1] * inv),
                                      f2b(sv[mtj * 4 + 2] * inv), f2b(sv[mtj * 4 + 3] * inv));
      *(ushort4*)&s_lds[h][i][mtj * 16 + lk * 4] = pk;
    }
  }
  __syncthreads();

  f32x4 oacc[4][2];
  #pragma unroll
  for (int a = 0; a < 4; ++a) { oacc[a][0] = (f32x4){0,0,0,0}; oacc[a][1] = (f32x4){0,0,0,0}; }
  #pragma unroll
  for (int ks = 0; ks < 2; ++ks) {
    bf16x8 pa[4];
    #pragma unroll
    for (int mt = 0; mt < 4; ++mt) {
      const u16* pr = &s_lds[h][mt * 16 + lr][ks * 32 + lk * 8];
      const bf16x4 lo = *(const bf16x4*)pr;
      const bf16x4 hi = *(const bf16x4*)(pr + 4);
      pa[mt] = __builtin_shufflevector(lo, hi, 0, 1, 2, 3, 4, 5, 6, 7);
    }
    bf16x8 bv[2];
    #pragma unroll
    for (int nd = 0; nd < 2; ++nd) {
      const u16* vb = base + 256 + h * DH + nd * 16 + lr;
      #pragma unroll
      for (int jj = 0; jj < 8; ++jj) {
        int jc = ks * 32 + lk * 8 + jj; if (jc > 58) jc = 58;
        bv[nd][jj] = (short)vb[(size_t)jc * 384];
      }
    }
    #pragma unroll
    for (int mt = 0; mt < 4; ++mt)
      #pragma unroll
      for (int nd = 0; nd < 2; ++nd)
        oacc[mt][nd] = __builtin_amdgcn_mfma_f32_16x16x32_bf16(pa[mt], bv[nd], oacc[mt][nd], 0, 0, 0);
  }

  // ---- O -> own LDS plane (reads of P in this wave's plane are complete) ----
  #pragma unroll
  for (int mt = 0; mt < 4; ++mt)
    #pragma unroll
    for (int reg = 0; reg < 4; ++reg) {
      const int i = mt * 16 + lk * 4 + reg;
      s_lds[h][i][lr]      = f2b(oacc[mt][0][reg]);
      s_lds[h][i][16 + lr] = f2b(oacc[mt][1][reg]);
    }
  __syncthreads();

  // ---- coalesced store: wave h stores head h, lane = row i ----
  {
    const int i = lane;
    if (i < NWIN) {
      const u16* src = &s_lds[h][i][0];
      u16* dst = attn_out + ((size_t)b_ * NWIN + i) * CH + h * DH;
      #pragma unroll
      for (int c = 0; c < 8; ++c)
        *(uint2*)(dst + c * 4) = *(const uint2*)(src + c * 4);
    }
  }
}

// ---------------------------------------------------------------------------
extern "C" void kernel_launch(void* const* d_in, const int* in_sizes, int n_in,
                              void* d_out, int out_size, void* d_ws, size_t ws_size,
                              hipStream_t stream)
{
  const float* x       = (const float*)d_in[0];
  const float* prompts = (const float*)d_in[1];
  const float* n1g     = (const float*)d_in[2];
  const float* n1b     = (const float*)d_in[3];
  const float* qkv_w   = (const float*)d_in[4];
  const float* qkv_b   = (const float*)d_in[5];
  const float* qkv_la  = (const float*)d_in[6];
  const float* qkv_lb  = (const float*)d_in[7];
  const float* rpb     = (const float*)d_in[8];
  const float* proj_w  = (const float*)d_in[9];
  const float* proj_b  = (const float*)d_in[10];
  const float* proj_la = (const float*)d_in[11];
  const float* proj_lb = (const float*)d_in[12];
  const float* n2g     = (const float*)d_in[13];
  const float* n2b     = (const float*)d_in[14];
  const float* fc1_w   = (const float*)d_in[15];
  const float* fc1_b   = (const float*)d_in[16];
  const float* fc1_la  = (const float*)d_in[17];
  const float* fc1_lb  = (const float*)d_in[18];
  const float* fc2_w   = (const float*)d_in[19];
  const float* fc2_b   = (const float*)d_in[20];
  const float* fc2_la  = (const float*)d_in[21];
  const float* fc2_lb  = (const float*)d_in[22];

  // workspace: [wT bf16 196608 | bm f32 65536] | regA | regB | regC
  char* ws = (char*)d_ws;
  u16* wT     = (u16*)ws;
  u16* wqkvT  = wT;
  u16* wprojT = wT + 49152;
  u16* wfc1T  = wT + 65536;
  u16* wfc2T  = wT + 131072;
  float* bm   = (float*)(ws + 393216);
  char* regA = ws + 393216 + 262144;
  u16* tbuf   = (u16*)regA;          // MWIN*128 bf16
  u16* aobuf  = (u16*)regA;          // MPIX*128 bf16
  char* regB = regA + (size_t)MWIN * CH * 2;
  u16*   qkvbuf = (u16*)regB;        // MWIN*384 bf16
  float* x1buf  = (float*)regB;      // MPIX*128 f32
  u16*   mbuf   = (u16*)(regB + (size_t)MPIX * CH * 4);  // MPIX*128 bf16
  char* regC = regB + (size_t)MWIN * 384 * 2;
  u16* hbuf = (u16*)regC;            // MPIX*512 bf16

  fuse_all_kernel<<<768, 256, 0, stream>>>(
      qkv_w, qkv_la, qkv_lb, proj_w, proj_la, proj_lb,
      fc1_w, fc1_la, fc1_lb, fc2_w, fc2_la, fc2_lb, wT);

  bm_kernel<<<256, 256, 0, stream>>>(rpb, bm);

  ln1_gather_kernel<<<MWIN / 4, 256, 0, stream>>>(x, prompts, n1g, n1b, tbuf);

  gemm_kernel<128, 384, 0><<<dim3(MWIN / 128, 3), 256, 0, stream>>>(
      tbuf, wqkvT, qkv_b, nullptr, nullptr, nullptr, nullptr, qkvbuf);

  attn_mfma_kernel<<<BWIN, 256, 0, stream>>>(qkvbuf, bm, aobuf);

  gemm_kernel<128, 128, 1><<<dim3(MPIX / 128, 1), 256, 0, stream>>>(
      aobuf, wprojT, proj_b, x, n2g, n2b, x1buf, mbuf);

  gemm_kernel<128, 512, 2><<<dim3(MPIX / 128, 4), 256, 0, stream>>>(
      mbuf, wfc1T, fc1_b, nullptr, nullptr, nullptr, nullptr, hbuf);

  gemm_kernel<512, 128, 3><<<dim3(MPIX / 128, 1), 256, 0, stream>>>(
      hbuf, wfc2T, fc2_b, x1buf, nullptr, nullptr, (float*)d_out, nullptr);
}

// Round 7
// 246.496 us; speedup vs baseline: 1.2566x; 1.0858x over previous
//
#include <hip/hip_runtime.h>

typedef unsigned short u16;
typedef unsigned int   u32;
typedef short bf16x8 __attribute__((ext_vector_type(8)));
typedef short bf16x4 __attribute__((ext_vector_type(4)));
typedef float f32x4  __attribute__((ext_vector_type(4)));

#define HIMG 56
#define WIMG 56
#define CH   128
#define NHEADS 4
#define WSZ  7
#define SSH  3
#define PP   10
#define HIDD 512
#define NWIN 49          // window tokens
#define NTOK 59          // P + NWIN
#define BWIN 2048        // B * NW
#define DH   32          // head dim
#define MWIN 120832      // BWIN * NTOK
#define MPIX 100352      // B * 56 * 56

__device__ __forceinline__ u16 f2b(float f) {
  u32 u = __float_as_uint(f);
  u += 0x7fffu + ((u >> 16) & 1u);
  return (u16)(u >> 16);
}
__device__ __forceinline__ u32 pack2(float a, float b) {
  return (u32)f2b(a) | ((u32)f2b(b) << 16);
}
// fast exact-GELU: Abramowitz-Stegun 7.1.26 erf (max err 1.5e-7, << bf16 ulp)
__device__ __forceinline__ float gelu(float x) {
  const float z = fabsf(x) * 0.70710678118654752f;
  const float t = 1.0f / (1.0f + 0.3275911f * z);
  const float p = t * (0.254829592f + t * (-0.284496736f + t * (1.421413741f +
                  t * (-1.453152027f + t * 1.061405429f))));
  const float erfz = copysignf(1.0f - p * __expf(-z * z), x);
  return 0.5f * x * (1.0f + erfz);
}

// ---------------------------------------------------------------------------
// Fold LoRA into effective weights, store TRANSPOSED bf16 (K-contiguous).
// ---------------------------------------------------------------------------
__global__ void fuse_all_kernel(
    const float* __restrict__ qw,  const float* __restrict__ qa,  const float* __restrict__ qb,
    const float* __restrict__ pw,  const float* __restrict__ pa,  const float* __restrict__ pb,
    const float* __restrict__ f1w, const float* __restrict__ f1a, const float* __restrict__ f1b,
    const float* __restrict__ f2w, const float* __restrict__ f2a, const float* __restrict__ f2b2,
    u16* __restrict__ out)
{
  int idx = blockIdx.x * 256 + threadIdx.x;
  if (idx >= 196608) return;
  const float *w, *la, *lb; int Nc, K, base;
  if (idx < 49152)       { w = qw;  la = qa;  lb = qb;   Nc = 384; K = 128; base = 0; }
  else if (idx < 65536)  { w = pw;  la = pa;  lb = pb;   Nc = 128; K = 128; base = 49152; }
  else if (idx < 131072) { w = f1w; la = f1a; lb = f1b;  Nc = 512; K = 128; base = 65536; }
  else                   { w = f2w; la = f2a; lb = f2b2; Nc = 128; K = 512; base = 131072; }
  const int li = idx - base;
  const int k = li / Nc, n = li - k * Nc;
  float s = w[li];
  #pragma unroll
  for (int r = 0; r < 4; ++r) s += la[k * 4 + r] * lb[r * Nc + n];
  out[base + n * K + k] = f2b(s);
}

// ---------------------------------------------------------------------------
// Precompute bias+mask table bm[type][h][64][64] f32.
// ---------------------------------------------------------------------------
__global__ void bm_kernel(const float* __restrict__ rpb, float* __restrict__ bm)
{
  const int idx = blockIdx.x * 256 + threadIdx.x;   // 65536
  const int j = idx & 63, i = (idx >> 6) & 63, h = (idx >> 12) & 3, type = idx >> 14;
  float v = 0.f;
  if (i < 49) {
    if (j >= 59) v = -1e30f;
    else if (j >= PP) {
      const int jw = j - PP;
      const int ih = i / 7, iw = i - ih * 7, jh = jw / 7, jw2 = jw - jh * 7;
      v = rpb[((ih - jh + 6) * 13 + (iw - jw2 + 6)) * NHEADS + h];
      const int wh7 = type >> 1, ww7 = type & 1;
      const int mi = 3 * (wh7 ? (ih < 4 ? 1 : 2) : 0) + (ww7 ? (iw < 4 ? 1 : 2) : 0);
      const int mj = 3 * (wh7 ? (jh < 4 ? 1 : 2) : 0) + (ww7 ? (jw2 < 4 ? 1 : 2) : 0);
      if (mi != mj) v -= 100.f;
    }
  }
  bm[idx] = v;
}

// ---------------------------------------------------------------------------
// LN1 + roll(-3,-3) + window partition + prompt concat -> t (MWIN x 128) bf16
// ---------------------------------------------------------------------------
__global__ __launch_bounds__(256) void ln1_gather_kernel(
    const float* __restrict__ x, const float* __restrict__ prompts,
    const float* __restrict__ g, const float* __restrict__ bb,
    u16* __restrict__ t)
{
  const int tok  = blockIdx.x * 4 + (threadIdx.x >> 6);
  const int lane = threadIdx.x & 63;
  const int b_ = tok / NTOK, n = tok - b_ * NTOK;
  u32* dst = (u32*)(t + (size_t)tok * CH) + lane;
  if (n < PP) {
    const int b = b_ >> 6;
    const float2 v = *(const float2*)(prompts + ((size_t)b * PP + n) * CH + lane * 2);
    *dst = pack2(v.x, v.y);
    return;
  }
  const int w  = b_ & 63;
  const int wi = n - PP;
  const int hr = (w >> 3) * WSZ + wi / WSZ;
  const int wc = (w & 7) * WSZ + wi % WSZ;
  const int hs  = (hr + SSH) % HIMG;
  const int ws2 = (wc + SSH) % WIMG;
  const float2 v = *(const float2*)(x + ((size_t)(b_ >> 6) * (HIMG * WIMG) + hs * WIMG + ws2) * CH + lane * 2);
  float s = v.x + v.y, s2 = v.x * v.x + v.y * v.y;
  #pragma unroll
  for (int o = 32; o > 0; o >>= 1) { s += __shfl_xor(s, o); s2 += __shfl_xor(s2, o); }
  const float mean = s * (1.0f / CH);
  const float inv  = rsqrtf(s2 * (1.0f / CH) - mean * mean + 1e-5f);
  const float2 gg = *(const float2*)(g  + lane * 2);
  const float2 bv = *(const float2*)(bb + lane * 2);
  *dst = pack2((v.x - mean) * inv * gg.x + bv.x, (v.y - mean) * inv * gg.y + bv.y);
}

// ---------------------------------------------------------------------------
// FUSED qkv GEMM + window attention. One block = one window, wave w:
//   phase 1: qkv cols [w*96, w*96+96) via MFMA (A = t rows from global,
//            B = wqkvT from L2); C-frags scattered to LDS planes
//            q[64][136], k[64][136], vT[128][72].
//   phase 2: wave w = head w, R4-proven attention math; P overlays q+k.
// ---------------------------------------------------------------------------
#define QKS 136   // q/k LDS row stride (u16): 272B, 16B-aligned, 2-way banks
#define VTS 72    // vT row stride: 144B, 16B-aligned, 2-way banks
#define PS  68    // P row stride: 136B, 8B-aligned (b64 reads), 2-way banks
__global__ __launch_bounds__(256, 2) void qkv_attn_kernel(
    const u16* __restrict__ t, const u16* __restrict__ wqkvT,
    const float* __restrict__ qbias, const float* __restrict__ bm,
    u16* __restrict__ attn_out)
{
  __shared__ __align__(16) u16 smem[26624];   // 53248 B
  u16* q_lds = smem;                // [64][QKS]
  u16* k_lds = smem + 64 * QKS;     // [64][QKS]
  u16* vt    = smem + 128 * QKS;    // [128][VTS]
  u16* p_lds = smem;                // overlay q+k: [4][64][PS] = 34816 B

  const int tid = threadIdx.x;
  const int wv = tid >> 6, lane = tid & 63;
  const int lr = lane & 15, lk = lane >> 4;
  const int b_ = blockIdx.x;
  const long tbase = (long)b_ * NTOK;

  // ---- phase 1: qkv ----
  bf16x8 af[4][4];
  #pragma unroll
  for (int mt = 0; mt < 4; ++mt) {
    int tok = mt * 16 + lr; if (tok > 58) tok = 58;
    #pragma unroll
    for (int kk = 0; kk < 4; ++kk)
      af[mt][kk] = *(const bf16x8*)(t + (tbase + tok) * CH + kk * 32 + lk * 8);
  }
  #pragma unroll
  for (int nf = 0; nf < 6; ++nf) {
    const int c = wv * 96 + nf * 16 + lr;      // output col (uniform range per wave/nf)
    bf16x8 bw[4];
    #pragma unroll
    for (int kk = 0; kk < 4; ++kk)
      bw[kk] = *(const bf16x8*)(wqkvT + (long)c * CH + kk * 32 + lk * 8);
    f32x4 a4[4];
    #pragma unroll
    for (int mt = 0; mt < 4; ++mt) a4[mt] = (f32x4){0.f, 0.f, 0.f, 0.f};
    #pragma unroll
    for (int kk = 0; kk < 4; ++kk)
      #pragma unroll
      for (int mt = 0; mt < 4; ++mt)
        a4[mt] = __builtin_amdgcn_mfma_f32_16x16x32_bf16(af[mt][kk], bw[kk], a4[mt], 0, 0, 0);
    const float bs = qbias[c];
    const int sel = wv * 6 + nf;               // uniform: which plane this strip hits
    #pragma unroll
    for (int mt = 0; mt < 4; ++mt) {
      const int tok0 = mt * 16 + lk * 4;
      if (sel < 8) {                            // c in [0,128): q
        #pragma unroll
        for (int rg = 0; rg < 4; ++rg)
          q_lds[(tok0 + rg) * QKS + c] = f2b(a4[mt][rg] + bs);
      } else if (sel < 16) {                    // c in [128,256): k
        #pragma unroll
        for (int rg = 0; rg < 4; ++rg)
          k_lds[(tok0 + rg) * QKS + (c - 128)] = f2b(a4[mt][rg] + bs);
      } else {                                  // c in [256,384): v -> vT[d][tok]
        ushort4 pk = make_ushort4(f2b(a4[mt][0] + bs), f2b(a4[mt][1] + bs),
                                  f2b(a4[mt][2] + bs), f2b(a4[mt][3] + bs));
        *(ushort4*)&vt[(c - 256) * VTS + tok0] = pk;
      }
    }
  }
  __syncthreads();

  // ---- phase 2: attention, wave = head h ----
  const int h = wv;
  const int w = b_ & 63;
  const int type = (((w >> 3) == 7) ? 2 : 0) + (((w & 7) == 7) ? 1 : 0);
  const float scale = 0.17677669529663687f;    // 32^-0.5

  bf16x8 kf[4], qf[4];
  #pragma unroll
  for (int t4 = 0; t4 < 4; ++t4) {
    kf[t4] = *(const bf16x8*)&k_lds[(t4 * 16 + lr) * QKS + h * DH + lk * 8];
    int tq = PP + t4 * 16 + lr; if (tq > 63) tq = 63;
    qf[t4] = *(const bf16x8*)&q_lds[tq * QKS + h * DH + lk * 8];
  }
  f32x4 sacc[4][4];   // [mtj][nti]
  #pragma unroll
  for (int a = 0; a < 4; ++a)
    #pragma unroll
    for (int b = 0; b < 4; ++b)
      sacc[a][b] = (f32x4){0.f, 0.f, 0.f, 0.f};
  #pragma unroll
  for (int mtj = 0; mtj < 4; ++mtj)
    #pragma unroll
    for (int nti = 0; nti < 4; ++nti)
      sacc[mtj][nti] = __builtin_amdgcn_mfma_f32_16x16x32_bf16(kf[mtj], qf[nti], sacc[mtj][nti], 0, 0, 0);

  const float* bmh = bm + (size_t)(type * NHEADS + h) * 64 * 64;
  #pragma unroll
  for (int nti = 0; nti < 4; ++nti) {
    const int i = nti * 16 + lr;
    float sv[16];
    #pragma unroll
    for (int mtj = 0; mtj < 4; ++mtj) {
      const float4 bmv = *(const float4*)(bmh + i * 64 + mtj * 16 + lk * 4);
      sv[mtj * 4 + 0] = sacc[mtj][nti][0] * scale + bmv.x;
      sv[mtj * 4 + 1] = sacc[mtj][nti][1] * scale + bmv.y;
      sv[mtj * 4 + 2] = sacc[mtj][nti][2] * scale + bmv.z;
      sv[mtj * 4 + 3] = sacc[mtj][nti][3] * scale + bmv.w;
    }
    float mx = sv[0];
    #pragma unroll
    for (int q = 1; q < 16; ++q) mx = fmaxf(mx, sv[q]);
    mx = fmaxf(mx, __shfl_xor(mx, 16));
    mx = fmaxf(mx, __shfl_xor(mx, 32));
    float sum = 0.f;
    #pragma unroll
    for (int q = 0; q < 16; ++q) { sv[q] = __expf(sv[q] - mx); sum += sv[q]; }
    sum += __shfl_xor(sum, 16);
    sum += __shfl_xor(sum, 32);
    const float inv = 1.0f / sum;
    #pragma unroll
    for (int mtj = 0; mtj < 4; ++mtj) {
      sacc[mtj][nti][0] = sv[mtj * 4 + 0] * inv;
      sacc[mtj][nti][1] = sv[mtj * 4 + 1] * inv;
      sacc[mtj][nti][2] = sv[mtj * 4 + 2] * inv;
      sacc[mtj][nti][3] = sv[mtj * 4 + 3] * inv;
    }
  }
  __syncthreads();            // all q/k reads done before P overlays them

  u16* ph = p_lds + h * 64 * PS;
  #pragma unroll
  for (int nti = 0; nti < 4; ++nti) {
    const int i = nti * 16 + lr;
    #pragma unroll
    for (int mtj = 0; mtj < 4; ++mtj) {
      const ushort4 pk = make_ushort4(f2b(sacc[mtj][nti][0]), f2b(sacc[mtj][nti][1]),
                                      f2b(sacc[mtj][nti][2]), f2b(sacc[mtj][nti][3]));
      *(ushort4*)&ph[i * PS + mtj * 16 + lk * 4] = pk;
    }
  }
  __syncthreads();

  // PV
  f32x4 oacc[4][2];
  #pragma unroll
  for (int a = 0; a < 4; ++a) { oacc[a][0] = (f32x4){0,0,0,0}; oacc[a][1] = (f32x4){0,0,0,0}; }
  #pragma unroll
  for (int ks = 0; ks < 2; ++ks) {
    bf16x8 pa[4];
    #pragma unroll
    for (int mt = 0; mt < 4; ++mt) {
      const u16* pr = &ph[(mt * 16 + lr) * PS + ks * 32 + lk * 8];
      const bf16x4 lo = *(const bf16x4*)pr;
      const bf16x4 hi = *(const bf16x4*)(pr + 4);
      pa[mt] = __builtin_shufflevector(lo, hi, 0, 1, 2, 3, 4, 5, 6, 7);
    }
    bf16x8 bv[2];
    #pragma unroll
    for (int nd = 0; nd < 2; ++nd)
      bv[nd] = *(const bf16x8*)&vt[(h * DH + nd * 16 + lr) * VTS + ks * 32 + lk * 8];
    #pragma unroll
    for (int mt = 0; mt < 4; ++mt)
      #pragma unroll
      for (int nd = 0; nd < 2; ++nd)
        oacc[mt][nd] = __builtin_amdgcn_mfma_f32_16x16x32_bf16(pa[mt], bv[nd], oacc[mt][nd], 0, 0, 0);
  }

  // O -> own P plane, then coalesced store
  #pragma unroll
  for (int mt = 0; mt < 4; ++mt)
    #pragma unroll
    for (int rg = 0; rg < 4; ++rg) {
      const int i = mt * 16 + lk * 4 + rg;
      ph[i * PS + lr]      = f2b(oacc[mt][0][rg]);
      ph[i * PS + 16 + lr] = f2b(oacc[mt][1][rg]);
    }
  __syncthreads();
  if (lane < NWIN) {
    const u16* src = &ph[lane * PS];
    u16* dst = attn_out + ((size_t)b_ * NWIN + lane) * CH + h * DH;
    #pragma unroll
    for (int c = 0; c < 8; ++c)
      *(uint2*)(dst + c * 4) = *(const uint2*)(src + c * 4);
  }
}

// ---------------------------------------------------------------------------
// proj GEMM (R6-validated): MODE 1 = window-reverse + residual -> x1 f32
// AND fused LN2 -> bf16 mbuf.
// ---------------------------------------------------------------------------
template<int KTOT, int NCOLT, int MODE>
__global__ __launch_bounds__(256, 4) void gemm_kernel(
    const u16* __restrict__ A, const u16* __restrict__ WT,
    const float* __restrict__ bias, const float* __restrict__ aux,
    const float* __restrict__ g2, const float* __restrict__ b2,
    float* __restrict__ outf, u16* __restrict__ outb)
{
  __shared__ __align__(16) char smem[34816];
  u16* sa = (u16*)smem;
  u16* sb = (u16*)(smem + 16384);
  const int tid = threadIdx.x;
  const int wv = tid >> 6, lane = tid & 63;
  const int lr = lane & 15, lk = lane >> 4;
  const int wrow = wv >> 1, wcol = wv & 1;
  const long rowbase = (long)blockIdx.x * 128;
  const int colbase = blockIdx.y * 128;

  f32x4 acc[4][4];
  #pragma unroll
  for (int m = 0; m < 4; ++m)
    #pragma unroll
    for (int n = 0; n < 4; ++n)
      acc[m][n] = (f32x4){0.f, 0.f, 0.f, 0.f};

  for (int kb = 0; kb < KTOT; kb += 64) {
    #pragma unroll
    for (int it = 0; it < 4; ++it) {
      const int c = wv * 256 + it * 64 + lane;
      const int r = c >> 3, s = c & 7;
      const int k8 = s ^ (r & 7);
      __builtin_amdgcn_global_load_lds((const void*)(A + (rowbase + r) * KTOT + kb + k8 * 8),
                                       (void*)(sa + c * 8), 16, 0, 0);
      __builtin_amdgcn_global_load_lds((const void*)(WT + (long)(colbase + r) * KTOT + kb + k8 * 8),
                                       (void*)(sb + c * 8), 16, 0, 0);
    }
    __syncthreads();
    const char* la = (const char*)sa;
    const char* lb = (const char*)sb;
    #pragma unroll
    for (int k32 = 0; k32 < 2; ++k32) {
      bf16x8 af[4], bfv[4];
      #pragma unroll
      for (int m = 0; m < 4; ++m) {
        const int r = wrow * 64 + m * 16 + lr;
        af[m] = *(const bf16x8*)(la + r * 128 + (((k32 * 4 + lk) ^ (r & 7)) << 4));
      }
      #pragma unroll
      for (int n = 0; n < 4; ++n) {
        const int r = wcol * 64 + n * 16 + lr;
        bfv[n] = *(const bf16x8*)(lb + r * 128 + (((k32 * 4 + lk) ^ (r & 7)) << 4));
      }
      #pragma unroll
      for (int m = 0; m < 4; ++m)
        #pragma unroll
        for (int n = 0; n < 4; ++n)
          acc[m][n] = __builtin_amdgcn_mfma_f32_16x16x32_bf16(af[m], bfv[n], acc[m][n], 0, 0, 0);
    }
    __syncthreads();
  }

  // f32 transpose epilogue: [64][132] in two 64-row chunks
  float* T32 = (float*)smem;
  #pragma unroll
  for (int ch = 0; ch < 2; ++ch) {
    if (wrow == ch) {
      #pragma unroll
      for (int n = 0; n < 4; ++n) {
        const int col = wcol * 64 + n * 16 + lr;
        const float bs = bias[colbase + col];
        #pragma unroll
        for (int m = 0; m < 4; ++m)
          #pragma unroll
          for (int j = 0; j < 4; ++j)
            T32[(m * 16 + lk * 4 + j) * 132 + col] = acc[m][n][j] + bs;
      }
    }
    __syncthreads();
    const int rl = tid >> 2, q = tid & 3;
    const long grow = rowbase + ch * 64 + rl;
    float4 v[8];
    #pragma unroll
    for (int i = 0; i < 8; ++i)
      v[i] = *(const float4*)&T32[rl * 132 + q * 4 + i * 16];
    {
      // MODE 1: window-reverse + residual + fused LN2
      const int mi = (int)grow;
      const int b_ = mi / NWIN, wi = mi - b_ * NWIN;
      const int w  = b_ & 63;
      const int hr = (w >> 3) * WSZ + wi / WSZ;
      const int wc2 = (w & 7) * WSZ + wi % WSZ;
      const int hf = (hr + SSH) % HIMG;
      const int wf = (wc2 + SSH) % WIMG;
      const long pix = (long)(b_ >> 6) * (HIMG * WIMG) + hf * WIMG + wf;
      const float* arow = aux + pix * CH;
      float* xrow = outf + pix * CH;
      float sum = 0.f, sq = 0.f;
      #pragma unroll
      for (int i = 0; i < 8; ++i) {
        const float4 ax = *(const float4*)(arow + q * 4 + i * 16);
        float4 tv = v[i];
        tv.x += ax.x; tv.y += ax.y; tv.z += ax.z; tv.w += ax.w;
        v[i] = tv;
        *(float4*)(xrow + q * 4 + i * 16) = tv;
        sum += tv.x + tv.y + tv.z + tv.w;
        sq  += tv.x * tv.x + tv.y * tv.y + tv.z * tv.z + tv.w * tv.w;
      }
      sum += __shfl_xor(sum, 1); sq += __shfl_xor(sq, 1);
      sum += __shfl_xor(sum, 2); sq += __shfl_xor(sq, 2);
      const float mean = sum * (1.0f / CH);
      const float inv  = rsqrtf(sq * (1.0f / CH) - mean * mean + 1e-5f);
      u16* mrow = outb + pix * CH;
      #pragma unroll
      for (int i2 = 0; i2 < 4; ++i2) {
        const float4 a = v[2 * i2], b = v[2 * i2 + 1];
        const float4 ga = *(const float4*)(g2 + q * 4 + (2 * i2) * 16);
        const float4 gb = *(const float4*)(g2 + q * 4 + (2 * i2 + 1) * 16);
        const float4 ba = *(const float4*)(b2 + q * 4 + (2 * i2) * 16);
        const float4 bb = *(const float4*)(b2 + q * 4 + (2 * i2 + 1) * 16);
        uint2 pkA, pkB;
        pkA.x = pack2((a.x - mean) * inv * ga.x + ba.x, (a.y - mean) * inv * ga.y + ba.y);
        pkA.y = pack2((a.z - mean) * inv * ga.z + ba.z, (a.w - mean) * inv * ga.w + ba.w);
        pkB.x = pack2((b.x - mean) * inv * gb.x + bb.x, (b.y - mean) * inv * gb.y + bb.y);
        pkB.y = pack2((b.z - mean) * inv * gb.z + bb.z, (b.w - mean) * inv * gb.w + bb.w);
        *(uint2*)(mrow + q * 4 + (2 * i2) * 16) = pkA;
        *(uint2*)(mrow + q * 4 + (2 * i2 + 1) * 16) = pkB;
      }
    }
    if (ch == 0) __syncthreads();
  }
}

// ---------------------------------------------------------------------------
// FUSED MLP: out = GELU(m @ W1 + b1) @ W2 + b2 + x1, hidden stays on-chip.
// Per block: 128 rows. m staged once (swizzle16); 8 hidden-blocks of 64:
//   stage1 (2x2 waves, 64x32 tiles) -> GELU -> H[128][72] LDS
//   stage2 accumulate out (2x2 waves, 64x64 tiles).
// Epilogue: R6 MODE-3 f32 transpose + residual.
// ---------------------------------------------------------------------------
#define HS 72
__global__ __launch_bounds__(256, 2) void mlp_kernel(
    const u16* __restrict__ m, const u16* __restrict__ w1T, const float* __restrict__ b1,
    const u16* __restrict__ w2T, const float* __restrict__ b2,
    const float* __restrict__ x1, float* __restrict__ outp)
{
  __shared__ __align__(16) char smem[51200];
  u16* sa = (u16*)smem;               // [128][128] m-tile
  u16* hl = (u16*)(smem + 32768);     // [128][HS]
  float* T32 = (float*)smem;          // epilogue overlay [64][132]
  const int tid = threadIdx.x;
  const int wv = tid >> 6, lane = tid & 63;
  const int lr = lane & 15, lk = lane >> 4;
  const int wrow = wv >> 1, wcol = wv & 1;
  const long rowbase = (long)blockIdx.x * 128;

  #pragma unroll
  for (int it = 0; it < 8; ++it) {
    const int c = it * 256 + tid;
    const int r = c >> 4, s = c & 15;
    const int k8 = s ^ (r & 15);
    __builtin_amdgcn_global_load_lds((const void*)(m + (rowbase + r) * CH + k8 * 8),
                                     (void*)(sa + c * 8), 16, 0, 0);
  }
  __syncthreads();

  f32x4 oad[4][4];
  #pragma unroll
  for (int a = 0; a < 4; ++a)
    #pragma unroll
    for (int b = 0; b < 4; ++b)
      oad[a][b] = (f32x4){0.f, 0.f, 0.f, 0.f};

  for (int hb = 0; hb < 8; ++hb) {
    // ---- stage 1: H strip = GELU(m @ W1[:, hb*64 .. +64)) ----
    f32x4 acc2[4][2];
    #pragma unroll
    for (int a = 0; a < 4; ++a) { acc2[a][0] = (f32x4){0,0,0,0}; acc2[a][1] = (f32x4){0,0,0,0}; }
    #pragma unroll
    for (int kk = 0; kk < 4; ++kk) {
      bf16x8 a1[4];
      #pragma unroll
      for (int mt = 0; mt < 4; ++mt) {
        const int r = wrow * 64 + mt * 16 + lr;
        a1[mt] = *(const bf16x8*)(sa + r * 128 + (((kk * 4 + lk) ^ (r & 15)) << 3));
      }
      #pragma unroll
      for (int nf = 0; nf < 2; ++nf) {
        const bf16x8 bw = *(const bf16x8*)(w1T + (long)(hb * 64 + wcol * 32 + nf * 16 + lr) * CH + kk * 32 + lk * 8);
        #pragma unroll
        for (int mt = 0; mt < 4; ++mt)
          acc2[mt][nf] = __builtin_amdgcn_mfma_f32_16x16x32_bf16(a1[mt], bw, acc2[mt][nf], 0, 0, 0);
      }
    }
    #pragma unroll
    for (int nf = 0; nf < 2; ++nf) {
      const int hc = wcol * 32 + nf * 16 + lr;
      const float bs = b1[hb * 64 + hc];
      #pragma unroll
      for (int mt = 0; mt < 4; ++mt) {
        const int tok0 = wrow * 64 + mt * 16 + lk * 4;
        #pragma unroll
        for (int rg = 0; rg < 4; ++rg)
          hl[(tok0 + rg) * HS + hc] = f2b(gelu(acc2[mt][nf][rg] + bs));
      }
    }
    __syncthreads();
    // ---- stage 2: out += H @ W2[hb*64 .. +64, :] ----
    #pragma unroll
    for (int kk2 = 0; kk2 < 2; ++kk2) {
      bf16x8 a2[4];
      #pragma unroll
      for (int mt = 0; mt < 4; ++mt)
        a2[mt] = *(const bf16x8*)&hl[(wrow * 64 + mt * 16 + lr) * HS + kk2 * 32 + lk * 8];
      #pragma unroll
      for (int nf2 = 0; nf2 < 4; ++nf2) {
        const bf16x8 bw2 = *(const bf16x8*)(w2T + (long)(wcol * 64 + nf2 * 16 + lr) * HIDD + hb * 64 + kk2 * 32 + lk * 8);
        #pragma unroll
        for (int mt = 0; mt < 4; ++mt)
          oad[mt][nf2] = __builtin_amdgcn_mfma_f32_16x16x32_bf16(a2[mt], bw2, oad[mt][nf2], 0, 0, 0);
      }
    }
    __syncthreads();
  }

  // ---- epilogue: transpose + bias + x1 residual -> f32 out ----
  #pragma unroll
  for (int ch = 0; ch < 2; ++ch) {
    if (wrow == ch) {
      #pragma unroll
      for (int n = 0; n < 4; ++n) {
        const int col = wcol * 64 + n * 16 + lr;
        const float bs = b2[col];
        #pragma unroll
        for (int mt = 0; mt < 4; ++mt)
          #pragma unroll
          for (int j = 0; j < 4; ++j)
            T32[(mt * 16 + lk * 4 + j) * 132 + col] = oad[mt][n][j] + bs;
      }
    }
    __syncthreads();
    const int rl = tid >> 2, q = tid & 3;
    const long grow = rowbase + ch * 64 + rl;
    const float* arow = x1 + grow * CH;
    float* orow = outp + grow * CH;
    #pragma unroll
    for (int i = 0; i < 8; ++i) {
      float4 v = *(const float4*)&T32[rl * 132 + q * 4 + i * 16];
      const float4 ax = *(const float4*)(arow + q * 4 + i * 16);
      v.x += ax.x; v.y += ax.y; v.z += ax.z; v.w += ax.w;
      *(float4*)(orow + q * 4 + i * 16) = v;
    }
    if (ch == 0) __syncthreads();
  }
}

// ---------------------------------------------------------------------------
extern "C" void kernel_launch(void* const* d_in, const int* in_sizes, int n_in,
                              void* d_out, int out_size, void* d_ws, size_t ws_size,
                              hipStream_t stream)
{
  const float* x       = (const float*)d_in[0];
  const float* prompts = (const float*)d_in[1];
  const float* n1g     = (const float*)d_in[2];
  const float* n1b     = (const float*)d_in[3];
  const float* qkv_w   = (const float*)d_in[4];
  const float* qkv_b   = (const float*)d_in[5];
  const float* qkv_la  = (const float*)d_in[6];
  const float* qkv_lb  = (const float*)d_in[7];
  const float* rpb     = (const float*)d_in[8];
  const float* proj_w  = (const float*)d_in[9];
  const float* proj_b  = (const float*)d_in[10];
  const float* proj_la = (const float*)d_in[11];
  const float* proj_lb = (const float*)d_in[12];
  const float* n2g     = (const float*)d_in[13];
  const float* n2b     = (const float*)d_in[14];
  const float* fc1_w   = (const float*)d_in[15];
  const float* fc1_b   = (const float*)d_in[16];
  const float* fc1_la  = (const float*)d_in[17];
  const float* fc1_lb  = (const float*)d_in[18];
  const float* fc2_w   = (const float*)d_in[19];
  const float* fc2_b   = (const float*)d_in[20];
  const float* fc2_la  = (const float*)d_in[21];
  const float* fc2_lb  = (const float*)d_in[22];

  // workspace: wT | bm | tbuf | aobuf | x1 | mbuf   (~134 MB)
  char* ws = (char*)d_ws;
  u16* wT     = (u16*)ws;
  u16* wqkvT  = wT;
  u16* wprojT = wT + 49152;
  u16* wfc1T  = wT + 65536;
  u16* wfc2T  = wT + 131072;
  float* bm   = (float*)(ws + 393216);
  char* p = ws + 393216 + 262144;
  u16* tbuf  = (u16*)p;                       p += (size_t)MWIN * CH * 2;
  u16* aobuf = (u16*)p;                       p += (size_t)MPIX * CH * 2;
  float* x1buf = (float*)p;                   p += (size_t)MPIX * CH * 4;
  u16* mbuf  = (u16*)p;

  fuse_all_kernel<<<768, 256, 0, stream>>>(
      qkv_w, qkv_la, qkv_lb, proj_w, proj_la, proj_lb,
      fc1_w, fc1_la, fc1_lb, fc2_w, fc2_la, fc2_lb, wT);

  bm_kernel<<<256, 256, 0, stream>>>(rpb, bm);

  ln1_gather_kernel<<<MWIN / 4, 256, 0, stream>>>(x, prompts, n1g, n1b, tbuf);

  qkv_attn_kernel<<<BWIN, 256, 0, stream>>>(tbuf, wqkvT, qkv_b, bm, aobuf);

  gemm_kernel<128, 128, 1><<<dim3(MPIX / 128, 1), 256, 0, stream>>>(
      aobuf, wprojT, proj_b, x, n2g, n2b, x1buf, mbuf);

  mlp_kernel<<<MPIX / 128, 256, 0, stream>>>(
      mbuf, wfc1T, fc1_b, wfc2T, fc2_b, x1buf, (float*)d_out);
}

// Round 8
// 218.203 us; speedup vs baseline: 1.4195x; 1.1297x over previous
//
#include <hip/hip_runtime.h>

typedef unsigned short u16;
typedef unsigned int   u32;
typedef short bf16x8 __attribute__((ext_vector_type(8)));
typedef short bf16x4 __attribute__((ext_vector_type(4)));
typedef float f32x4  __attribute__((ext_vector_type(4)));

#define HIMG 56
#define WIMG 56
#define CH   128
#define NHEADS 4
#define WSZ  7
#define SSH  3
#define PP   10
#define HIDD 512
#define NWIN 49          // window tokens
#define NTOK 59          // P + NWIN
#define BWIN 2048        // B * NW
#define DH   32          // head dim
#define MWIN 120832      // BWIN * NTOK
#define MPIX 100352      // B * 56 * 56

__device__ __forceinline__ u16 f2b(float f) {
  u32 u = __float_as_uint(f);
  u += 0x7fffu + ((u >> 16) & 1u);
  return (u16)(u >> 16);
}
__device__ __forceinline__ u32 pack2(float a, float b) {
  return (u32)f2b(a) | ((u32)f2b(b) << 16);
}
// fast exact-GELU: Abramowitz-Stegun 7.1.26 erf (max err 1.5e-7) — R7-proven
__device__ __forceinline__ float gelu(float x) {
  const float z = fabsf(x) * 0.70710678118654752f;
  const float t = 1.0f / (1.0f + 0.3275911f * z);
  const float p = t * (0.254829592f + t * (-0.284496736f + t * (1.421413741f +
                  t * (-1.453152027f + t * 1.061405429f))));
  const float erfz = copysignf(1.0f - p * __expf(-z * z), x);
  return 0.5f * x * (1.0f + erfz);
}

// ---------------------------------------------------------------------------
// Fold LoRA into effective weights. Layouts:
//   wqf  [c16=24][kk=4][lane][8]  : qkv B-fragments, coalesced 16B/lane
//   wprojT [128][128] row-major-T : proj (gemm_kernel gload_lds path)
//   w1f  [c16=32][kk=4][lane][8]  : fc1 A-fragments (row = hidden col)
//   w2f  [o16=8][hb=8][kk2=2][lane][8] : fc2 B-fragments
// frag elem (lane,j): row/col = 16*c16 + (lane&15), k = kbase + (lane>>4)*8 + j
// ---------------------------------------------------------------------------
__global__ void fuse_all_kernel(
    const float* __restrict__ qw,  const float* __restrict__ qa,  const float* __restrict__ qb,
    const float* __restrict__ pw,  const float* __restrict__ pa,  const float* __restrict__ pb,
    const float* __restrict__ f1w, const float* __restrict__ f1a, const float* __restrict__ f1b,
    const float* __restrict__ f2w, const float* __restrict__ f2a, const float* __restrict__ f2b2,
    u16* __restrict__ out)
{
  int idx = blockIdx.x * 256 + threadIdx.x;
  if (idx >= 196608) return;
  int n, k, Nc;
  const float *w, *la, *lb;
  if (idx < 49152) {                    // wqf
    const int li = idx;
    const int j = li & 7, lane = (li >> 3) & 63, kk = (li >> 9) & 3, c16 = li >> 11;
    n = c16 * 16 + (lane & 15);
    k = kk * 32 + (lane >> 4) * 8 + j;
    w = qw; la = qa; lb = qb; Nc = 384;
  } else if (idx < 65536) {             // wprojT [n][k]
    const int li = idx - 49152;
    n = li >> 7; k = li & 127;
    w = pw; la = pa; lb = pb; Nc = 128;
  } else if (idx < 131072) {            // w1f
    const int li = idx - 65536;
    const int j = li & 7, lane = (li >> 3) & 63, kk = (li >> 9) & 3, c16 = li >> 11;
    n = c16 * 16 + (lane & 15);
    k = kk * 32 + (lane >> 4) * 8 + j;
    w = f1w; la = f1a; lb = f1b; Nc = 512;
  } else {                              // w2f
    const int li = idx - 131072;
    const int j = li & 7, lane = (li >> 3) & 63, kk2 = (li >> 9) & 1, hb = (li >> 10) & 7, o16 = li >> 13;
    n = o16 * 16 + (lane & 15);
    k = hb * 64 + kk2 * 32 + (lane >> 4) * 8 + j;
    w = f2w; la = f2a; lb = f2b2; Nc = 128;
  }
  float s = w[k * Nc + n];
  #pragma unroll
  for (int r = 0; r < 4; ++r) s += la[k * 4 + r] * lb[r * Nc + n];
  out[idx] = f2b(s);
}

// ---------------------------------------------------------------------------
// Precompute bias+mask table bm[type][h][64][64] f32.
// ---------------------------------------------------------------------------
__global__ void bm_kernel(const float* __restrict__ rpb, float* __restrict__ bm)
{
  const int idx = blockIdx.x * 256 + threadIdx.x;   // 65536
  const int j = idx & 63, i = (idx >> 6) & 63, h = (idx >> 12) & 3, type = idx >> 14;
  float v = 0.f;
  if (i < 49) {
    if (j >= 59) v = -1e30f;
    else if (j >= PP) {
      const int jw = j - PP;
      const int ih = i / 7, iw = i - ih * 7, jh = jw / 7, jw2 = jw - jh * 7;
      v = rpb[((ih - jh + 6) * 13 + (iw - jw2 + 6)) * NHEADS + h];
      const int wh7 = type >> 1, ww7 = type & 1;
      const int mi = 3 * (wh7 ? (ih < 4 ? 1 : 2) : 0) + (ww7 ? (iw < 4 ? 1 : 2) : 0);
      const int mj = 3 * (wh7 ? (jh < 4 ? 1 : 2) : 0) + (ww7 ? (jw2 < 4 ? 1 : 2) : 0);
      if (mi != mj) v -= 100.f;
    }
  }
  bm[idx] = v;
}

// ---------------------------------------------------------------------------
// LN1 + roll(-3,-3) + window partition + prompt concat -> t (MWIN x 128) bf16
// ---------------------------------------------------------------------------
__global__ __launch_bounds__(256) void ln1_gather_kernel(
    const float* __restrict__ x, const float* __restrict__ prompts,
    const float* __restrict__ g, const float* __restrict__ bb,
    u16* __restrict__ t)
{
  const int tok  = blockIdx.x * 4 + (threadIdx.x >> 6);
  const int lane = threadIdx.x & 63;
  const int b_ = tok / NTOK, n = tok - b_ * NTOK;
  u32* dst = (u32*)(t + (size_t)tok * CH) + lane;
  if (n < PP) {
    const int b = b_ >> 6;
    const float2 v = *(const float2*)(prompts + ((size_t)b * PP + n) * CH + lane * 2);
    *dst = pack2(v.x, v.y);
    return;
  }
  const int w  = b_ & 63;
  const int wi = n - PP;
  const int hr = (w >> 3) * WSZ + wi / WSZ;
  const int wc = (w & 7) * WSZ + wi % WSZ;
  const int hs  = (hr + SSH) % HIMG;
  const int ws2 = (wc + SSH) % WIMG;
  const float2 v = *(const float2*)(x + ((size_t)(b_ >> 6) * (HIMG * WIMG) + hs * WIMG + ws2) * CH + lane * 2);
  float s = v.x + v.y, s2 = v.x * v.x + v.y * v.y;
  #pragma unroll
  for (int o = 32; o > 0; o >>= 1) { s += __shfl_xor(s, o); s2 += __shfl_xor(s2, o); }
  const float mean = s * (1.0f / CH);
  const float inv  = rsqrtf(s2 * (1.0f / CH) - mean * mean + 1e-5f);
  const float2 gg = *(const float2*)(g  + lane * 2);
  const float2 bv = *(const float2*)(bb + lane * 2);
  *dst = pack2((v.x - mean) * inv * gg.x + bv.x, (v.y - mean) * inv * gg.y + bv.y);
}

// ---------------------------------------------------------------------------
// FUSED qkv GEMM + window attention (R7-proven; B-frags now from wqf).
// ---------------------------------------------------------------------------
#define QKS 136
#define VTS 72
#define PS  68
__global__ __launch_bounds__(256, 2) void qkv_attn_kernel(
    const u16* __restrict__ t, const u16* __restrict__ wqf,
    const float* __restrict__ qbias, const float* __restrict__ bm,
    u16* __restrict__ attn_out)
{
  __shared__ __align__(16) u16 smem[26624];   // 53248 B
  u16* q_lds = smem;                // [64][QKS]
  u16* k_lds = smem + 64 * QKS;     // [64][QKS]
  u16* vt    = smem + 128 * QKS;    // [128][VTS]
  u16* p_lds = smem;                // overlay q+k: [4][64][PS]

  const int tid = threadIdx.x;
  const int wv = tid >> 6, lane = tid & 63;
  const int lr = lane & 15, lk = lane >> 4;
  const int b_ = blockIdx.x;
  const long tbase = (long)b_ * NTOK;

  // ---- phase 1: qkv ----
  bf16x8 af[4][4];
  #pragma unroll
  for (int mt = 0; mt < 4; ++mt) {
    int tok = mt * 16 + lr; if (tok > 58) tok = 58;
    #pragma unroll
    for (int kk = 0; kk < 4; ++kk)
      af[mt][kk] = *(const bf16x8*)(t + (tbase + tok) * CH + kk * 32 + lk * 8);
  }
  #pragma unroll
  for (int nf = 0; nf < 6; ++nf) {
    const int c = wv * 96 + nf * 16 + lr;
    const int sel = wv * 6 + nf;
    bf16x8 bw[4];
    #pragma unroll
    for (int kk = 0; kk < 4; ++kk)
      bw[kk] = *(const bf16x8*)(wqf + ((sel * 4 + kk) * 64 + lane) * 8);
    f32x4 a4[4];
    #pragma unroll
    for (int mt = 0; mt < 4; ++mt) a4[mt] = (f32x4){0.f, 0.f, 0.f, 0.f};
    #pragma unroll
    for (int kk = 0; kk < 4; ++kk)
      #pragma unroll
      for (int mt = 0; mt < 4; ++mt)
        a4[mt] = __builtin_amdgcn_mfma_f32_16x16x32_bf16(af[mt][kk], bw[kk], a4[mt], 0, 0, 0);
    const float bs = qbias[c];
    #pragma unroll
    for (int mt = 0; mt < 4; ++mt) {
      const int tok0 = mt * 16 + lk * 4;
      if (sel < 8) {
        #pragma unroll
        for (int rg = 0; rg < 4; ++rg)
          q_lds[(tok0 + rg) * QKS + c] = f2b(a4[mt][rg] + bs);
      } else if (sel < 16) {
        #pragma unroll
        for (int rg = 0; rg < 4; ++rg)
          k_lds[(tok0 + rg) * QKS + (c - 128)] = f2b(a4[mt][rg] + bs);
      } else {
        ushort4 pk = make_ushort4(f2b(a4[mt][0] + bs), f2b(a4[mt][1] + bs),
                                  f2b(a4[mt][2] + bs), f2b(a4[mt][3] + bs));
        *(ushort4*)&vt[(c - 256) * VTS + tok0] = pk;
      }
    }
  }
  __syncthreads();

  // ---- phase 2: attention, wave = head h ----
  const int h = wv;
  const int w = b_ & 63;
  const int type = (((w >> 3) == 7) ? 2 : 0) + (((w & 7) == 7) ? 1 : 0);
  const float scale = 0.17677669529663687f;

  bf16x8 kf[4], qf[4];
  #pragma unroll
  for (int t4 = 0; t4 < 4; ++t4) {
    kf[t4] = *(const bf16x8*)&k_lds[(t4 * 16 + lr) * QKS + h * DH + lk * 8];
    int tq = PP + t4 * 16 + lr; if (tq > 63) tq = 63;
    qf[t4] = *(const bf16x8*)&q_lds[tq * QKS + h * DH + lk * 8];
  }
  f32x4 sacc[4][4];
  #pragma unroll
  for (int a = 0; a < 4; ++a)
    #pragma unroll
    for (int b = 0; b < 4; ++b)
      sacc[a][b] = (f32x4){0.f, 0.f, 0.f, 0.f};
  #pragma unroll
  for (int mtj = 0; mtj < 4; ++mtj)
    #pragma unroll
    for (int nti = 0; nti < 4; ++nti)
      sacc[mtj][nti] = __builtin_amdgcn_mfma_f32_16x16x32_bf16(kf[mtj], qf[nti], sacc[mtj][nti], 0, 0, 0);

  const float* bmh = bm + (size_t)(type * NHEADS + h) * 64 * 64;
  #pragma unroll
  for (int nti = 0; nti < 4; ++nti) {
    const int i = nti * 16 + lr;
    float sv[16];
    #pragma unroll
    for (int mtj = 0; mtj < 4; ++mtj) {
      const float4 bmv = *(const float4*)(bmh + i * 64 + mtj * 16 + lk * 4);
      sv[mtj * 4 + 0] = sacc[mtj][nti][0] * scale + bmv.x;
      sv[mtj * 4 + 1] = sacc[mtj][nti][1] * scale + bmv.y;
      sv[mtj * 4 + 2] = sacc[mtj][nti][2] * scale + bmv.z;
      sv[mtj * 4 + 3] = sacc[mtj][nti][3] * scale + bmv.w;
    }
    float mx = sv[0];
    #pragma unroll
    for (int q = 1; q < 16; ++q) mx = fmaxf(mx, sv[q]);
    mx = fmaxf(mx, __shfl_xor(mx, 16));
    mx = fmaxf(mx, __shfl_xor(mx, 32));
    float sum = 0.f;
    #pragma unroll
    for (int q = 0; q < 16; ++q) { sv[q] = __expf(sv[q] - mx); sum += sv[q]; }
    sum += __shfl_xor(sum, 16);
    sum += __shfl_xor(sum, 32);
    const float inv = 1.0f / sum;
    #pragma unroll
    for (int mtj = 0; mtj < 4; ++mtj) {
      sacc[mtj][nti][0] = sv[mtj * 4 + 0] * inv;
      sacc[mtj][nti][1] = sv[mtj * 4 + 1] * inv;
      sacc[mtj][nti][2] = sv[mtj * 4 + 2] * inv;
      sacc[mtj][nti][3] = sv[mtj * 4 + 3] * inv;
    }
  }
  __syncthreads();

  u16* ph = p_lds + h * 64 * PS;
  #pragma unroll
  for (int nti = 0; nti < 4; ++nti) {
    const int i = nti * 16 + lr;
    #pragma unroll
    for (int mtj = 0; mtj < 4; ++mtj) {
      const ushort4 pk = make_ushort4(f2b(sacc[mtj][nti][0]), f2b(sacc[mtj][nti][1]),
                                      f2b(sacc[mtj][nti][2]), f2b(sacc[mtj][nti][3]));
      *(ushort4*)&ph[i * PS + mtj * 16 + lk * 4] = pk;
    }
  }
  __syncthreads();

  f32x4 oacc[4][2];
  #pragma unroll
  for (int a = 0; a < 4; ++a) { oacc[a][0] = (f32x4){0,0,0,0}; oacc[a][1] = (f32x4){0,0,0,0}; }
  #pragma unroll
  for (int ks = 0; ks < 2; ++ks) {
    bf16x8 pa[4];
    #pragma unroll
    for (int mt = 0; mt < 4; ++mt) {
      const u16* pr = &ph[(mt * 16 + lr) * PS + ks * 32 + lk * 8];
      const bf16x4 lo = *(const bf16x4*)pr;
      const bf16x4 hi = *(const bf16x4*)(pr + 4);
      pa[mt] = __builtin_shufflevector(lo, hi, 0, 1, 2, 3, 4, 5, 6, 7);
    }
    bf16x8 bv[2];
    #pragma unroll
    for (int nd = 0; nd < 2; ++nd)
      bv[nd] = *(const bf16x8*)&vt[(h * DH + nd * 16 + lr) * VTS + ks * 32 + lk * 8];
    #pragma unroll
    for (int mt = 0; mt < 4; ++mt)
      #pragma unroll
      for (int nd = 0; nd < 2; ++nd)
        oacc[mt][nd] = __builtin_amdgcn_mfma_f32_16x16x32_bf16(pa[mt], bv[nd], oacc[mt][nd], 0, 0, 0);
  }

  #pragma unroll
  for (int mt = 0; mt < 4; ++mt)
    #pragma unroll
    for (int rg = 0; rg < 4; ++rg) {
      const int i = mt * 16 + lk * 4 + rg;
      ph[i * PS + lr]      = f2b(oacc[mt][0][rg]);
      ph[i * PS + 16 + lr] = f2b(oacc[mt][1][rg]);
    }
  __syncthreads();
  if (lane < NWIN) {
    const u16* src = &ph[lane * PS];
    u16* dst = attn_out + ((size_t)b_ * NWIN + lane) * CH + h * DH;
    #pragma unroll
    for (int c = 0; c < 8; ++c)
      *(uint2*)(dst + c * 4) = *(const uint2*)(src + c * 4);
  }
}

// ---------------------------------------------------------------------------
// proj GEMM (R6-validated): MODE 1 = window-reverse + residual -> x1 f32
// AND fused LN2 -> bf16 mbuf.
// ---------------------------------------------------------------------------
template<int KTOT, int NCOLT, int MODE>
__global__ __launch_bounds__(256, 4) void gemm_kernel(
    const u16* __restrict__ A, const u16* __restrict__ WT,
    const float* __restrict__ bias, const float* __restrict__ aux,
    const float* __restrict__ g2, const float* __restrict__ b2,
    float* __restrict__ outf, u16* __restrict__ outb)
{
  __shared__ __align__(16) char smem[34816];
  u16* sa = (u16*)smem;
  u16* sb = (u16*)(smem + 16384);
  const int tid = threadIdx.x;
  const int wv = tid >> 6, lane = tid & 63;
  const int lr = lane & 15, lk = lane >> 4;
  const int wrow = wv >> 1, wcol = wv & 1;
  const long rowbase = (long)blockIdx.x * 128;
  const int colbase = blockIdx.y * 128;

  f32x4 acc[4][4];
  #pragma unroll
  for (int m = 0; m < 4; ++m)
    #pragma unroll
    for (int n = 0; n < 4; ++n)
      acc[m][n] = (f32x4){0.f, 0.f, 0.f, 0.f};

  for (int kb = 0; kb < KTOT; kb += 64) {
    #pragma unroll
    for (int it = 0; it < 4; ++it) {
      const int c = wv * 256 + it * 64 + lane;
      const int r = c >> 3, s = c & 7;
      const int k8 = s ^ (r & 7);
      __builtin_amdgcn_global_load_lds((const void*)(A + (rowbase + r) * KTOT + kb + k8 * 8),
                                       (void*)(sa + c * 8), 16, 0, 0);
      __builtin_amdgcn_global_load_lds((const void*)(WT + (long)(colbase + r) * KTOT + kb + k8 * 8),
                                       (void*)(sb + c * 8), 16, 0, 0);
    }
    __syncthreads();
    const char* la = (const char*)sa;
    const char* lb = (const char*)sb;
    #pragma unroll
    for (int k32 = 0; k32 < 2; ++k32) {
      bf16x8 af[4], bfv[4];
      #pragma unroll
      for (int m = 0; m < 4; ++m) {
        const int r = wrow * 64 + m * 16 + lr;
        af[m] = *(const bf16x8*)(la + r * 128 + (((k32 * 4 + lk) ^ (r & 7)) << 4));
      }
      #pragma unroll
      for (int n = 0; n < 4; ++n) {
        const int r = wcol * 64 + n * 16 + lr;
        bfv[n] = *(const bf16x8*)(lb + r * 128 + (((k32 * 4 + lk) ^ (r & 7)) << 4));
      }
      #pragma unroll
      for (int m = 0; m < 4; ++m)
        #pragma unroll
        for (int n = 0; n < 4; ++n)
          acc[m][n] = __builtin_amdgcn_mfma_f32_16x16x32_bf16(af[m], bfv[n], acc[m][n], 0, 0, 0);
    }
    __syncthreads();
  }

  float* T32 = (float*)smem;
  #pragma unroll
  for (int ch = 0; ch < 2; ++ch) {
    if (wrow == ch) {
      #pragma unroll
      for (int n = 0; n < 4; ++n) {
        const int col = wcol * 64 + n * 16 + lr;
        const float bs = bias[colbase + col];
        #pragma unroll
        for (int m = 0; m < 4; ++m)
          #pragma unroll
          for (int j = 0; j < 4; ++j)
            T32[(m * 16 + lk * 4 + j) * 132 + col] = acc[m][n][j] + bs;
      }
    }
    __syncthreads();
    const int rl = tid >> 2, q = tid & 3;
    const long grow = rowbase + ch * 64 + rl;
    float4 v[8];
    #pragma unroll
    for (int i = 0; i < 8; ++i)
      v[i] = *(const float4*)&T32[rl * 132 + q * 4 + i * 16];
    {
      const int mi = (int)grow;
      const int b_ = mi / NWIN, wi = mi - b_ * NWIN;
      const int w  = b_ & 63;
      const int hr = (w >> 3) * WSZ + wi / WSZ;
      const int wc2 = (w & 7) * WSZ + wi % WSZ;
      const int hf = (hr + SSH) % HIMG;
      const int wf = (wc2 + SSH) % WIMG;
      const long pix = (long)(b_ >> 6) * (HIMG * WIMG) + hf * WIMG + wf;
      const float* arow = aux + pix * CH;
      float* xrow = outf + pix * CH;
      float sum = 0.f, sq = 0.f;
      #pragma unroll
      for (int i = 0; i < 8; ++i) {
        const float4 ax = *(const float4*)(arow + q * 4 + i * 16);
        float4 tv = v[i];
        tv.x += ax.x; tv.y += ax.y; tv.z += ax.z; tv.w += ax.w;
        v[i] = tv;
        *(float4*)(xrow + q * 4 + i * 16) = tv;
        sum += tv.x + tv.y + tv.z + tv.w;
        sq  += tv.x * tv.x + tv.y * tv.y + tv.z * tv.z + tv.w * tv.w;
      }
      sum += __shfl_xor(sum, 1); sq += __shfl_xor(sq, 1);
      sum += __shfl_xor(sum, 2); sq += __shfl_xor(sq, 2);
      const float mean = sum * (1.0f / CH);
      const float inv  = rsqrtf(sq * (1.0f / CH) - mean * mean + 1e-5f);
      u16* mrow = outb + pix * CH;
      #pragma unroll
      for (int i2 = 0; i2 < 4; ++i2) {
        const float4 a = v[2 * i2], b = v[2 * i2 + 1];
        const float4 ga = *(const float4*)(g2 + q * 4 + (2 * i2) * 16);
        const float4 gb = *(const float4*)(g2 + q * 4 + (2 * i2 + 1) * 16);
        const float4 ba = *(const float4*)(b2 + q * 4 + (2 * i2) * 16);
        const float4 bb = *(const float4*)(b2 + q * 4 + (2 * i2 + 1) * 16);
        uint2 pkA, pkB;
        pkA.x = pack2((a.x - mean) * inv * ga.x + ba.x, (a.y - mean) * inv * ga.y + ba.y);
        pkA.y = pack2((a.z - mean) * inv * ga.z + ba.z, (a.w - mean) * inv * ga.w + ba.w);
        pkB.x = pack2((b.x - mean) * inv * gb.x + bb.x, (b.y - mean) * inv * gb.y + bb.y);
        pkB.y = pack2((b.z - mean) * inv * gb.z + bb.z, (b.w - mean) * inv * gb.w + bb.w);
        *(uint2*)(mrow + q * 4 + (2 * i2) * 16) = pkA;
        *(uint2*)(mrow + q * 4 + (2 * i2 + 1) * 16) = pkB;
      }
    }
    if (ch == 0) __syncthreads();
  }
}

// ---------------------------------------------------------------------------
// FUSED MLP v2: swapped stage-1 MFMA (H^T frags -> row-major ushort4 writes),
// coalesced weight fragments, double-buffered H, ONE barrier per hb.
//   stage1(hb): H[tok][hc] = GELU(m @ W1 strip) via mfma(w1f, m-frag)
//   stage2(hb): out += H @ W2 strip, A = ds_read_b128 of H, B = w2f frags.
// ---------------------------------------------------------------------------
#define HS 72
__global__ __launch_bounds__(256, 2) void mlp_kernel(
    const u16* __restrict__ m, const u16* __restrict__ w1f, const float* __restrict__ b1,
    const u16* __restrict__ w2f, const float* __restrict__ b2,
    const float* __restrict__ x1, float* __restrict__ outp)
{
  __shared__ __align__(16) char smem[69632];
  u16* sa = (u16*)smem;                 // [128][128] m-tile, swizzle16
  u16* H  = (u16*)(smem + 32768);       // [2][128][HS]
  float* T32 = (float*)(smem + 32768);  // epilogue overlay [64][132]
  const int tid = threadIdx.x;
  const int wv = tid >> 6, lane = tid & 63;
  const int lr = lane & 15, lk = lane >> 4;
  const int whid = wv >> 1, wtok = wv & 1;   // stage1 roles
  const int wrow = wv >> 1, wcol = wv & 1;   // stage2 roles
  const long rowbase = (long)blockIdx.x * 128;

  #pragma unroll
  for (int it = 0; it < 8; ++it) {
    const int c = it * 256 + tid;
    const int r = c >> 4, s = c & 15;
    const int k8 = s ^ (r & 15);
    __builtin_amdgcn_global_load_lds((const void*)(m + (rowbase + r) * CH + k8 * 8),
                                     (void*)(sa + c * 8), 16, 0, 0);
  }
  __syncthreads();

  f32x4 oad[4][4];
  #pragma unroll
  for (int a = 0; a < 4; ++a)
    #pragma unroll
    for (int b = 0; b < 4; ++b)
      oad[a][b] = (f32x4){0.f, 0.f, 0.f, 0.f};

  auto stage1 = [&](int hb, u16* Hbuf) {
    f32x4 c1[2][4];                       // [mt_h][nt]
    #pragma unroll
    for (int a = 0; a < 2; ++a)
      #pragma unroll
      for (int b = 0; b < 4; ++b)
        c1[a][b] = (f32x4){0.f, 0.f, 0.f, 0.f};
    #pragma unroll
    for (int kk = 0; kk < 4; ++kk) {
      bf16x8 a1[2];
      #pragma unroll
      for (int mt_h = 0; mt_h < 2; ++mt_h) {
        const int c16 = hb * 4 + whid * 2 + mt_h;
        a1[mt_h] = *(const bf16x8*)(w1f + ((c16 * 4 + kk) * 64 + lane) * 8);
      }
      bf16x8 bmv[4];
      #pragma unroll
      for (int nt = 0; nt < 4; ++nt) {
        const int r = wtok * 64 + nt * 16 + lr;
        bmv[nt] = *(const bf16x8*)(sa + r * 128 + (((kk * 4 + lk) ^ (r & 15)) << 3));
      }
      #pragma unroll
      for (int mt_h = 0; mt_h < 2; ++mt_h)
        #pragma unroll
        for (int nt = 0; nt < 4; ++nt)
          c1[mt_h][nt] = __builtin_amdgcn_mfma_f32_16x16x32_bf16(a1[mt_h], bmv[nt], c1[mt_h][nt], 0, 0, 0);
    }
    #pragma unroll
    for (int mt_h = 0; mt_h < 2; ++mt_h) {
      const int hc0 = whid * 32 + mt_h * 16 + lk * 4;
      const float4 bs = *(const float4*)(b1 + hb * 64 + hc0);
      #pragma unroll
      for (int nt = 0; nt < 4; ++nt) {
        const int tok = wtok * 64 + nt * 16 + lr;
        const ushort4 pk = make_ushort4(
            f2b(gelu(c1[mt_h][nt][0] + bs.x)), f2b(gelu(c1[mt_h][nt][1] + bs.y)),
            f2b(gelu(c1[mt_h][nt][2] + bs.z)), f2b(gelu(c1[mt_h][nt][3] + bs.w)));
        *(ushort4*)&Hbuf[tok * HS + hc0] = pk;
      }
    }
  };

  auto stage2 = [&](int hb, const u16* Hbuf) {
    #pragma unroll
    for (int kk2 = 0; kk2 < 2; ++kk2) {
      bf16x8 a2[4];
      #pragma unroll
      for (int mt = 0; mt < 4; ++mt)
        a2[mt] = *(const bf16x8*)&Hbuf[(wrow * 64 + mt * 16 + lr) * HS + kk2 * 32 + lk * 8];
      #pragma unroll
      for (int nf2 = 0; nf2 < 4; ++nf2) {
        const int o16 = wcol * 4 + nf2;
        const bf16x8 bw = *(const bf16x8*)(w2f + (((o16 * 8 + hb) * 2 + kk2) * 64 + lane) * 8);
        #pragma unroll
        for (int mt = 0; mt < 4; ++mt)
          oad[mt][nf2] = __builtin_amdgcn_mfma_f32_16x16x32_bf16(a2[mt], bw, oad[mt][nf2], 0, 0, 0);
      }
    }
  };

  stage1(0, H);
  __syncthreads();
  for (int hb = 0; hb < 8; ++hb) {
    if (hb < 7) stage1(hb + 1, H + ((hb + 1) & 1) * 128 * HS);
    stage2(hb, H + (hb & 1) * 128 * HS);
    __syncthreads();
  }

  // ---- epilogue: transpose + bias + x1 residual -> f32 out ----
  #pragma unroll
  for (int ch = 0; ch < 2; ++ch) {
    if (wrow == ch) {
      #pragma unroll
      for (int n = 0; n < 4; ++n) {
        const int col = wcol * 64 + n * 16 + lr;
        const float bs = b2[col];
        #pragma unroll
        for (int mt = 0; mt < 4; ++mt)
          #pragma unroll
          for (int j = 0; j < 4; ++j)
            T32[(mt * 16 + lk * 4 + j) * 132 + col] = oad[mt][n][j] + bs;
      }
    }
    __syncthreads();
    const int rl = tid >> 2, q = tid & 3;
    const long grow = rowbase + ch * 64 + rl;
    const float* arow = x1 + grow * CH;
    float* orow = outp + grow * CH;
    #pragma unroll
    for (int i = 0; i < 8; ++i) {
      float4 v = *(const float4*)&T32[rl * 132 + q * 4 + i * 16];
      const float4 ax = *(const float4*)(arow + q * 4 + i * 16);
      v.x += ax.x; v.y += ax.y; v.z += ax.z; v.w += ax.w;
      *(float4*)(orow + q * 4 + i * 16) = v;
    }
    if (ch == 0) __syncthreads();
  }
}

// ---------------------------------------------------------------------------
extern "C" void kernel_launch(void* const* d_in, const int* in_sizes, int n_in,
                              void* d_out, int out_size, void* d_ws, size_t ws_size,
                              hipStream_t stream)
{
  const float* x       = (const float*)d_in[0];
  const float* prompts = (const float*)d_in[1];
  const float* n1g     = (const float*)d_in[2];
  const float* n1b     = (const float*)d_in[3];
  const float* qkv_w   = (const float*)d_in[4];
  const float* qkv_b   = (const float*)d_in[5];
  const float* qkv_la  = (const float*)d_in[6];
  const float* qkv_lb  = (const float*)d_in[7];
  const float* rpb     = (const float*)d_in[8];
  const float* proj_w  = (const float*)d_in[9];
  const float* proj_b  = (const float*)d_in[10];
  const float* proj_la = (const float*)d_in[11];
  const float* proj_lb = (const float*)d_in[12];
  const float* n2g     = (const float*)d_in[13];
  const float* n2b     = (const float*)d_in[14];
  const float* fc1_w   = (const float*)d_in[15];
  const float* fc1_b   = (const float*)d_in[16];
  const float* fc1_la  = (const float*)d_in[17];
  const float* fc1_lb  = (const float*)d_in[18];
  const float* fc2_w   = (const float*)d_in[19];
  const float* fc2_b   = (const float*)d_in[20];
  const float* fc2_la  = (const float*)d_in[21];
  const float* fc2_lb  = (const float*)d_in[22];

  // workspace: [wqf|wprojT|w1f|w2f = 196608 u16] [bm 65536 f32] | buffers
  char* ws = (char*)d_ws;
  u16* wT     = (u16*)ws;
  u16* wqf    = wT;
  u16* wprojT = wT + 49152;
  u16* w1f    = wT + 65536;
  u16* w2f    = wT + 131072;
  float* bm   = (float*)(ws + 393216);
  char* p = ws + 393216 + 262144;
  u16* tbuf  = (u16*)p;                       p += (size_t)MWIN * CH * 2;
  u16* aobuf = (u16*)p;                       p += (size_t)MPIX * CH * 2;
  float* x1buf = (float*)p;                   p += (size_t)MPIX * CH * 4;
  u16* mbuf  = (u16*)p;

  fuse_all_kernel<<<768, 256, 0, stream>>>(
      qkv_w, qkv_la, qkv_lb, proj_w, proj_la, proj_lb,
      fc1_w, fc1_la, fc1_lb, fc2_w, fc2_la, fc2_lb, wT);

  bm_kernel<<<256, 256, 0, stream>>>(rpb, bm);

  ln1_gather_kernel<<<MWIN / 4, 256, 0, stream>>>(x, prompts, n1g, n1b, tbuf);

  qkv_attn_kernel<<<BWIN, 256, 0, stream>>>(tbuf, wqf, qkv_b, bm, aobuf);

  gemm_kernel<128, 128, 1><<<dim3(MPIX / 128, 1), 256, 0, stream>>>(
      aobuf, wprojT, proj_b, x, n2g, n2b, x1buf, mbuf);

  mlp_kernel<<<MPIX / 128, 256, 0, stream>>>(
      mbuf, w1f, fc1_b, w2f, fc2_b, x1buf, (float*)d_out);
}

// Round 9
// 192.380 us; speedup vs baseline: 1.6101x; 1.1342x over previous
//
#include <hip/hip_runtime.h>

typedef unsigned short u16;
typedef unsigned int   u32;
typedef short bf16x8 __attribute__((ext_vector_type(8)));
typedef short bf16x4 __attribute__((ext_vector_type(4)));
typedef float f32x4  __attribute__((ext_vector_type(4)));

#define HIMG 56
#define WIMG 56
#define CH   128
#define NHEADS 4
#define WSZ  7
#define SSH  3
#define PP   10
#define HIDD 512
#define NWIN 49          // window tokens
#define NTOK 59          // P + NWIN
#define BWIN 2048        // B * NW
#define DH   32          // head dim
#define MWIN 120832      // BWIN * NTOK
#define MPIX 100352      // B * 56 * 56

__device__ __forceinline__ u16 f2b(float f) {
  u32 u = __float_as_uint(f);
  u += 0x7fffu + ((u >> 16) & 1u);
  return (u16)(u >> 16);
}
__device__ __forceinline__ u32 pack2(float a, float b) {
  return (u32)f2b(a) | ((u32)f2b(b) << 16);
}
// fast exact-GELU: Abramowitz-Stegun 7.1.26 erf (max err 1.5e-7) — R7-proven
__device__ __forceinline__ float gelu(float x) {
  const float z = fabsf(x) * 0.70710678118654752f;
  const float t = 1.0f / (1.0f + 0.3275911f * z);
  const float p = t * (0.254829592f + t * (-0.284496736f + t * (1.421413741f +
                  t * (-1.453152027f + t * 1.061405429f))));
  const float erfz = copysignf(1.0f - p * __expf(-z * z), x);
  return 0.5f * x * (1.0f + erfz);
}

// ---------------------------------------------------------------------------
// Fold LoRA into effective weights (R8-proven fragment layouts).
// ---------------------------------------------------------------------------
__global__ void fuse_all_kernel(
    const float* __restrict__ qw,  const float* __restrict__ qa,  const float* __restrict__ qb,
    const float* __restrict__ pw,  const float* __restrict__ pa,  const float* __restrict__ pb,
    const float* __restrict__ f1w, const float* __restrict__ f1a, const float* __restrict__ f1b,
    const float* __restrict__ f2w, const float* __restrict__ f2a, const float* __restrict__ f2b2,
    u16* __restrict__ out)
{
  int idx = blockIdx.x * 256 + threadIdx.x;
  if (idx >= 196608) return;
  int n, k, Nc;
  const float *w, *la, *lb;
  if (idx < 49152) {                    // wqf
    const int li = idx;
    const int j = li & 7, lane = (li >> 3) & 63, kk = (li >> 9) & 3, c16 = li >> 11;
    n = c16 * 16 + (lane & 15);
    k = kk * 32 + (lane >> 4) * 8 + j;
    w = qw; la = qa; lb = qb; Nc = 384;
  } else if (idx < 65536) {             // wprojT [n][k]
    const int li = idx - 49152;
    n = li >> 7; k = li & 127;
    w = pw; la = pa; lb = pb; Nc = 128;
  } else if (idx < 131072) {            // w1f
    const int li = idx - 65536;
    const int j = li & 7, lane = (li >> 3) & 63, kk = (li >> 9) & 3, c16 = li >> 11;
    n = c16 * 16 + (lane & 15);
    k = kk * 32 + (lane >> 4) * 8 + j;
    w = f1w; la = f1a; lb = f1b; Nc = 512;
  } else {                              // w2f
    const int li = idx - 131072;
    const int j = li & 7, lane = (li >> 3) & 63, kk2 = (li >> 9) & 1, hb = (li >> 10) & 7, o16 = li >> 13;
    n = o16 * 16 + (lane & 15);
    k = hb * 64 + kk2 * 32 + (lane >> 4) * 8 + j;
    w = f2w; la = f2a; lb = f2b2; Nc = 128;
  }
  float s = w[k * Nc + n];
  #pragma unroll
  for (int r = 0; r < 4; ++r) s += la[k * 4 + r] * lb[r * Nc + n];
  out[idx] = f2b(s);
}

// ---------------------------------------------------------------------------
// Precompute bias+mask table bm[type][h][64][64] f32.
// ---------------------------------------------------------------------------
__global__ void bm_kernel(const float* __restrict__ rpb, float* __restrict__ bm)
{
  const int idx = blockIdx.x * 256 + threadIdx.x;   // 65536
  const int j = idx & 63, i = (idx >> 6) & 63, h = (idx >> 12) & 3, type = idx >> 14;
  float v = 0.f;
  if (i < 49) {
    if (j >= 59) v = -1e30f;
    else if (j >= PP) {
      const int jw = j - PP;
      const int ih = i / 7, iw = i - ih * 7, jh = jw / 7, jw2 = jw - jh * 7;
      v = rpb[((ih - jh + 6) * 13 + (iw - jw2 + 6)) * NHEADS + h];
      const int wh7 = type >> 1, ww7 = type & 1;
      const int mi = 3 * (wh7 ? (ih < 4 ? 1 : 2) : 0) + (ww7 ? (iw < 4 ? 1 : 2) : 0);
      const int mj = 3 * (wh7 ? (jh < 4 ? 1 : 2) : 0) + (ww7 ? (jw2 < 4 ? 1 : 2) : 0);
      if (mi != mj) v -= 100.f;
    }
  }
  bm[idx] = v;
}

// ---------------------------------------------------------------------------
// LN1 + roll(-3,-3) + window partition + prompt concat -> t (MWIN x 128) bf16
// ---------------------------------------------------------------------------
__global__ __launch_bounds__(256) void ln1_gather_kernel(
    const float* __restrict__ x, const float* __restrict__ prompts,
    const float* __restrict__ g, const float* __restrict__ bb,
    u16* __restrict__ t)
{
  const int tok  = blockIdx.x * 4 + (threadIdx.x >> 6);
  const int lane = threadIdx.x & 63;
  const int b_ = tok / NTOK, n = tok - b_ * NTOK;
  u32* dst = (u32*)(t + (size_t)tok * CH) + lane;
  if (n < PP) {
    const int b = b_ >> 6;
    const float2 v = *(const float2*)(prompts + ((size_t)b * PP + n) * CH + lane * 2);
    *dst = pack2(v.x, v.y);
    return;
  }
  const int w  = b_ & 63;
  const int wi = n - PP;
  const int hr = (w >> 3) * WSZ + wi / WSZ;
  const int wc = (w & 7) * WSZ + wi % WSZ;
  const int hs  = (hr + SSH) % HIMG;
  const int ws2 = (wc + SSH) % WIMG;
  const float2 v = *(const float2*)(x + ((size_t)(b_ >> 6) * (HIMG * WIMG) + hs * WIMG + ws2) * CH + lane * 2);
  float s = v.x + v.y, s2 = v.x * v.x + v.y * v.y;
  #pragma unroll
  for (int o = 32; o > 0; o >>= 1) { s += __shfl_xor(s, o); s2 += __shfl_xor(s2, o); }
  const float mean = s * (1.0f / CH);
  const float inv  = rsqrtf(s2 * (1.0f / CH) - mean * mean + 1e-5f);
  const float2 gg = *(const float2*)(g  + lane * 2);
  const float2 bv = *(const float2*)(bb + lane * 2);
  *dst = pack2((v.x - mean) * inv * gg.x + bv.x, (v.y - mean) * inv * gg.y + bv.y);
}

// ---------------------------------------------------------------------------
// FUSED qkv GEMM + window attention (R7/R8-proven). Now min 3 waves/EU.
// ---------------------------------------------------------------------------
#define QKS 136
#define VTS 72
#define PS  68
__global__ __launch_bounds__(256, 3) void qkv_attn_kernel(
    const u16* __restrict__ t, const u16* __restrict__ wqf,
    const float* __restrict__ qbias, const float* __restrict__ bm,
    u16* __restrict__ attn_out)
{
  __shared__ __align__(16) u16 smem[26624];   // 53248 B -> 3 blocks/CU
  u16* q_lds = smem;                // [64][QKS]
  u16* k_lds = smem + 64 * QKS;     // [64][QKS]
  u16* vt    = smem + 128 * QKS;    // [128][VTS]
  u16* p_lds = smem;                // overlay q+k: [4][64][PS]

  const int tid = threadIdx.x;
  const int wv = tid >> 6, lane = tid & 63;
  const int lr = lane & 15, lk = lane >> 4;
  const int b_ = blockIdx.x;
  const long tbase = (long)b_ * NTOK;

  // ---- phase 1: qkv ----
  bf16x8 af[4][4];
  #pragma unroll
  for (int mt = 0; mt < 4; ++mt) {
    int tok = mt * 16 + lr; if (tok > 58) tok = 58;
    #pragma unroll
    for (int kk = 0; kk < 4; ++kk)
      af[mt][kk] = *(const bf16x8*)(t + (tbase + tok) * CH + kk * 32 + lk * 8);
  }
  #pragma unroll
  for (int nf = 0; nf < 6; ++nf) {
    const int c = wv * 96 + nf * 16 + lr;
    const int sel = wv * 6 + nf;
    bf16x8 bw[4];
    #pragma unroll
    for (int kk = 0; kk < 4; ++kk)
      bw[kk] = *(const bf16x8*)(wqf + ((sel * 4 + kk) * 64 + lane) * 8);
    f32x4 a4[4];
    #pragma unroll
    for (int mt = 0; mt < 4; ++mt) a4[mt] = (f32x4){0.f, 0.f, 0.f, 0.f};
    #pragma unroll
    for (int kk = 0; kk < 4; ++kk)
      #pragma unroll
      for (int mt = 0; mt < 4; ++mt)
        a4[mt] = __builtin_amdgcn_mfma_f32_16x16x32_bf16(af[mt][kk], bw[kk], a4[mt], 0, 0, 0);
    const float bs = qbias[c];
    #pragma unroll
    for (int mt = 0; mt < 4; ++mt) {
      const int tok0 = mt * 16 + lk * 4;
      if (sel < 8) {
        #pragma unroll
        for (int rg = 0; rg < 4; ++rg)
          q_lds[(tok0 + rg) * QKS + c] = f2b(a4[mt][rg] + bs);
      } else if (sel < 16) {
        #pragma unroll
        for (int rg = 0; rg < 4; ++rg)
          k_lds[(tok0 + rg) * QKS + (c - 128)] = f2b(a4[mt][rg] + bs);
      } else {
        ushort4 pk = make_ushort4(f2b(a4[mt][0] + bs), f2b(a4[mt][1] + bs),
                                  f2b(a4[mt][2] + bs), f2b(a4[mt][3] + bs));
        *(ushort4*)&vt[(c - 256) * VTS + tok0] = pk;
      }
    }
  }
  __syncthreads();

  // ---- phase 2: attention, wave = head h ----
  const int h = wv;
  const int w = b_ & 63;
  const int type = (((w >> 3) == 7) ? 2 : 0) + (((w & 7) == 7) ? 1 : 0);
  const float scale = 0.17677669529663687f;

  bf16x8 kf[4], qf[4];
  #pragma unroll
  for (int t4 = 0; t4 < 4; ++t4) {
    kf[t4] = *(const bf16x8*)&k_lds[(t4 * 16 + lr) * QKS + h * DH + lk * 8];
    int tq = PP + t4 * 16 + lr; if (tq > 63) tq = 63;
    qf[t4] = *(const bf16x8*)&q_lds[tq * QKS + h * DH + lk * 8];
  }
  f32x4 sacc[4][4];
  #pragma unroll
  for (int a = 0; a < 4; ++a)
    #pragma unroll
    for (int b = 0; b < 4; ++b)
      sacc[a][b] = (f32x4){0.f, 0.f, 0.f, 0.f};
  #pragma unroll
  for (int mtj = 0; mtj < 4; ++mtj)
    #pragma unroll
    for (int nti = 0; nti < 4; ++nti)
      sacc[mtj][nti] = __builtin_amdgcn_mfma_f32_16x16x32_bf16(kf[mtj], qf[nti], sacc[mtj][nti], 0, 0, 0);

  const float* bmh = bm + (size_t)(type * NHEADS + h) * 64 * 64;
  #pragma unroll
  for (int nti = 0; nti < 4; ++nti) {
    const int i = nti * 16 + lr;
    float sv[16];
    #pragma unroll
    for (int mtj = 0; mtj < 4; ++mtj) {
      const float4 bmv = *(const float4*)(bmh + i * 64 + mtj * 16 + lk * 4);
      sv[mtj * 4 + 0] = sacc[mtj][nti][0] * scale + bmv.x;
      sv[mtj * 4 + 1] = sacc[mtj][nti][1] * scale + bmv.y;
      sv[mtj * 4 + 2] = sacc[mtj][nti][2] * scale + bmv.z;
      sv[mtj * 4 + 3] = sacc[mtj][nti][3] * scale + bmv.w;
    }
    float mx = sv[0];
    #pragma unroll
    for (int q = 1; q < 16; ++q) mx = fmaxf(mx, sv[q]);
    mx = fmaxf(mx, __shfl_xor(mx, 16));
    mx = fmaxf(mx, __shfl_xor(mx, 32));
    float sum = 0.f;
    #pragma unroll
    for (int q = 0; q < 16; ++q) { sv[q] = __expf(sv[q] - mx); sum += sv[q]; }
    sum += __shfl_xor(sum, 16);
    sum += __shfl_xor(sum, 32);
    const float inv = 1.0f / sum;
    #pragma unroll
    for (int mtj = 0; mtj < 4; ++mtj) {
      sacc[mtj][nti][0] = sv[mtj * 4 + 0] * inv;
      sacc[mtj][nti][1] = sv[mtj * 4 + 1] * inv;
      sacc[mtj][nti][2] = sv[mtj * 4 + 2] * inv;
      sacc[mtj][nti][3] = sv[mtj * 4 + 3] * inv;
    }
  }
  __syncthreads();

  u16* ph = p_lds + h * 64 * PS;
  #pragma unroll
  for (int nti = 0; nti < 4; ++nti) {
    const int i = nti * 16 + lr;
    #pragma unroll
    for (int mtj = 0; mtj < 4; ++mtj) {
      const ushort4 pk = make_ushort4(f2b(sacc[mtj][nti][0]), f2b(sacc[mtj][nti][1]),
                                      f2b(sacc[mtj][nti][2]), f2b(sacc[mtj][nti][3]));
      *(ushort4*)&ph[i * PS + mtj * 16 + lk * 4] = pk;
    }
  }
  __syncthreads();

  f32x4 oacc[4][2];
  #pragma unroll
  for (int a = 0; a < 4; ++a) { oacc[a][0] = (f32x4){0,0,0,0}; oacc[a][1] = (f32x4){0,0,0,0}; }
  #pragma unroll
  for (int ks = 0; ks < 2; ++ks) {
    bf16x8 pa[4];
    #pragma unroll
    for (int mt = 0; mt < 4; ++mt) {
      const u16* pr = &ph[(mt * 16 + lr) * PS + ks * 32 + lk * 8];
      const bf16x4 lo = *(const bf16x4*)pr;
      const bf16x4 hi = *(const bf16x4*)(pr + 4);
      pa[mt] = __builtin_shufflevector(lo, hi, 0, 1, 2, 3, 4, 5, 6, 7);
    }
    bf16x8 bv[2];
    #pragma unroll
    for (int nd = 0; nd < 2; ++nd)
      bv[nd] = *(const bf16x8*)&vt[(h * DH + nd * 16 + lr) * VTS + ks * 32 + lk * 8];
    #pragma unroll
    for (int mt = 0; mt < 4; ++mt)
      #pragma unroll
      for (int nd = 0; nd < 2; ++nd)
        oacc[mt][nd] = __builtin_amdgcn_mfma_f32_16x16x32_bf16(pa[mt], bv[nd], oacc[mt][nd], 0, 0, 0);
  }

  #pragma unroll
  for (int mt = 0; mt < 4; ++mt)
    #pragma unroll
    for (int rg = 0; rg < 4; ++rg) {
      const int i = mt * 16 + lk * 4 + rg;
      ph[i * PS + lr]      = f2b(oacc[mt][0][rg]);
      ph[i * PS + 16 + lr] = f2b(oacc[mt][1][rg]);
    }
  __syncthreads();
  if (lane < NWIN) {
    const u16* src = &ph[lane * PS];
    u16* dst = attn_out + ((size_t)b_ * NWIN + lane) * CH + h * DH;
    #pragma unroll
    for (int c = 0; c < 8; ++c)
      *(uint2*)(dst + c * 4) = *(const uint2*)(src + c * 4);
  }
}

// ---------------------------------------------------------------------------
// proj GEMM (R6-validated): MODE 1 = window-reverse + residual -> x1 f32
// AND fused LN2 -> bf16 mbuf.
// ---------------------------------------------------------------------------
template<int KTOT, int NCOLT, int MODE>
__global__ __launch_bounds__(256, 4) void gemm_kernel(
    const u16* __restrict__ A, const u16* __restrict__ WT,
    const float* __restrict__ bias, const float* __restrict__ aux,
    const float* __restrict__ g2, const float* __restrict__ b2,
    float* __restrict__ outf, u16* __restrict__ outb)
{
  __shared__ __align__(16) char smem[34816];
  u16* sa = (u16*)smem;
  u16* sb = (u16*)(smem + 16384);
  const int tid = threadIdx.x;
  const int wv = tid >> 6, lane = tid & 63;
  const int lr = lane & 15, lk = lane >> 4;
  const int wrow = wv >> 1, wcol = wv & 1;
  const long rowbase = (long)blockIdx.x * 128;
  const int colbase = blockIdx.y * 128;

  f32x4 acc[4][4];
  #pragma unroll
  for (int m = 0; m < 4; ++m)
    #pragma unroll
    for (int n = 0; n < 4; ++n)
      acc[m][n] = (f32x4){0.f, 0.f, 0.f, 0.f};

  for (int kb = 0; kb < KTOT; kb += 64) {
    #pragma unroll
    for (int it = 0; it < 4; ++it) {
      const int c = wv * 256 + it * 64 + lane;
      const int r = c >> 3, s = c & 7;
      const int k8 = s ^ (r & 7);
      __builtin_amdgcn_global_load_lds((const void*)(A + (rowbase + r) * KTOT + kb + k8 * 8),
                                       (void*)(sa + c * 8), 16, 0, 0);
      __builtin_amdgcn_global_load_lds((const void*)(WT + (long)(colbase + r) * KTOT + kb + k8 * 8),
                                       (void*)(sb + c * 8), 16, 0, 0);
    }
    __syncthreads();
    const char* la = (const char*)sa;
    const char* lb = (const char*)sb;
    #pragma unroll
    for (int k32 = 0; k32 < 2; ++k32) {
      bf16x8 af[4], bfv[4];
      #pragma unroll
      for (int m = 0; m < 4; ++m) {
        const int r = wrow * 64 + m * 16 + lr;
        af[m] = *(const bf16x8*)(la + r * 128 + (((k32 * 4 + lk) ^ (r & 7)) << 4));
      }
      #pragma unroll
      for (int n = 0; n < 4; ++n) {
        const int r = wcol * 64 + n * 16 + lr;
        bfv[n] = *(const bf16x8*)(lb + r * 128 + (((k32 * 4 + lk) ^ (r & 7)) << 4));
      }
      #pragma unroll
      for (int m = 0; m < 4; ++m)
        #pragma unroll
        for (int n = 0; n < 4; ++n)
          acc[m][n] = __builtin_amdgcn_mfma_f32_16x16x32_bf16(af[m], bfv[n], acc[m][n], 0, 0, 0);
    }
    __syncthreads();
  }

  float* T32 = (float*)smem;
  #pragma unroll
  for (int ch = 0; ch < 2; ++ch) {
    if (wrow == ch) {
      #pragma unroll
      for (int n = 0; n < 4; ++n) {
        const int col = wcol * 64 + n * 16 + lr;
        const float bs = bias[colbase + col];
        #pragma unroll
        for (int m = 0; m < 4; ++m)
          #pragma unroll
          for (int j = 0; j < 4; ++j)
            T32[(m * 16 + lk * 4 + j) * 132 + col] = acc[m][n][j] + bs;
      }
    }
    __syncthreads();
    const int rl = tid >> 2, q = tid & 3;
    const long grow = rowbase + ch * 64 + rl;
    float4 v[8];
    #pragma unroll
    for (int i = 0; i < 8; ++i)
      v[i] = *(const float4*)&T32[rl * 132 + q * 4 + i * 16];
    {
      const int mi = (int)grow;
      const int b_ = mi / NWIN, wi = mi - b_ * NWIN;
      const int w  = b_ & 63;
      const int hr = (w >> 3) * WSZ + wi / WSZ;
      const int wc2 = (w & 7) * WSZ + wi % WSZ;
      const int hf = (hr + SSH) % HIMG;
      const int wf = (wc2 + SSH) % WIMG;
      const long pix = (long)(b_ >> 6) * (HIMG * WIMG) + hf * WIMG + wf;
      const float* arow = aux + pix * CH;
      float* xrow = outf + pix * CH;
      float sum = 0.f, sq = 0.f;
      #pragma unroll
      for (int i = 0; i < 8; ++i) {
        const float4 ax = *(const float4*)(arow + q * 4 + i * 16);
        float4 tv = v[i];
        tv.x += ax.x; tv.y += ax.y; tv.z += ax.z; tv.w += ax.w;
        v[i] = tv;
        *(float4*)(xrow + q * 4 + i * 16) = tv;
        sum += tv.x + tv.y + tv.z + tv.w;
        sq  += tv.x * tv.x + tv.y * tv.y + tv.z * tv.z + tv.w * tv.w;
      }
      sum += __shfl_xor(sum, 1); sq += __shfl_xor(sq, 1);
      sum += __shfl_xor(sum, 2); sq += __shfl_xor(sq, 2);
      const float mean = sum * (1.0f / CH);
      const float inv  = rsqrtf(sq * (1.0f / CH) - mean * mean + 1e-5f);
      u16* mrow = outb + pix * CH;
      #pragma unroll
      for (int i2 = 0; i2 < 4; ++i2) {
        const float4 a = v[2 * i2], b = v[2 * i2 + 1];
        const float4 ga = *(const float4*)(g2 + q * 4 + (2 * i2) * 16);
        const float4 gb = *(const float4*)(g2 + q * 4 + (2 * i2 + 1) * 16);
        const float4 ba = *(const float4*)(b2 + q * 4 + (2 * i2) * 16);
        const float4 bb = *(const float4*)(b2 + q * 4 + (2 * i2 + 1) * 16);
        uint2 pkA, pkB;
        pkA.x = pack2((a.x - mean) * inv * ga.x + ba.x, (a.y - mean) * inv * ga.y + ba.y);
        pkA.y = pack2((a.z - mean) * inv * ga.z + ba.z, (a.w - mean) * inv * ga.w + ba.w);
        pkB.x = pack2((b.x - mean) * inv * gb.x + bb.x, (b.y - mean) * inv * gb.y + bb.y);
        pkB.y = pack2((b.z - mean) * inv * gb.z + bb.z, (b.w - mean) * inv * gb.w + bb.w);
        *(uint2*)(mrow + q * 4 + (2 * i2) * 16) = pkA;
        *(uint2*)(mrow + q * 4 + (2 * i2 + 1) * 16) = pkB;
      }
    }
    if (ch == 0) __syncthreads();
  }
}

// ---------------------------------------------------------------------------
// FUSED MLP v3: BM=64 rows/block, 4 blocks/CU (34KB LDS, launch_bounds(256,4)).
// stage1(hb): wave wv computes hidden strip c16 = hb*4+wv (16 wide, 64 tok)
//             via swapped mfma(w1f, m-frag); GELU -> H[tok][68] ushort4.
// stage2(hb): wave wv computes out cols [wv*32,+32): A = H rows (b64 pairs),
//             B = w2f frags. H double-buffered, one barrier per hb.
// ---------------------------------------------------------------------------
#define HS 68
__global__ __launch_bounds__(256, 4) void mlp_kernel(
    const u16* __restrict__ m, const u16* __restrict__ w1f, const float* __restrict__ b1,
    const u16* __restrict__ w2f, const float* __restrict__ b2,
    const float* __restrict__ x1, float* __restrict__ outp)
{
  __shared__ __align__(16) char smem[34816];
  u16* sa = (u16*)smem;                 // [64][128] m-tile, swizzle16 (16KB)
  u16* H  = (u16*)(smem + 16384);       // [2][64][HS] = 17408B
  float* T32 = (float*)smem;            // epilogue overlay [64][132] = 33792B
  const int tid = threadIdx.x;
  const int wv = tid >> 6, lane = tid & 63;
  const int lr = lane & 15, lk = lane >> 4;
  const long rowbase = (long)blockIdx.x * 64;

  #pragma unroll
  for (int it = 0; it < 4; ++it) {
    const int c = it * 256 + tid;
    const int r = c >> 4, s = c & 15;
    const int k8 = s ^ (r & 15);
    __builtin_amdgcn_global_load_lds((const void*)(m + (rowbase + r) * CH + k8 * 8),
                                     (void*)(sa + c * 8), 16, 0, 0);
  }
  __syncthreads();

  f32x4 oad[4][2];   // [mt over 64 tok][nf2 over 2x16 cols]
  #pragma unroll
  for (int a = 0; a < 4; ++a) { oad[a][0] = (f32x4){0,0,0,0}; oad[a][1] = (f32x4){0,0,0,0}; }

  auto stage1 = [&](int hb, u16* Hbuf) {
    f32x4 c1[4];                          // [nt]
    #pragma unroll
    for (int a = 0; a < 4; ++a) c1[a] = (f32x4){0.f, 0.f, 0.f, 0.f};
    #pragma unroll
    for (int kk = 0; kk < 4; ++kk) {
      const int c16 = hb * 4 + wv;
      const bf16x8 a1 = *(const bf16x8*)(w1f + ((c16 * 4 + kk) * 64 + lane) * 8);
      bf16x8 bmv[4];
      #pragma unroll
      for (int nt = 0; nt < 4; ++nt) {
        const int r = nt * 16 + lr;
        bmv[nt] = *(const bf16x8*)(sa + r * 128 + (((kk * 4 + lk) ^ (r & 15)) << 3));
      }
      #pragma unroll
      for (int nt = 0; nt < 4; ++nt)
        c1[nt] = __builtin_amdgcn_mfma_f32_16x16x32_bf16(a1, bmv[nt], c1[nt], 0, 0, 0);
    }
    const int hc0 = wv * 16 + lk * 4;
    const float4 bs = *(const float4*)(b1 + hb * 64 + hc0);
    #pragma unroll
    for (int nt = 0; nt < 4; ++nt) {
      const int tok = nt * 16 + lr;
      const ushort4 pk = make_ushort4(
          f2b(gelu(c1[nt][0] + bs.x)), f2b(gelu(c1[nt][1] + bs.y)),
          f2b(gelu(c1[nt][2] + bs.z)), f2b(gelu(c1[nt][3] + bs.w)));
      *(ushort4*)&Hbuf[tok * HS + hc0] = pk;
    }
  };

  auto stage2 = [&](int hb, const u16* Hbuf) {
    #pragma unroll
    for (int kk2 = 0; kk2 < 2; ++kk2) {
      bf16x8 a2[4];
      #pragma unroll
      for (int mt = 0; mt < 4; ++mt) {
        const u16* pr = &Hbuf[(mt * 16 + lr) * HS + kk2 * 32 + lk * 8];
        const bf16x4 lo = *(const bf16x4*)pr;
        const bf16x4 hi = *(const bf16x4*)(pr + 4);
        a2[mt] = __builtin_shufflevector(lo, hi, 0, 1, 2, 3, 4, 5, 6, 7);
      }
      #pragma unroll
      for (int nf2 = 0; nf2 < 2; ++nf2) {
        const int o16 = wv * 2 + nf2;
        const bf16x8 bw = *(const bf16x8*)(w2f + (((o16 * 8 + hb) * 2 + kk2) * 64 + lane) * 8);
        #pragma unroll
        for (int mt = 0; mt < 4; ++mt)
          oad[mt][nf2] = __builtin_amdgcn_mfma_f32_16x16x32_bf16(a2[mt], bw, oad[mt][nf2], 0, 0, 0);
      }
    }
  };

  u16* H0 = H;
  u16* H1 = H + 64 * HS;
  stage1(0, H0);
  __syncthreads();
  for (int hb = 0; hb < 8; ++hb) {
    u16* cur = (hb & 1) ? H1 : H0;
    u16* nxt = (hb & 1) ? H0 : H1;
    if (hb < 7) stage1(hb + 1, nxt);
    stage2(hb, cur);
    __syncthreads();
  }

  // ---- epilogue: single pass (64 rows) ----
  #pragma unroll
  for (int nf2 = 0; nf2 < 2; ++nf2) {
    const int col = wv * 32 + nf2 * 16 + lr;
    const float bs = b2[col];
    #pragma unroll
    for (int mt = 0; mt < 4; ++mt)
      #pragma unroll
      for (int j = 0; j < 4; ++j)
        T32[(mt * 16 + lk * 4 + j) * 132 + col] = oad[mt][nf2][j] + bs;
  }
  __syncthreads();
  const int rl = tid >> 2, q = tid & 3;
  const long grow = rowbase + rl;
  const float* arow = x1 + grow * CH;
  float* orow = outp + grow * CH;
  #pragma unroll
  for (int i = 0; i < 8; ++i) {
    float4 v = *(const float4*)&T32[rl * 132 + q * 4 + i * 16];
    const float4 ax = *(const float4*)(arow + q * 4 + i * 16);
    v.x += ax.x; v.y += ax.y; v.z += ax.z; v.w += ax.w;
    *(float4*)(orow + q * 4 + i * 16) = v;
  }
}

// ---------------------------------------------------------------------------
extern "C" void kernel_launch(void* const* d_in, const int* in_sizes, int n_in,
                              void* d_out, int out_size, void* d_ws, size_t ws_size,
                              hipStream_t stream)
{
  const float* x       = (const float*)d_in[0];
  const float* prompts = (const float*)d_in[1];
  const float* n1g     = (const float*)d_in[2];
  const float* n1b     = (const float*)d_in[3];
  const float* qkv_w   = (const float*)d_in[4];
  const float* qkv_b   = (const float*)d_in[5];
  const float* qkv_la  = (const float*)d_in[6];
  const float* qkv_lb  = (const float*)d_in[7];
  const float* rpb     = (const float*)d_in[8];
  const float* proj_w  = (const float*)d_in[9];
  const float* proj_b  = (const float*)d_in[10];
  const float* proj_la = (const float*)d_in[11];
  const float* proj_lb = (const float*)d_in[12];
  const float* n2g     = (const float*)d_in[13];
  const float* n2b     = (const float*)d_in[14];
  const float* fc1_w   = (const float*)d_in[15];
  const float* fc1_b   = (const float*)d_in[16];
  const float* fc1_la  = (const float*)d_in[17];
  const float* fc1_lb  = (const float*)d_in[18];
  const float* fc2_w   = (const float*)d_in[19];
  const float* fc2_b   = (const float*)d_in[20];
  const float* fc2_la  = (const float*)d_in[21];
  const float* fc2_lb  = (const float*)d_in[22];

  // workspace: [wqf|wprojT|w1f|w2f = 196608 u16] [bm 65536 f32] | buffers
  char* ws = (char*)d_ws;
  u16* wT     = (u16*)ws;
  u16* wqf    = wT;
  u16* wprojT = wT + 49152;
  u16* w1f    = wT + 65536;
  u16* w2f    = wT + 131072;
  float* bm   = (float*)(ws + 393216);
  char* p = ws + 393216 + 262144;
  u16* tbuf  = (u16*)p;                       p += (size_t)MWIN * CH * 2;
  u16* aobuf = (u16*)p;                       p += (size_t)MPIX * CH * 2;
  float* x1buf = (float*)p;                   p += (size_t)MPIX * CH * 4;
  u16* mbuf  = (u16*)p;

  fuse_all_kernel<<<768, 256, 0, stream>>>(
      qkv_w, qkv_la, qkv_lb, proj_w, proj_la, proj_lb,
      fc1_w, fc1_la, fc1_lb, fc2_w, fc2_la, fc2_lb, wT);

  bm_kernel<<<256, 256, 0, stream>>>(rpb, bm);

  ln1_gather_kernel<<<MWIN / 4, 256, 0, stream>>>(x, prompts, n1g, n1b, tbuf);

  qkv_attn_kernel<<<BWIN, 256, 0, stream>>>(tbuf, wqf, qkv_b, bm, aobuf);

  gemm_kernel<128, 128, 1><<<dim3(MPIX / 128, 1), 256, 0, stream>>>(
      aobuf, wprojT, proj_b, x, n2g, n2b, x1buf, mbuf);

  mlp_kernel<<<MPIX / 64, 256, 0, stream>>>(
      mbuf, w1f, fc1_b, w2f, fc2_b, x1buf, (float*)d_out);
}

// Round 10
// 189.788 us; speedup vs baseline: 1.6321x; 1.0137x over previous
//
#include <hip/hip_runtime.h>

typedef unsigned short u16;
typedef unsigned int   u32;
typedef short bf16x8 __attribute__((ext_vector_type(8)));
typedef short bf16x4 __attribute__((ext_vector_type(4)));
typedef float f32x4  __attribute__((ext_vector_type(4)));

#define HIMG 56
#define WIMG 56
#define CH   128
#define NHEADS 4
#define WSZ  7
#define SSH  3
#define PP   10
#define HIDD 512
#define NWIN 49          // window tokens
#define NTOK 59          // P + NWIN
#define BWIN 2048        // B * NW
#define DH   32          // head dim
#define MWIN 120832      // BWIN * NTOK
#define MPIX 100352      // B * 56 * 56

__device__ __forceinline__ u16 f2b(float f) {
  u32 u = __float_as_uint(f);
  u += 0x7fffu + ((u >> 16) & 1u);
  return (u16)(u >> 16);
}
__device__ __forceinline__ u32 pack2(float a, float b) {
  return (u32)f2b(a) | ((u32)f2b(b) << 16);
}
// fast exact-GELU: Abramowitz-Stegun 7.1.26 erf (max err 1.5e-7) — R7-proven
__device__ __forceinline__ float gelu(float x) {
  const float z = fabsf(x) * 0.70710678118654752f;
  const float t = 1.0f / (1.0f + 0.3275911f * z);
  const float p = t * (0.254829592f + t * (-0.284496736f + t * (1.421413741f +
                  t * (-1.453152027f + t * 1.061405429f))));
  const float erfz = copysignf(1.0f - p * __expf(-z * z), x);
  return 0.5f * x * (1.0f + erfz);
}

// ---------------------------------------------------------------------------
// Fold LoRA into effective weights (R8-proven fragment layouts).
// ---------------------------------------------------------------------------
__global__ void fuse_all_kernel(
    const float* __restrict__ qw,  const float* __restrict__ qa,  const float* __restrict__ qb,
    const float* __restrict__ pw,  const float* __restrict__ pa,  const float* __restrict__ pb,
    const float* __restrict__ f1w, const float* __restrict__ f1a, const float* __restrict__ f1b,
    const float* __restrict__ f2w, const float* __restrict__ f2a, const float* __restrict__ f2b2,
    u16* __restrict__ out)
{
  int idx = blockIdx.x * 256 + threadIdx.x;
  if (idx >= 196608) return;
  int n, k, Nc;
  const float *w, *la, *lb;
  if (idx < 49152) {                    // wqf
    const int li = idx;
    const int j = li & 7, lane = (li >> 3) & 63, kk = (li >> 9) & 3, c16 = li >> 11;
    n = c16 * 16 + (lane & 15);
    k = kk * 32 + (lane >> 4) * 8 + j;
    w = qw; la = qa; lb = qb; Nc = 384;
  } else if (idx < 65536) {             // wprojT [n][k]
    const int li = idx - 49152;
    n = li >> 7; k = li & 127;
    w = pw; la = pa; lb = pb; Nc = 128;
  } else if (idx < 131072) {            // w1f
    const int li = idx - 65536;
    const int j = li & 7, lane = (li >> 3) & 63, kk = (li >> 9) & 3, c16 = li >> 11;
    n = c16 * 16 + (lane & 15);
    k = kk * 32 + (lane >> 4) * 8 + j;
    w = f1w; la = f1a; lb = f1b; Nc = 512;
  } else {                              // w2f
    const int li = idx - 131072;
    const int j = li & 7, lane = (li >> 3) & 63, kk2 = (li >> 9) & 1, hb = (li >> 10) & 7, o16 = li >> 13;
    n = o16 * 16 + (lane & 15);
    k = hb * 64 + kk2 * 32 + (lane >> 4) * 8 + j;
    w = f2w; la = f2a; lb = f2b2; Nc = 128;
  }
  float s = w[k * Nc + n];
  #pragma unroll
  for (int r = 0; r < 4; ++r) s += la[k * 4 + r] * lb[r * Nc + n];
  out[idx] = f2b(s);
}

// ---------------------------------------------------------------------------
// Precompute bias+mask table bm[type][h][64][64] f32.
// ---------------------------------------------------------------------------
__global__ void bm_kernel(const float* __restrict__ rpb, float* __restrict__ bm)
{
  const int idx = blockIdx.x * 256 + threadIdx.x;   // 65536
  const int j = idx & 63, i = (idx >> 6) & 63, h = (idx >> 12) & 3, type = idx >> 14;
  float v = 0.f;
  if (i < 49) {
    if (j >= 59) v = -1e30f;
    else if (j >= PP) {
      const int jw = j - PP;
      const int ih = i / 7, iw = i - ih * 7, jh = jw / 7, jw2 = jw - jh * 7;
      v = rpb[((ih - jh + 6) * 13 + (iw - jw2 + 6)) * NHEADS + h];
      const int wh7 = type >> 1, ww7 = type & 1;
      const int mi = 3 * (wh7 ? (ih < 4 ? 1 : 2) : 0) + (ww7 ? (iw < 4 ? 1 : 2) : 0);
      const int mj = 3 * (wh7 ? (jh < 4 ? 1 : 2) : 0) + (ww7 ? (jw2 < 4 ? 1 : 2) : 0);
      if (mi != mj) v -= 100.f;
    }
  }
  bm[idx] = v;
}

// ---------------------------------------------------------------------------
// LN1 + roll(-3,-3) + window partition + prompt concat -> t (MWIN x 128) bf16
// ---------------------------------------------------------------------------
__global__ __launch_bounds__(256) void ln1_gather_kernel(
    const float* __restrict__ x, const float* __restrict__ prompts,
    const float* __restrict__ g, const float* __restrict__ bb,
    u16* __restrict__ t)
{
  const int tok  = blockIdx.x * 4 + (threadIdx.x >> 6);
  const int lane = threadIdx.x & 63;
  const int b_ = tok / NTOK, n = tok - b_ * NTOK;
  u32* dst = (u32*)(t + (size_t)tok * CH) + lane;
  if (n < PP) {
    const int b = b_ >> 6;
    const float2 v = *(const float2*)(prompts + ((size_t)b * PP + n) * CH + lane * 2);
    *dst = pack2(v.x, v.y);
    return;
  }
  const int w  = b_ & 63;
  const int wi = n - PP;
  const int hr = (w >> 3) * WSZ + wi / WSZ;
  const int wc = (w & 7) * WSZ + wi % WSZ;
  const int hs  = (hr + SSH) % HIMG;
  const int ws2 = (wc + SSH) % WIMG;
  const float2 v = *(const float2*)(x + ((size_t)(b_ >> 6) * (HIMG * WIMG) + hs * WIMG + ws2) * CH + lane * 2);
  float s = v.x + v.y, s2 = v.x * v.x + v.y * v.y;
  #pragma unroll
  for (int o = 32; o > 0; o >>= 1) { s += __shfl_xor(s, o); s2 += __shfl_xor(s2, o); }
  const float mean = s * (1.0f / CH);
  const float inv  = rsqrtf(s2 * (1.0f / CH) - mean * mean + 1e-5f);
  const float2 gg = *(const float2*)(g  + lane * 2);
  const float2 bv = *(const float2*)(bb + lane * 2);
  *dst = pack2((v.x - mean) * inv * gg.x + bv.x, (v.y - mean) * inv * gg.y + bv.y);
}

// ---------------------------------------------------------------------------
// FUSED qkv GEMM + window attention (R7/R8-proven).
// ---------------------------------------------------------------------------
#define QKS 136
#define VTS 72
#define PS  68
__global__ __launch_bounds__(256, 3) void qkv_attn_kernel(
    const u16* __restrict__ t, const u16* __restrict__ wqf,
    const float* __restrict__ qbias, const float* __restrict__ bm,
    u16* __restrict__ attn_out)
{
  __shared__ __align__(16) u16 smem[26624];   // 53248 B -> 3 blocks/CU
  u16* q_lds = smem;                // [64][QKS]
  u16* k_lds = smem + 64 * QKS;     // [64][QKS]
  u16* vt    = smem + 128 * QKS;    // [128][VTS]
  u16* p_lds = smem;                // overlay q+k: [4][64][PS]

  const int tid = threadIdx.x;
  const int wv = tid >> 6, lane = tid & 63;
  const int lr = lane & 15, lk = lane >> 4;
  const int b_ = blockIdx.x;
  const long tbase = (long)b_ * NTOK;

  // ---- phase 1: qkv ----
  bf16x8 af[4][4];
  #pragma unroll
  for (int mt = 0; mt < 4; ++mt) {
    int tok = mt * 16 + lr; if (tok > 58) tok = 58;
    #pragma unroll
    for (int kk = 0; kk < 4; ++kk)
      af[mt][kk] = *(const bf16x8*)(t + (tbase + tok) * CH + kk * 32 + lk * 8);
  }
  #pragma unroll
  for (int nf = 0; nf < 6; ++nf) {
    const int c = wv * 96 + nf * 16 + lr;
    const int sel = wv * 6 + nf;
    bf16x8 bw[4];
    #pragma unroll
    for (int kk = 0; kk < 4; ++kk)
      bw[kk] = *(const bf16x8*)(wqf + ((sel * 4 + kk) * 64 + lane) * 8);
    f32x4 a4[4];
    #pragma unroll
    for (int mt = 0; mt < 4; ++mt) a4[mt] = (f32x4){0.f, 0.f, 0.f, 0.f};
    #pragma unroll
    for (int kk = 0; kk < 4; ++kk)
      #pragma unroll
      for (int mt = 0; mt < 4; ++mt)
        a4[mt] = __builtin_amdgcn_mfma_f32_16x16x32_bf16(af[mt][kk], bw[kk], a4[mt], 0, 0, 0);
    const float bs = qbias[c];
    #pragma unroll
    for (int mt = 0; mt < 4; ++mt) {
      const int tok0 = mt * 16 + lk * 4;
      if (sel < 8) {
        #pragma unroll
        for (int rg = 0; rg < 4; ++rg)
          q_lds[(tok0 + rg) * QKS + c] = f2b(a4[mt][rg] + bs);
      } else if (sel < 16) {
        #pragma unroll
        for (int rg = 0; rg < 4; ++rg)
          k_lds[(tok0 + rg) * QKS + (c - 128)] = f2b(a4[mt][rg] + bs);
      } else {
        ushort4 pk = make_ushort4(f2b(a4[mt][0] + bs), f2b(a4[mt][1] + bs),
                                  f2b(a4[mt][2] + bs), f2b(a4[mt][3] + bs));
        *(ushort4*)&vt[(c - 256) * VTS + tok0] = pk;
      }
    }
  }
  __syncthreads();

  // ---- phase 2: attention, wave = head h ----
  const int h = wv;
  const int w = b_ & 63;
  const int type = (((w >> 3) == 7) ? 2 : 0) + (((w & 7) == 7) ? 1 : 0);
  const float scale = 0.17677669529663687f;

  bf16x8 kf[4], qf[4];
  #pragma unroll
  for (int t4 = 0; t4 < 4; ++t4) {
    kf[t4] = *(const bf16x8*)&k_lds[(t4 * 16 + lr) * QKS + h * DH + lk * 8];
    int tq = PP + t4 * 16 + lr; if (tq > 63) tq = 63;
    qf[t4] = *(const bf16x8*)&q_lds[tq * QKS + h * DH + lk * 8];
  }
  f32x4 sacc[4][4];
  #pragma unroll
  for (int a = 0; a < 4; ++a)
    #pragma unroll
    for (int b = 0; b < 4; ++b)
      sacc[a][b] = (f32x4){0.f, 0.f, 0.f, 0.f};
  #pragma unroll
  for (int mtj = 0; mtj < 4; ++mtj)
    #pragma unroll
    for (int nti = 0; nti < 4; ++nti)
      sacc[mtj][nti] = __builtin_amdgcn_mfma_f32_16x16x32_bf16(kf[mtj], qf[nti], sacc[mtj][nti], 0, 0, 0);

  const float* bmh = bm + (size_t)(type * NHEADS + h) * 64 * 64;
  #pragma unroll
  for (int nti = 0; nti < 4; ++nti) {
    const int i = nti * 16 + lr;
    float sv[16];
    #pragma unroll
    for (int mtj = 0; mtj < 4; ++mtj) {
      const float4 bmv = *(const float4*)(bmh + i * 64 + mtj * 16 + lk * 4);
      sv[mtj * 4 + 0] = sacc[mtj][nti][0] * scale + bmv.x;
      sv[mtj * 4 + 1] = sacc[mtj][nti][1] * scale + bmv.y;
      sv[mtj * 4 + 2] = sacc[mtj][nti][2] * scale + bmv.z;
      sv[mtj * 4 + 3] = sacc[mtj][nti][3] * scale + bmv.w;
    }
    float mx = sv[0];
    #pragma unroll
    for (int q = 1; q < 16; ++q) mx = fmaxf(mx, sv[q]);
    mx = fmaxf(mx, __shfl_xor(mx, 16));
    mx = fmaxf(mx, __shfl_xor(mx, 32));
    float sum = 0.f;
    #pragma unroll
    for (int q = 0; q < 16; ++q) { sv[q] = __expf(sv[q] - mx); sum += sv[q]; }
    sum += __shfl_xor(sum, 16);
    sum += __shfl_xor(sum, 32);
    const float inv = 1.0f / sum;
    #pragma unroll
    for (int mtj = 0; mtj < 4; ++mtj) {
      sacc[mtj][nti][0] = sv[mtj * 4 + 0] * inv;
      sacc[mtj][nti][1] = sv[mtj * 4 + 1] * inv;
      sacc[mtj][nti][2] = sv[mtj * 4 + 2] * inv;
      sacc[mtj][nti][3] = sv[mtj * 4 + 3] * inv;
    }
  }
  __syncthreads();

  u16* ph = p_lds + h * 64 * PS;
  #pragma unroll
  for (int nti = 0; nti < 4; ++nti) {
    const int i = nti * 16 + lr;
    #pragma unroll
    for (int mtj = 0; mtj < 4; ++mtj) {
      const ushort4 pk = make_ushort4(f2b(sacc[mtj][nti][0]), f2b(sacc[mtj][nti][1]),
                                      f2b(sacc[mtj][nti][2]), f2b(sacc[mtj][nti][3]));
      *(ushort4*)&ph[i * PS + mtj * 16 + lk * 4] = pk;
    }
  }
  __syncthreads();

  f32x4 oacc[4][2];
  #pragma unroll
  for (int a = 0; a < 4; ++a) { oacc[a][0] = (f32x4){0,0,0,0}; oacc[a][1] = (f32x4){0,0,0,0}; }
  #pragma unroll
  for (int ks = 0; ks < 2; ++ks) {
    bf16x8 pa[4];
    #pragma unroll
    for (int mt = 0; mt < 4; ++mt) {
      const u16* pr = &ph[(mt * 16 + lr) * PS + ks * 32 + lk * 8];
      const bf16x4 lo = *(const bf16x4*)pr;
      const bf16x4 hi = *(const bf16x4*)(pr + 4);
      pa[mt] = __builtin_shufflevector(lo, hi, 0, 1, 2, 3, 4, 5, 6, 7);
    }
    bf16x8 bv[2];
    #pragma unroll
    for (int nd = 0; nd < 2; ++nd)
      bv[nd] = *(const bf16x8*)&vt[(h * DH + nd * 16 + lr) * VTS + ks * 32 + lk * 8];
    #pragma unroll
    for (int mt = 0; mt < 4; ++mt)
      #pragma unroll
      for (int nd = 0; nd < 2; ++nd)
        oacc[mt][nd] = __builtin_amdgcn_mfma_f32_16x16x32_bf16(pa[mt], bv[nd], oacc[mt][nd], 0, 0, 0);
  }

  #pragma unroll
  for (int mt = 0; mt < 4; ++mt)
    #pragma unroll
    for (int rg = 0; rg < 4; ++rg) {
      const int i = mt * 16 + lk * 4 + rg;
      ph[i * PS + lr]      = f2b(oacc[mt][0][rg]);
      ph[i * PS + 16 + lr] = f2b(oacc[mt][1][rg]);
    }
  __syncthreads();
  if (lane < NWIN) {
    const u16* src = &ph[lane * PS];
    u16* dst = attn_out + ((size_t)b_ * NWIN + lane) * CH + h * DH;
    #pragma unroll
    for (int c = 0; c < 8; ++c)
      *(uint2*)(dst + c * 4) = *(const uint2*)(src + c * 4);
  }
}

// ---------------------------------------------------------------------------
// proj GEMM (R6-validated): MODE 1 = window-reverse + residual -> x1 f32
// AND fused LN2 -> bf16 mbuf.
// ---------------------------------------------------------------------------
template<int KTOT, int NCOLT, int MODE>
__global__ __launch_bounds__(256, 4) void gemm_kernel(
    const u16* __restrict__ A, const u16* __restrict__ WT,
    const float* __restrict__ bias, const float* __restrict__ aux,
    const float* __restrict__ g2, const float* __restrict__ b2,
    float* __restrict__ outf, u16* __restrict__ outb)
{
  __shared__ __align__(16) char smem[34816];
  u16* sa = (u16*)smem;
  u16* sb = (u16*)(smem + 16384);
  const int tid = threadIdx.x;
  const int wv = tid >> 6, lane = tid & 63;
  const int lr = lane & 15, lk = lane >> 4;
  const int wrow = wv >> 1, wcol = wv & 1;
  const long rowbase = (long)blockIdx.x * 128;
  const int colbase = blockIdx.y * 128;

  f32x4 acc[4][4];
  #pragma unroll
  for (int m = 0; m < 4; ++m)
    #pragma unroll
    for (int n = 0; n < 4; ++n)
      acc[m][n] = (f32x4){0.f, 0.f, 0.f, 0.f};

  for (int kb = 0; kb < KTOT; kb += 64) {
    #pragma unroll
    for (int it = 0; it < 4; ++it) {
      const int c = wv * 256 + it * 64 + lane;
      const int r = c >> 3, s = c & 7;
      const int k8 = s ^ (r & 7);
      __builtin_amdgcn_global_load_lds((const void*)(A + (rowbase + r) * KTOT + kb + k8 * 8),
                                       (void*)(sa + c * 8), 16, 0, 0);
      __builtin_amdgcn_global_load_lds((const void*)(WT + (long)(colbase + r) * KTOT + kb + k8 * 8),
                                       (void*)(sb + c * 8), 16, 0, 0);
    }
    __syncthreads();
    const char* la = (const char*)sa;
    const char* lb = (const char*)sb;
    #pragma unroll
    for (int k32 = 0; k32 < 2; ++k32) {
      bf16x8 af[4], bfv[4];
      #pragma unroll
      for (int m = 0; m < 4; ++m) {
        const int r = wrow * 64 + m * 16 + lr;
        af[m] = *(const bf16x8*)(la + r * 128 + (((k32 * 4 + lk) ^ (r & 7)) << 4));
      }
      #pragma unroll
      for (int n = 0; n < 4; ++n) {
        const int r = wcol * 64 + n * 16 + lr;
        bfv[n] = *(const bf16x8*)(lb + r * 128 + (((k32 * 4 + lk) ^ (r & 7)) << 4));
      }
      #pragma unroll
      for (int m = 0; m < 4; ++m)
        #pragma unroll
        for (int n = 0; n < 4; ++n)
          acc[m][n] = __builtin_amdgcn_mfma_f32_16x16x32_bf16(af[m], bfv[n], acc[m][n], 0, 0, 0);
    }
    __syncthreads();
  }

  float* T32 = (float*)smem;
  #pragma unroll
  for (int ch = 0; ch < 2; ++ch) {
    if (wrow == ch) {
      #pragma unroll
      for (int n = 0; n < 4; ++n) {
        const int col = wcol * 64 + n * 16 + lr;
        const float bs = bias[colbase + col];
        #pragma unroll
        for (int m = 0; m < 4; ++m)
          #pragma unroll
          for (int j = 0; j < 4; ++j)
            T32[(m * 16 + lk * 4 + j) * 132 + col] = acc[m][n][j] + bs;
      }
    }
    __syncthreads();
    const int rl = tid >> 2, q = tid & 3;
    const long grow = rowbase + ch * 64 + rl;
    float4 v[8];
    #pragma unroll
    for (int i = 0; i < 8; ++i)
      v[i] = *(const float4*)&T32[rl * 132 + q * 4 + i * 16];
    {
      const int mi = (int)grow;
      const int b_ = mi / NWIN, wi = mi - b_ * NWIN;
      const int w  = b_ & 63;
      const int hr = (w >> 3) * WSZ + wi / WSZ;
      const int wc2 = (w & 7) * WSZ + wi % WSZ;
      const int hf = (hr + SSH) % HIMG;
      const int wf = (wc2 + SSH) % WIMG;
      const long pix = (long)(b_ >> 6) * (HIMG * WIMG) + hf * WIMG + wf;
      const float* arow = aux + pix * CH;
      float* xrow = outf + pix * CH;
      float sum = 0.f, sq = 0.f;
      #pragma unroll
      for (int i = 0; i < 8; ++i) {
        const float4 ax = *(const float4*)(arow + q * 4 + i * 16);
        float4 tv = v[i];
        tv.x += ax.x; tv.y += ax.y; tv.z += ax.z; tv.w += ax.w;
        v[i] = tv;
        *(float4*)(xrow + q * 4 + i * 16) = tv;
        sum += tv.x + tv.y + tv.z + tv.w;
        sq  += tv.x * tv.x + tv.y * tv.y + tv.z * tv.z + tv.w * tv.w;
      }
      sum += __shfl_xor(sum, 1); sq += __shfl_xor(sq, 1);
      sum += __shfl_xor(sum, 2); sq += __shfl_xor(sq, 2);
      const float mean = sum * (1.0f / CH);
      const float inv  = rsqrtf(sq * (1.0f / CH) - mean * mean + 1e-5f);
      u16* mrow = outb + pix * CH;
      #pragma unroll
      for (int i2 = 0; i2 < 4; ++i2) {
        const float4 a = v[2 * i2], b = v[2 * i2 + 1];
        const float4 ga = *(const float4*)(g2 + q * 4 + (2 * i2) * 16);
        const float4 gb = *(const float4*)(g2 + q * 4 + (2 * i2 + 1) * 16);
        const float4 ba = *(const float4*)(b2 + q * 4 + (2 * i2) * 16);
        const float4 bb = *(const float4*)(b2 + q * 4 + (2 * i2 + 1) * 16);
        uint2 pkA, pkB;
        pkA.x = pack2((a.x - mean) * inv * ga.x + ba.x, (a.y - mean) * inv * ga.y + ba.y);
        pkA.y = pack2((a.z - mean) * inv * ga.z + ba.z, (a.w - mean) * inv * ga.w + ba.w);
        pkB.x = pack2((b.x - mean) * inv * gb.x + bb.x, (b.y - mean) * inv * gb.y + bb.y);
        pkB.y = pack2((b.z - mean) * inv * gb.z + bb.z, (b.w - mean) * inv * gb.w + bb.w);
        *(uint2*)(mrow + q * 4 + (2 * i2) * 16) = pkA;
        *(uint2*)(mrow + q * 4 + (2 * i2 + 1) * 16) = pkB;
      }
    }
    if (ch == 0) __syncthreads();
  }
}

// ---------------------------------------------------------------------------
// FUSED MLP v4: BM=32 rows/block, 8 blocks/CU (16.9KB LDS, launch_bounds(256,8))
// -> full 32-wave/CU occupancy to hide L2-weight + barrier latency.
// stage1(hb): wave wv computes hidden strip c16 = hb*4+wv over 32 tokens
//             via swapped mfma(w1f, m-frag); GELU -> H[tok][68] ushort4.
// stage2(hb): wave wv computes out cols [wv*32,+32): A = H rows (b64 pairs),
//             B = w2f frags. H double-buffered, one barrier per hb.
// ---------------------------------------------------------------------------
#define HS 68
__global__ __launch_bounds__(256, 8) void mlp_kernel(
    const u16* __restrict__ m, const u16* __restrict__ w1f, const float* __restrict__ b1,
    const u16* __restrict__ w2f, const float* __restrict__ b2,
    const float* __restrict__ x1, float* __restrict__ outp)
{
  __shared__ __align__(16) char smem[16896];
  u16* sa = (u16*)smem;                 // [32][128] m-tile, swizzle16 (8KB)
  u16* H  = (u16*)(smem + 8192);        // [2][32][HS] = 8704B
  float* T32 = (float*)smem;            // epilogue overlay [32][132] = 16896B
  const int tid = threadIdx.x;
  const int wv = tid >> 6, lane = tid & 63;
  const int lr = lane & 15, lk = lane >> 4;
  const long rowbase = (long)blockIdx.x * 32;

  #pragma unroll
  for (int it = 0; it < 2; ++it) {
    const int c = it * 256 + tid;
    const int r = c >> 4, s = c & 15;
    const int k8 = s ^ (r & 15);
    __builtin_amdgcn_global_load_lds((const void*)(m + (rowbase + r) * CH + k8 * 8),
                                     (void*)(sa + c * 8), 16, 0, 0);
  }
  __syncthreads();

  f32x4 oad[2][2];   // [mt over 32 tok][nf2 over 2x16 cols]
  #pragma unroll
  for (int a = 0; a < 2; ++a) { oad[a][0] = (f32x4){0,0,0,0}; oad[a][1] = (f32x4){0,0,0,0}; }

  auto stage1 = [&](int hb, u16* Hbuf) {
    f32x4 c1[2];                          // [nt over 32 tok]
    c1[0] = (f32x4){0.f, 0.f, 0.f, 0.f};
    c1[1] = (f32x4){0.f, 0.f, 0.f, 0.f};
    #pragma unroll
    for (int kk = 0; kk < 4; ++kk) {
      const int c16 = hb * 4 + wv;
      const bf16x8 a1 = *(const bf16x8*)(w1f + ((c16 * 4 + kk) * 64 + lane) * 8);
      bf16x8 bmv[2];
      #pragma unroll
      for (int nt = 0; nt < 2; ++nt) {
        const int r = nt * 16 + lr;
        bmv[nt] = *(const bf16x8*)(sa + r * 128 + (((kk * 4 + lk) ^ (r & 15)) << 3));
      }
      c1[0] = __builtin_amdgcn_mfma_f32_16x16x32_bf16(a1, bmv[0], c1[0], 0, 0, 0);
      c1[1] = __builtin_amdgcn_mfma_f32_16x16x32_bf16(a1, bmv[1], c1[1], 0, 0, 0);
    }
    const int hc0 = wv * 16 + lk * 4;
    const float4 bs = *(const float4*)(b1 + hb * 64 + hc0);
    #pragma unroll
    for (int nt = 0; nt < 2; ++nt) {
      const int tok = nt * 16 + lr;
      const ushort4 pk = make_ushort4(
          f2b(gelu(c1[nt][0] + bs.x)), f2b(gelu(c1[nt][1] + bs.y)),
          f2b(gelu(c1[nt][2] + bs.z)), f2b(gelu(c1[nt][3] + bs.w)));
      *(ushort4*)&Hbuf[tok * HS + hc0] = pk;
    }
  };

  auto stage2 = [&](int hb, const u16* Hbuf) {
    #pragma unroll
    for (int kk2 = 0; kk2 < 2; ++kk2) {
      bf16x8 a2[2];
      #pragma unroll
      for (int mt = 0; mt < 2; ++mt) {
        const u16* pr = &Hbuf[(mt * 16 + lr) * HS + kk2 * 32 + lk * 8];
        const bf16x4 lo = *(const bf16x4*)pr;
        const bf16x4 hi = *(const bf16x4*)(pr + 4);
        a2[mt] = __builtin_shufflevector(lo, hi, 0, 1, 2, 3, 4, 5, 6, 7);
      }
      #pragma unroll
      for (int nf2 = 0; nf2 < 2; ++nf2) {
        const int o16 = wv * 2 + nf2;
        const bf16x8 bw = *(const bf16x8*)(w2f + (((o16 * 8 + hb) * 2 + kk2) * 64 + lane) * 8);
        #pragma unroll
        for (int mt = 0; mt < 2; ++mt)
          oad[mt][nf2] = __builtin_amdgcn_mfma_f32_16x16x32_bf16(a2[mt], bw, oad[mt][nf2], 0, 0, 0);
      }
    }
  };

  u16* H0 = H;
  u16* H1 = H + 32 * HS;
  stage1(0, H0);
  __syncthreads();
  for (int hb = 0; hb < 8; ++hb) {
    u16* cur = (hb & 1) ? H1 : H0;
    u16* nxt = (hb & 1) ? H0 : H1;
    if (hb < 7) stage1(hb + 1, nxt);
    stage2(hb, cur);
    __syncthreads();
  }

  // ---- epilogue: transpose + bias, then residual + store (32 rows) ----
  #pragma unroll
  for (int nf2 = 0; nf2 < 2; ++nf2) {
    const int col = wv * 32 + nf2 * 16 + lr;
    const float bs = b2[col];
    #pragma unroll
    for (int mt = 0; mt < 2; ++mt)
      #pragma unroll
      for (int j = 0; j < 4; ++j)
        T32[(mt * 16 + lk * 4 + j) * 132 + col] = oad[mt][nf2][j] + bs;
  }
  __syncthreads();
  const int rl = tid >> 3, q = tid & 7;      // 32 rows x 8 threads/row
  const long grow = rowbase + rl;
  const float* arow = x1 + grow * CH;
  float* orow = outp + grow * CH;
  #pragma unroll
  for (int i = 0; i < 4; ++i) {
    float4 v = *(const float4*)&T32[rl * 132 + q * 4 + i * 32];
    const float4 ax = *(const float4*)(arow + q * 4 + i * 32);
    v.x += ax.x; v.y += ax.y; v.z += ax.z; v.w += ax.w;
    *(float4*)(orow + q * 4 + i * 32) = v;
  }
}

// ---------------------------------------------------------------------------
extern "C" void kernel_launch(void* const* d_in, const int* in_sizes, int n_in,
                              void* d_out, int out_size, void* d_ws, size_t ws_size,
                              hipStream_t stream)
{
  const float* x       = (const float*)d_in[0];
  const float* prompts = (const float*)d_in[1];
  const float* n1g     = (const float*)d_in[2];
  const float* n1b     = (const float*)d_in[3];
  const float* qkv_w   = (const float*)d_in[4];
  const float* qkv_b   = (const float*)d_in[5];
  const float* qkv_la  = (const float*)d_in[6];
  const float* qkv_lb  = (const float*)d_in[7];
  const float* rpb     = (const float*)d_in[8];
  const float* proj_w  = (const float*)d_in[9];
  const float* proj_b  = (const float*)d_in[10];
  const float* proj_la = (const float*)d_in[11];
  const float* proj_lb = (const float*)d_in[12];
  const float* n2g     = (const float*)d_in[13];
  const float* n2b     = (const float*)d_in[14];
  const float* fc1_w   = (const float*)d_in[15];
  const float* fc1_b   = (const float*)d_in[16];
  const float* fc1_la  = (const float*)d_in[17];
  const float* fc1_lb  = (const float*)d_in[18];
  const float* fc2_w   = (const float*)d_in[19];
  const float* fc2_b   = (const float*)d_in[20];
  const float* fc2_la  = (const float*)d_in[21];
  const float* fc2_lb  = (const float*)d_in[22];

  // workspace: [wqf|wprojT|w1f|w2f = 196608 u16] [bm 65536 f32] | buffers
  char* ws = (char*)d_ws;
  u16* wT     = (u16*)ws;
  u16* wqf    = wT;
  u16* wprojT = wT + 49152;
  u16* w1f    = wT + 65536;
  u16* w2f    = wT + 131072;
  float* bm   = (float*)(ws + 393216);
  char* p = ws + 393216 + 262144;
  u16* tbuf  = (u16*)p;                       p += (size_t)MWIN * CH * 2;
  u16* aobuf = (u16*)p;                       p += (size_t)MPIX * CH * 2;
  float* x1buf = (float*)p;                   p += (size_t)MPIX * CH * 4;
  u16* mbuf  = (u16*)p;

  fuse_all_kernel<<<768, 256, 0, stream>>>(
      qkv_w, qkv_la, qkv_lb, proj_w, proj_la, proj_lb,
      fc1_w, fc1_la, fc1_lb, fc2_w, fc2_la, fc2_lb, wT);

  bm_kernel<<<256, 256, 0, stream>>>(rpb, bm);

  ln1_gather_kernel<<<MWIN / 4, 256, 0, stream>>>(x, prompts, n1g, n1b, tbuf);

  qkv_attn_kernel<<<BWIN, 256, 0, stream>>>(tbuf, wqf, qkv_b, bm, aobuf);

  gemm_kernel<128, 128, 1><<<dim3(MPIX / 128, 1), 256, 0, stream>>>(
      aobuf, wprojT, proj_b, x, n2g, n2b, x1buf, mbuf);

  mlp_kernel<<<MPIX / 32, 256, 0, stream>>>(
      mbuf, w1f, fc1_b, w2f, fc2_b, x1buf, (float*)d_out);
}

// Round 11
// 160.632 us; speedup vs baseline: 1.9283x; 1.1815x over previous
//
#include <hip/hip_runtime.h>

typedef unsigned short u16;
typedef unsigned int   u32;
typedef short bf16x8 __attribute__((ext_vector_type(8)));
typedef short bf16x4 __attribute__((ext_vector_type(4)));
typedef float f32x4  __attribute__((ext_vector_type(4)));

#define HIMG 56
#define WIMG 56
#define CH   128
#define NHEADS 4
#define WSZ  7
#define SSH  3
#define PP   10
#define HIDD 512
#define NWIN 49          // window tokens
#define NTOK 59          // P + NWIN
#define BWIN 2048        // B * NW
#define DH   32          // head dim
#define MWIN 120832      // BWIN * NTOK
#define MPIX 100352      // B * 56 * 56

__device__ __forceinline__ u16 f2b(float f) {
  u32 u = __float_as_uint(f);
  u += 0x7fffu + ((u >> 16) & 1u);
  return (u16)(u >> 16);
}
__device__ __forceinline__ u32 pack2(float a, float b) {
  return (u32)f2b(a) | ((u32)f2b(b) << 16);
}
// fast exact-GELU: Abramowitz-Stegun 7.1.26 erf (max err 1.5e-7) — R7-proven
__device__ __forceinline__ float gelu(float x) {
  const float z = fabsf(x) * 0.70710678118654752f;
  const float t = 1.0f / (1.0f + 0.3275911f * z);
  const float p = t * (0.254829592f + t * (-0.284496736f + t * (1.421413741f +
                  t * (-1.453152027f + t * 1.061405429f))));
  const float erfz = copysignf(1.0f - p * __expf(-z * z), x);
  return 0.5f * x * (1.0f + erfz);
}

// ---------------------------------------------------------------------------
// Fold LoRA into effective weights. All in MFMA-fragment layout now:
//   wqf    [sel=24][kk=4][lane][8]      qkv B-frags
//   wprojf [c16=8][kk=4][lane][8]       proj B-frags
//   w1f    [c16=32][kk=4][lane][8]      fc1 A-frags (identity = hidden col)
//   w2f    [o16=8][hb=8][kk2=2][lane][8] fc2 B-frags
// frag elem (lane,j): identity = 16*c16 + (lane&15), k = kbase + (lane>>4)*8 + j
// ---------------------------------------------------------------------------
__global__ void fuse_all_kernel(
    const float* __restrict__ qw,  const float* __restrict__ qa,  const float* __restrict__ qb,
    const float* __restrict__ pw,  const float* __restrict__ pa,  const float* __restrict__ pb,
    const float* __restrict__ f1w, const float* __restrict__ f1a, const float* __restrict__ f1b,
    const float* __restrict__ f2w, const float* __restrict__ f2a, const float* __restrict__ f2b2,
    u16* __restrict__ out)
{
  int idx = blockIdx.x * 256 + threadIdx.x;
  if (idx >= 196608) return;
  int n, k, Nc;
  const float *w, *la, *lb;
  if (idx < 49152) {                    // wqf
    const int li = idx;
    const int j = li & 7, lane = (li >> 3) & 63, kk = (li >> 9) & 3, c16 = li >> 11;
    n = c16 * 16 + (lane & 15);
    k = kk * 32 + (lane >> 4) * 8 + j;
    w = qw; la = qa; lb = qb; Nc = 384;
  } else if (idx < 65536) {             // wprojf
    const int li = idx - 49152;
    const int j = li & 7, lane = (li >> 3) & 63, kk = (li >> 9) & 3, c16 = li >> 11;
    n = c16 * 16 + (lane & 15);
    k = kk * 32 + (lane >> 4) * 8 + j;
    w = pw; la = pa; lb = pb; Nc = 128;
  } else if (idx < 131072) {            // w1f
    const int li = idx - 65536;
    const int j = li & 7, lane = (li >> 3) & 63, kk = (li >> 9) & 3, c16 = li >> 11;
    n = c16 * 16 + (lane & 15);
    k = kk * 32 + (lane >> 4) * 8 + j;
    w = f1w; la = f1a; lb = f1b; Nc = 512;
  } else {                              // w2f
    const int li = idx - 131072;
    const int j = li & 7, lane = (li >> 3) & 63, kk2 = (li >> 9) & 1, hb = (li >> 10) & 7, o16 = li >> 13;
    n = o16 * 16 + (lane & 15);
    k = hb * 64 + kk2 * 32 + (lane >> 4) * 8 + j;
    w = f2w; la = f2a; lb = f2b2; Nc = 128;
  }
  float s = w[k * Nc + n];
  #pragma unroll
  for (int r = 0; r < 4; ++r) s += la[k * 4 + r] * lb[r * Nc + n];
  out[idx] = f2b(s);
}

// ---------------------------------------------------------------------------
// Precompute bias+mask table bm[type][h][64][64] f32.
// ---------------------------------------------------------------------------
__global__ void bm_kernel(const float* __restrict__ rpb, float* __restrict__ bm)
{
  const int idx = blockIdx.x * 256 + threadIdx.x;   // 65536
  const int j = idx & 63, i = (idx >> 6) & 63, h = (idx >> 12) & 3, type = idx >> 14;
  float v = 0.f;
  if (i < 49) {
    if (j >= 59) v = -1e30f;
    else if (j >= PP) {
      const int jw = j - PP;
      const int ih = i / 7, iw = i - ih * 7, jh = jw / 7, jw2 = jw - jh * 7;
      v = rpb[((ih - jh + 6) * 13 + (iw - jw2 + 6)) * NHEADS + h];
      const int wh7 = type >> 1, ww7 = type & 1;
      const int mi = 3 * (wh7 ? (ih < 4 ? 1 : 2) : 0) + (ww7 ? (iw < 4 ? 1 : 2) : 0);
      const int mj = 3 * (wh7 ? (jh < 4 ? 1 : 2) : 0) + (ww7 ? (jw2 < 4 ? 1 : 2) : 0);
      if (mi != mj) v -= 100.f;
    }
  }
  bm[idx] = v;
}

// ---------------------------------------------------------------------------
// LN1 + roll(-3,-3) + window partition + prompt concat -> t (MWIN x 128) bf16
// ---------------------------------------------------------------------------
__global__ __launch_bounds__(256) void ln1_gather_kernel(
    const float* __restrict__ x, const float* __restrict__ prompts,
    const float* __restrict__ g, const float* __restrict__ bb,
    u16* __restrict__ t)
{
  const int tok  = blockIdx.x * 4 + (threadIdx.x >> 6);
  const int lane = threadIdx.x & 63;
  const int b_ = tok / NTOK, n = tok - b_ * NTOK;
  u32* dst = (u32*)(t + (size_t)tok * CH) + lane;
  if (n < PP) {
    const int b = b_ >> 6;
    const float2 v = *(const float2*)(prompts + ((size_t)b * PP + n) * CH + lane * 2);
    *dst = pack2(v.x, v.y);
    return;
  }
  const int w  = b_ & 63;
  const int wi = n - PP;
  const int hr = (w >> 3) * WSZ + wi / WSZ;
  const int wc = (w & 7) * WSZ + wi % WSZ;
  const int hs  = (hr + SSH) % HIMG;
  const int ws2 = (wc + SSH) % WIMG;
  const float2 v = *(const float2*)(x + ((size_t)(b_ >> 6) * (HIMG * WIMG) + hs * WIMG + ws2) * CH + lane * 2);
  float s = v.x + v.y, s2 = v.x * v.x + v.y * v.y;
  #pragma unroll
  for (int o = 32; o > 0; o >>= 1) { s += __shfl_xor(s, o); s2 += __shfl_xor(s2, o); }
  const float mean = s * (1.0f / CH);
  const float inv  = rsqrtf(s2 * (1.0f / CH) - mean * mean + 1e-5f);
  const float2 gg = *(const float2*)(g  + lane * 2);
  const float2 bv = *(const float2*)(bb + lane * 2);
  *dst = pack2((v.x - mean) * inv * gg.x + bv.x, (v.y - mean) * inv * gg.y + bv.y);
}

// ---------------------------------------------------------------------------
// FUSED qkv GEMM + window attention (R7-R10 proven, unchanged).
// ---------------------------------------------------------------------------
#define QKS 136
#define VTS 72
#define PS  68
__global__ __launch_bounds__(256, 3) void qkv_attn_kernel(
    const u16* __restrict__ t, const u16* __restrict__ wqf,
    const float* __restrict__ qbias, const float* __restrict__ bm,
    u16* __restrict__ attn_out)
{
  __shared__ __align__(16) u16 smem[26624];   // 53248 B -> 3 blocks/CU
  u16* q_lds = smem;                // [64][QKS]
  u16* k_lds = smem + 64 * QKS;     // [64][QKS]
  u16* vt    = smem + 128 * QKS;    // [128][VTS]
  u16* p_lds = smem;                // overlay q+k: [4][64][PS]

  const int tid = threadIdx.x;
  const int wv = tid >> 6, lane = tid & 63;
  const int lr = lane & 15, lk = lane >> 4;
  const int b_ = blockIdx.x;
  const long tbase = (long)b_ * NTOK;

  // ---- phase 1: qkv ----
  bf16x8 af[4][4];
  #pragma unroll
  for (int mt = 0; mt < 4; ++mt) {
    int tok = mt * 16 + lr; if (tok > 58) tok = 58;
    #pragma unroll
    for (int kk = 0; kk < 4; ++kk)
      af[mt][kk] = *(const bf16x8*)(t + (tbase + tok) * CH + kk * 32 + lk * 8);
  }
  #pragma unroll
  for (int nf = 0; nf < 6; ++nf) {
    const int c = wv * 96 + nf * 16 + lr;
    const int sel = wv * 6 + nf;
    bf16x8 bw[4];
    #pragma unroll
    for (int kk = 0; kk < 4; ++kk)
      bw[kk] = *(const bf16x8*)(wqf + ((sel * 4 + kk) * 64 + lane) * 8);
    f32x4 a4[4];
    #pragma unroll
    for (int mt = 0; mt < 4; ++mt) a4[mt] = (f32x4){0.f, 0.f, 0.f, 0.f};
    #pragma unroll
    for (int kk = 0; kk < 4; ++kk)
      #pragma unroll
      for (int mt = 0; mt < 4; ++mt)
        a4[mt] = __builtin_amdgcn_mfma_f32_16x16x32_bf16(af[mt][kk], bw[kk], a4[mt], 0, 0, 0);
    const float bs = qbias[c];
    #pragma unroll
    for (int mt = 0; mt < 4; ++mt) {
      const int tok0 = mt * 16 + lk * 4;
      if (sel < 8) {
        #pragma unroll
        for (int rg = 0; rg < 4; ++rg)
          q_lds[(tok0 + rg) * QKS + c] = f2b(a4[mt][rg] + bs);
      } else if (sel < 16) {
        #pragma unroll
        for (int rg = 0; rg < 4; ++rg)
          k_lds[(tok0 + rg) * QKS + (c - 128)] = f2b(a4[mt][rg] + bs);
      } else {
        ushort4 pk = make_ushort4(f2b(a4[mt][0] + bs), f2b(a4[mt][1] + bs),
                                  f2b(a4[mt][2] + bs), f2b(a4[mt][3] + bs));
        *(ushort4*)&vt[(c - 256) * VTS + tok0] = pk;
      }
    }
  }
  __syncthreads();

  // ---- phase 2: attention, wave = head h ----
  const int h = wv;
  const int w = b_ & 63;
  const int type = (((w >> 3) == 7) ? 2 : 0) + (((w & 7) == 7) ? 1 : 0);
  const float scale = 0.17677669529663687f;

  bf16x8 kf[4], qf[4];
  #pragma unroll
  for (int t4 = 0; t4 < 4; ++t4) {
    kf[t4] = *(const bf16x8*)&k_lds[(t4 * 16 + lr) * QKS + h * DH + lk * 8];
    int tq = PP + t4 * 16 + lr; if (tq > 63) tq = 63;
    qf[t4] = *(const bf16x8*)&q_lds[tq * QKS + h * DH + lk * 8];
  }
  f32x4 sacc[4][4];
  #pragma unroll
  for (int a = 0; a < 4; ++a)
    #pragma unroll
    for (int b = 0; b < 4; ++b)
      sacc[a][b] = (f32x4){0.f, 0.f, 0.f, 0.f};
  #pragma unroll
  for (int mtj = 0; mtj < 4; ++mtj)
    #pragma unroll
    for (int nti = 0; nti < 4; ++nti)
      sacc[mtj][nti] = __builtin_amdgcn_mfma_f32_16x16x32_bf16(kf[mtj], qf[nti], sacc[mtj][nti], 0, 0, 0);

  const float* bmh = bm + (size_t)(type * NHEADS + h) * 64 * 64;
  #pragma unroll
  for (int nti = 0; nti < 4; ++nti) {
    const int i = nti * 16 + lr;
    float sv[16];
    #pragma unroll
    for (int mtj = 0; mtj < 4; ++mtj) {
      const float4 bmv = *(const float4*)(bmh + i * 64 + mtj * 16 + lk * 4);
      sv[mtj * 4 + 0] = sacc[mtj][nti][0] * scale + bmv.x;
      sv[mtj * 4 + 1] = sacc[mtj][nti][1] * scale + bmv.y;
      sv[mtj * 4 + 2] = sacc[mtj][nti][2] * scale + bmv.z;
      sv[mtj * 4 + 3] = sacc[mtj][nti][3] * scale + bmv.w;
    }
    float mx = sv[0];
    #pragma unroll
    for (int q = 1; q < 16; ++q) mx = fmaxf(mx, sv[q]);
    mx = fmaxf(mx, __shfl_xor(mx, 16));
    mx = fmaxf(mx, __shfl_xor(mx, 32));
    float sum = 0.f;
    #pragma unroll
    for (int q = 0; q < 16; ++q) { sv[q] = __expf(sv[q] - mx); sum += sv[q]; }
    sum += __shfl_xor(sum, 16);
    sum += __shfl_xor(sum, 32);
    const float inv = 1.0f / sum;
    #pragma unroll
    for (int mtj = 0; mtj < 4; ++mtj) {
      sacc[mtj][nti][0] = sv[mtj * 4 + 0] * inv;
      sacc[mtj][nti][1] = sv[mtj * 4 + 1] * inv;
      sacc[mtj][nti][2] = sv[mtj * 4 + 2] * inv;
      sacc[mtj][nti][3] = sv[mtj * 4 + 3] * inv;
    }
  }
  __syncthreads();

  u16* ph = p_lds + h * 64 * PS;
  #pragma unroll
  for (int nti = 0; nti < 4; ++nti) {
    const int i = nti * 16 + lr;
    #pragma unroll
    for (int mtj = 0; mtj < 4; ++mtj) {
      const ushort4 pk = make_ushort4(f2b(sacc[mtj][nti][0]), f2b(sacc[mtj][nti][1]),
                                      f2b(sacc[mtj][nti][2]), f2b(sacc[mtj][nti][3]));
      *(ushort4*)&ph[i * PS + mtj * 16 + lk * 4] = pk;
    }
  }
  __syncthreads();

  f32x4 oacc[4][2];
  #pragma unroll
  for (int a = 0; a < 4; ++a) { oacc[a][0] = (f32x4){0,0,0,0}; oacc[a][1] = (f32x4){0,0,0,0}; }
  #pragma unroll
  for (int ks = 0; ks < 2; ++ks) {
    bf16x8 pa[4];
    #pragma unroll
    for (int mt = 0; mt < 4; ++mt) {
      const u16* pr = &ph[(mt * 16 + lr) * PS + ks * 32 + lk * 8];
      const bf16x4 lo = *(const bf16x4*)pr;
      const bf16x4 hi = *(const bf16x4*)(pr + 4);
      pa[mt] = __builtin_shufflevector(lo, hi, 0, 1, 2, 3, 4, 5, 6, 7);
    }
    bf16x8 bv[2];
    #pragma unroll
    for (int nd = 0; nd < 2; ++nd)
      bv[nd] = *(const bf16x8*)&vt[(h * DH + nd * 16 + lr) * VTS + ks * 32 + lk * 8];
    #pragma unroll
    for (int mt = 0; mt < 4; ++mt)
      #pragma unroll
      for (int nd = 0; nd < 2; ++nd)
        oacc[mt][nd] = __builtin_amdgcn_mfma_f32_16x16x32_bf16(pa[mt], bv[nd], oacc[mt][nd], 0, 0, 0);
  }

  #pragma unroll
  for (int mt = 0; mt < 4; ++mt)
    #pragma unroll
    for (int rg = 0; rg < 4; ++rg) {
      const int i = mt * 16 + lk * 4 + rg;
      ph[i * PS + lr]      = f2b(oacc[mt][0][rg]);
      ph[i * PS + 16 + lr] = f2b(oacc[mt][1][rg]);
    }
  __syncthreads();
  if (lane < NWIN) {
    const u16* src = &ph[lane * PS];
    u16* dst = attn_out + ((size_t)b_ * NWIN + lane) * CH + h * DH;
    #pragma unroll
    for (int c = 0; c < 8; ++c)
      *(uint2*)(dst + c * 4) = *(const uint2*)(src + c * 4);
  }
}

// ---------------------------------------------------------------------------
// FUSED proj + LN2 + MLP. One block = 32 PIXEL rows; x1 and m never hit HBM.
//  A: gather window-permuted ao rows (inverse shift map) -> sa (swizzle16)
//  B: proj: 16 MFMA/wave, B-frags = wprojf
//  C: T32 transpose + x residual (coalesced) -> x1 in 16 VGPRs; LN2 via
//     8-thread shuffle; m -> sm (swizzle16)
//  D: R10-proven MLP stage1/stage2 double-buffered loop (reads sm)
//  E: T32 transpose + b2 bias + x1 regs -> out
// LDS 33792 B -> 4 blocks/CU.
// ---------------------------------------------------------------------------
#define HS 68
__global__ __launch_bounds__(256, 4) void proj_mlp_kernel(
    const u16* __restrict__ ao, const u16* __restrict__ wprojf,
    const float* __restrict__ pbias, const float* __restrict__ x,
    const float* __restrict__ g2, const float* __restrict__ b2,
    const u16* __restrict__ w1f, const float* __restrict__ b1,
    const u16* __restrict__ w2f, const float* __restrict__ b2f,
    float* __restrict__ outp)
{
  __shared__ __align__(16) char smem[33792];
  u16*   sa  = (u16*)smem;              // [32][128] gathered ao tile (phase A/B)
  float* T32 = (float*)smem;            // [32][132] transpose buffer (C, E)
  u16*   sm  = (u16*)(smem + 16896);    // [32][128] m tile, swizzle16
  u16*   H   = (u16*)(smem + 25088);    // [2][32][HS]
  const int tid = threadIdx.x;
  const int wv = tid >> 6, lane = tid & 63;
  const int lr = lane & 15, lk = lane >> 4;
  const long rowbase = (long)blockIdx.x * 32;

  // ---- A: gather ao rows (inverse window map), swizzle16 source ----
  #pragma unroll
  for (int it = 0; it < 2; ++it) {
    const int c = it * 256 + tid;
    const int r = c >> 4, s = c & 15;
    const int k8 = s ^ (r & 15);
    const int pix = (int)rowbase + r;
    const int b  = pix / 3136;
    const int rem = pix - b * 3136;
    const int hf = rem / 56, wf = rem - hf * 56;
    int hs = hf + 53; if (hs >= 56) hs -= 56;
    int ws2 = wf + 53; if (ws2 >= 56) ws2 -= 56;
    const int w  = (hs / 7) * 8 + (ws2 / 7);
    const int wi = (hs % 7) * 7 + (ws2 % 7);
    const long arow = ((long)b * 64 + w) * NWIN + wi;
    __builtin_amdgcn_global_load_lds((const void*)(ao + arow * CH + k8 * 8),
                                     (void*)(sa + c * 8), 16, 0, 0);
  }
  __syncthreads();

  // ---- B: proj MFMA (A = sa token rows, B = wprojf) ----
  f32x4 pacc[2][2];   // [mt tok-strip][nf col-strip]
  #pragma unroll
  for (int a = 0; a < 2; ++a) { pacc[a][0] = (f32x4){0,0,0,0}; pacc[a][1] = (f32x4){0,0,0,0}; }
  #pragma unroll
  for (int kk = 0; kk < 4; ++kk) {
    bf16x8 af[2];
    #pragma unroll
    for (int mt = 0; mt < 2; ++mt) {
      const int r = mt * 16 + lr;
      af[mt] = *(const bf16x8*)(sa + r * 128 + (((kk * 4 + lk) ^ (r & 15)) << 3));
    }
    #pragma unroll
    for (int nf = 0; nf < 2; ++nf) {
      const int c16 = wv * 2 + nf;
      const bf16x8 bw = *(const bf16x8*)(wprojf + ((c16 * 4 + kk) * 64 + lane) * 8);
      #pragma unroll
      for (int mt = 0; mt < 2; ++mt)
        pacc[mt][nf] = __builtin_amdgcn_mfma_f32_16x16x32_bf16(af[mt], bw, pacc[mt][nf], 0, 0, 0);
    }
  }
  __syncthreads();   // sa reads complete before T32 overlays it

  // ---- C: transpose + x residual + LN2 -> x1 regs + sm ----
  #pragma unroll
  for (int nf = 0; nf < 2; ++nf) {
    const int col = (wv * 2 + nf) * 16 + lr;
    const float bs = pbias[col];
    #pragma unroll
    for (int mt = 0; mt < 2; ++mt)
      #pragma unroll
      for (int j = 0; j < 4; ++j)
        T32[(mt * 16 + lk * 4 + j) * 132 + col] = pacc[mt][nf][j] + bs;
  }
  __syncthreads();
  const int rl = tid >> 3, q = tid & 7;      // 32 rows x 8 threads/row
  float4 xv[4];
  float sum = 0.f, sq = 0.f;
  {
    const float* xrow = x + (rowbase + rl) * CH;
    #pragma unroll
    for (int i = 0; i < 4; ++i) {
      float4 tv = *(const float4*)&T32[rl * 132 + q * 4 + i * 32];
      const float4 xr = *(const float4*)(xrow + q * 4 + i * 32);
      tv.x += xr.x; tv.y += xr.y; tv.z += xr.z; tv.w += xr.w;
      xv[i] = tv;
      sum += tv.x + tv.y + tv.z + tv.w;
      sq  += tv.x * tv.x + tv.y * tv.y + tv.z * tv.z + tv.w * tv.w;
    }
  }
  sum += __shfl_xor(sum, 1); sq += __shfl_xor(sq, 1);
  sum += __shfl_xor(sum, 2); sq += __shfl_xor(sq, 2);
  sum += __shfl_xor(sum, 4); sq += __shfl_xor(sq, 4);
  {
    const float mean = sum * (1.0f / CH);
    const float inv  = rsqrtf(sq * (1.0f / CH) - mean * mean + 1e-5f);
    #pragma unroll
    for (int i = 0; i < 4; ++i) {
      const int col0 = q * 4 + i * 32;
      const float4 gg = *(const float4*)(g2 + col0);
      const float4 bb = *(const float4*)(b2 + col0);
      const float m0 = (xv[i].x - mean) * inv * gg.x + bb.x;
      const float m1 = (xv[i].y - mean) * inv * gg.y + bb.y;
      const float m2 = (xv[i].z - mean) * inv * gg.z + bb.z;
      const float m3 = (xv[i].w - mean) * inv * gg.w + bb.w;
      const int slot = col0 >> 3;
      const int off = rl * 128 + ((slot ^ (rl & 15)) << 3) + (col0 & 7);
      uint2 pk; pk.x = pack2(m0, m1); pk.y = pack2(m2, m3);
      *(uint2*)&sm[off] = pk;
    }
  }
  __syncthreads();

  // ---- D: MLP (R10-proven), reading sm ----
  f32x4 oad[2][2];
  #pragma unroll
  for (int a = 0; a < 2; ++a) { oad[a][0] = (f32x4){0,0,0,0}; oad[a][1] = (f32x4){0,0,0,0}; }

  auto stage1 = [&](int hb, u16* Hbuf) {
    f32x4 c1[2];
    c1[0] = (f32x4){0.f, 0.f, 0.f, 0.f};
    c1[1] = (f32x4){0.f, 0.f, 0.f, 0.f};
    #pragma unroll
    for (int kk = 0; kk < 4; ++kk) {
      const int c16 = hb * 4 + wv;
      const bf16x8 a1 = *(const bf16x8*)(w1f + ((c16 * 4 + kk) * 64 + lane) * 8);
      bf16x8 bmv[2];
      #pragma unroll
      for (int nt = 0; nt < 2; ++nt) {
        const int r = nt * 16 + lr;
        bmv[nt] = *(const bf16x8*)(sm + r * 128 + (((kk * 4 + lk) ^ (r & 15)) << 3));
      }
      c1[0] = __builtin_amdgcn_mfma_f32_16x16x32_bf16(a1, bmv[0], c1[0], 0, 0, 0);
      c1[1] = __builtin_amdgcn_mfma_f32_16x16x32_bf16(a1, bmv[1], c1[1], 0, 0, 0);
    }
    const int hc0 = wv * 16 + lk * 4;
    const float4 bs = *(const float4*)(b1 + hb * 64 + hc0);
    #pragma unroll
    for (int nt = 0; nt < 2; ++nt) {
      const int tok = nt * 16 + lr;
      const ushort4 pk = make_ushort4(
          f2b(gelu(c1[nt][0] + bs.x)), f2b(gelu(c1[nt][1] + bs.y)),
          f2b(gelu(c1[nt][2] + bs.z)), f2b(gelu(c1[nt][3] + bs.w)));
      *(ushort4*)&Hbuf[tok * HS + hc0] = pk;
    }
  };

  auto stage2 = [&](int hb, const u16* Hbuf) {
    #pragma unroll
    for (int kk2 = 0; kk2 < 2; ++kk2) {
      bf16x8 a2[2];
      #pragma unroll
      for (int mt = 0; mt < 2; ++mt) {
        const u16* pr = &Hbuf[(mt * 16 + lr) * HS + kk2 * 32 + lk * 8];
        const bf16x4 lo = *(const bf16x4*)pr;
        const bf16x4 hi = *(const bf16x4*)(pr + 4);
        a2[mt] = __builtin_shufflevector(lo, hi, 0, 1, 2, 3, 4, 5, 6, 7);
      }
      #pragma unroll
      for (int nf2 = 0; nf2 < 2; ++nf2) {
        const int o16 = wv * 2 + nf2;
        const bf16x8 bw = *(const bf16x8*)(w2f + (((o16 * 8 + hb) * 2 + kk2) * 64 + lane) * 8);
        #pragma unroll
        for (int mt = 0; mt < 2; ++mt)
          oad[mt][nf2] = __builtin_amdgcn_mfma_f32_16x16x32_bf16(a2[mt], bw, oad[mt][nf2], 0, 0, 0);
      }
    }
  };

  u16* H0 = H;
  u16* H1 = H + 32 * HS;
  stage1(0, H0);
  __syncthreads();
  for (int hb = 0; hb < 8; ++hb) {
    u16* cur = (hb & 1) ? H1 : H0;
    u16* nxt = (hb & 1) ? H0 : H1;
    if (hb < 7) stage1(hb + 1, nxt);
    stage2(hb, cur);
    __syncthreads();
  }

  // ---- E: transpose + b2 bias, then + x1 regs -> out ----
  #pragma unroll
  for (int nf2 = 0; nf2 < 2; ++nf2) {
    const int col = wv * 32 + nf2 * 16 + lr;
    const float bs = b2f[col];
    #pragma unroll
    for (int mt = 0; mt < 2; ++mt)
      #pragma unroll
      for (int j = 0; j < 4; ++j)
        T32[(mt * 16 + lk * 4 + j) * 132 + col] = oad[mt][nf2][j] + bs;
  }
  __syncthreads();
  {
    float* orow = outp + (rowbase + rl) * CH;
    #pragma unroll
    for (int i = 0; i < 4; ++i) {
      float4 v = *(const float4*)&T32[rl * 132 + q * 4 + i * 32];
      v.x += xv[i].x; v.y += xv[i].y; v.z += xv[i].z; v.w += xv[i].w;
      *(float4*)(orow + q * 4 + i * 32) = v;
    }
  }
}

// ---------------------------------------------------------------------------
extern "C" void kernel_launch(void* const* d_in, const int* in_sizes, int n_in,
                              void* d_out, int out_size, void* d_ws, size_t ws_size,
                              hipStream_t stream)
{
  const float* x       = (const float*)d_in[0];
  const float* prompts = (const float*)d_in[1];
  const float* n1g     = (const float*)d_in[2];
  const float* n1b     = (const float*)d_in[3];
  const float* qkv_w   = (const float*)d_in[4];
  const float* qkv_b   = (const float*)d_in[5];
  const float* qkv_la  = (const float*)d_in[6];
  const float* qkv_lb  = (const float*)d_in[7];
  const float* rpb     = (const float*)d_in[8];
  const float* proj_w  = (const float*)d_in[9];
  const float* proj_b  = (const float*)d_in[10];
  const float* proj_la = (const float*)d_in[11];
  const float* proj_lb = (const float*)d_in[12];
  const float* n2g     = (const float*)d_in[13];
  const float* n2b     = (const float*)d_in[14];
  const float* fc1_w   = (const float*)d_in[15];
  const float* fc1_b   = (const float*)d_in[16];
  const float* fc1_la  = (const float*)d_in[17];
  const float* fc1_lb  = (const float*)d_in[18];
  const float* fc2_w   = (const float*)d_in[19];
  const float* fc2_b   = (const float*)d_in[20];
  const float* fc2_la  = (const float*)d_in[21];
  const float* fc2_lb  = (const float*)d_in[22];

  // workspace: [wqf|wprojf|w1f|w2f = 196608 u16] [bm 65536 f32] | tbuf | aobuf
  char* ws = (char*)d_ws;
  u16* wT     = (u16*)ws;
  u16* wqf    = wT;
  u16* wprojf = wT + 49152;
  u16* w1f    = wT + 65536;
  u16* w2f    = wT + 131072;
  float* bm   = (float*)(ws + 393216);
  char* p = ws + 393216 + 262144;
  u16* tbuf  = (u16*)p;                       p += (size_t)MWIN * CH * 2;
  u16* aobuf = (u16*)p;

  fuse_all_kernel<<<768, 256, 0, stream>>>(
      qkv_w, qkv_la, qkv_lb, proj_w, proj_la, proj_lb,
      fc1_w, fc1_la, fc1_lb, fc2_w, fc2_la, fc2_lb, wT);

  bm_kernel<<<256, 256, 0, stream>>>(rpb, bm);

  ln1_gather_kernel<<<MWIN / 4, 256, 0, stream>>>(x, prompts, n1g, n1b, tbuf);

  qkv_attn_kernel<<<BWIN, 256, 0, stream>>>(tbuf, wqf, qkv_b, bm, aobuf);

  proj_mlp_kernel<<<MPIX / 32, 256, 0, stream>>>(
      aobuf, wprojf, proj_b, x, n2g, n2b,
      w1f, fc1_b, w2f, fc2_b, (float*)d_out);
}